// Round 22
// baseline (166.224 us; speedup 1.0000x reference)
//
#include <hip/hip_runtime.h>
#include <math.h>

#define T_SEQ 2048
#define C_DIM 1024
#define NH    16
#define HD    64
#define HIN   4
#define DI    32
#define SINKN 4
#define KMINV 32
#define KMAXV 1024
#define NCAT  5120   // q|k|v|gv|go concatenated columns
#define IMPH  2228224 // packed-triangular imp floats per indexer head

typedef __bf16 bf16x8 __attribute__((ext_vector_type(8)));
typedef float  f32x4  __attribute__((ext_vector_type(4)));

__device__ __forceinline__ float sigf(float x) { return 1.f / (1.f + expf(-x)); }

__device__ __forceinline__ unsigned short f2bf(float f) {
    unsigned u = __float_as_uint(f);
    unsigned r = (u + 0x7FFFu + ((u >> 16) & 1u)) >> 16;   // RNE
    return (unsigned short)r;
}

__device__ __forceinline__ float bflo(unsigned u) { return __uint_as_float(u << 16); }
__device__ __forceinline__ float bfhi(unsigned u) { return __uint_as_float(u & 0xFFFF0000u); }
__device__ __forceinline__ float bf16f(unsigned short u) { return __uint_as_float((unsigned)u << 16); }

__device__ __forceinline__ void gload16(const unsigned short* g, unsigned short* l) {
    __builtin_amdgcn_global_load_lds(
        (const __attribute__((address_space(1))) unsigned int*)(const unsigned int*)g,
        (__attribute__((address_space(3))) unsigned int*)(unsigned int*)l,
        16, 0, 0);
}

// ---------------- bf16 MFMA GEMM body: C = A_bf16 @ B_bf16^T ------------------
template<bool OUT_BF16>
__device__ __forceinline__ void gemm_body(
    char* smemc,
    const unsigned short* __restrict__ A, const unsigned short* __restrict__ B,
    void* __restrict__ Cv, int ldc, int bx, int by)
{
    unsigned short* Asl = (unsigned short*)smemc;          // 16384 B
    unsigned short* Bsl = (unsigned short*)(smemc + 16384);// 16384 B
    const int K = C_DIM;
    const int tid = threadIdx.x;
    const int w = tid >> 6, lane = tid & 63;
    const int wm = w >> 1, wn = w & 1;
    const int m0 = by * 128, n0 = bx * 128;

    const f32x4 z4 = {0.f, 0.f, 0.f, 0.f};
    f32x4 acc[4][4];
#pragma unroll
    for (int i = 0; i < 4; ++i)
#pragma unroll
        for (int j = 0; j < 4; ++j) acc[i][j] = z4;

    const int lrow  = w * 8 + (lane >> 3);
    const int lslot = (lane & 7) ^ (lane >> 3);
    const unsigned short* Ag = A + (size_t)(m0 + lrow) * K + lslot * 8;
    const unsigned short* Bg = B + (size_t)(n0 + lrow) * K + lslot * 8;

    const int fr = lane & 15;
    const int kg = lane >> 4;

    for (int kt = 0; kt < K; kt += 64) {
        __syncthreads();
#pragma unroll
        for (int i = 0; i < 4; ++i) {
            gload16(Ag + (size_t)(i * 32) * K + kt, &Asl[(i * 32 + w * 8) * 64]);
            gload16(Bg + (size_t)(i * 32) * K + kt, &Bsl[(i * 32 + w * 8) * 64]);
        }
        __syncthreads();
#pragma unroll
        for (int ks = 0; ks < 2; ++ks) {
            bf16x8 af[4], bfr[4];
            const int aslot = ks * 4 + kg;
#pragma unroll
            for (int f = 0; f < 4; ++f) {
                const int arow = wm * 64 + f * 16 + fr;
                af[f] = *(const bf16x8*)&Asl[arow * 64 + ((aslot ^ (arow & 7)) * 8)];
                const int brow = wn * 64 + f * 16 + fr;
                bfr[f] = *(const bf16x8*)&Bsl[brow * 64 + ((aslot ^ (brow & 7)) * 8)];
            }
#pragma unroll
            for (int mi = 0; mi < 4; ++mi)
#pragma unroll
                for (int ni = 0; ni < 4; ++ni)
                    acc[mi][ni] = __builtin_amdgcn_mfma_f32_16x16x32_bf16(
                        af[mi], bfr[ni], acc[mi][ni], 0, 0, 0);
        }
    }

#pragma unroll
    for (int mi = 0; mi < 4; ++mi) {
        const int row = by * 128 + wm * 64 + mi * 16 + (lane >> 4) * 4;
#pragma unroll
        for (int ni = 0; ni < 4; ++ni) {
            const int col = bx * 128 + wn * 64 + ni * 16 + (lane & 15);
            if constexpr (OUT_BF16) {
                unsigned short* cp = (unsigned short*)Cv + (size_t)row * ldc + col;
#pragma unroll
                for (int r = 0; r < 4; ++r) cp[(size_t)r * ldc] = f2bf(acc[mi][ni][r]);
            } else {
                float* cp = (float*)Cv + (size_t)row * ldc + col;
#pragma unroll
                for (int r = 0; r < 4; ++r) cp[(size_t)r * ldc] = acc[mi][ni][r];
            }
        }
    }
}

// standalone final out-projection (f32 out)
__global__ __launch_bounds__(256) void gemm_out_kernel(
    const unsigned short* __restrict__ A, const unsigned short* __restrict__ B,
    float* __restrict__ C, int ldc)
{
    __shared__ __align__(16) char smem[32768];
    gemm_body<false>(smem, A, B, C, ldc, blockIdx.x, blockIdx.y);
}

// ---------------- component bodies ---------------------------------------------
__device__ __forceinline__ void convert_body(
    int b, const float* __restrict__ x,
    const float* __restrict__ Wq, const float* __restrict__ Wk, const float* __restrict__ Wv,
    const float* __restrict__ Wgv, const float* __restrict__ Wgo, const float* __restrict__ Wo,
    unsigned short* __restrict__ xb, unsigned short* __restrict__ Wcatb,
    unsigned short* __restrict__ Wob)
{
    const float* s; unsigned short* d; size_t off;
    if (b < 2048)      { s = x;  d = xb;  off = (size_t)b * 1024; }
    else if (b < 7168) {
        const int wsel = (b - 2048) >> 10;
        switch (wsel) {
            case 0: s = Wq;  break;
            case 1: s = Wk;  break;
            case 2: s = Wv;  break;
            case 3: s = Wgv; break;
            default: s = Wgo; break;
        }
        d = Wcatb + ((size_t)wsel << 20);
        off = (size_t)((b - 2048) & 1023) * 1024;
    } else             { s = Wo; d = Wob; off = (size_t)(b - 7168) * 1024; }

    const size_t i = off + threadIdx.x * 4;
    const float4 v = *(const float4*)(s + i);
    ushort4 o;
    o.x = f2bf(v.x); o.y = f2bf(v.y); o.z = f2bf(v.z); o.w = f2bf(v.w);
    *(ushort4*)(d + i) = o;
}

__device__ __forceinline__ void proj_w_body(
    int b, const float* __restrict__ x, const float* __restrict__ WIw,
    float* __restrict__ wsig)
{
    const int idx4 = b * 256 + threadIdx.x;
    const int part4 = idx4 & 3;
    const int oidx = idx4 >> 2;      // t*4 + hi
    const int t = oidx >> 2, hi = oidx & 3;
    const float4* xr = (const float4*)(x + (size_t)t * C_DIM + part4 * 256);
    const float4* wr = (const float4*)(WIw + (size_t)hi * C_DIM + part4 * 256);
    float s = 0.f;
#pragma unroll
    for (int i = 0; i < 64; ++i) {
        float4 a = xr[i], w4 = wr[i];
        s += a.x * w4.x + a.y * w4.y + a.z * w4.z + a.w * w4.w;
    }
    s += __shfl_xor(s, 1);
    s += __shfl_xor(s, 2);
    if (part4 == 0) wsig[oidx] = sigf(s);
}

__device__ __forceinline__ void rope_table_body(
    int b, float* __restrict__ cost, float* __restrict__ sint)
{
    const int idx = b * 256 + threadIdx.x;   // t*32 + i
    const int t = idx >> 5, i = idx & 31;
    const int j = (2 * i) & 31;
    const float invf = powf(10000.f, -(float)j / 32.f);
    const float f = (float)t * invf;
    float sv, cv;
    sincosf(f, &sv, &cv);
    cost[idx] = cv;
    sint[idx] = sv;
}

// split-K 16: kb = s*64, 4 K-iterations; 512 blocks -> 2 blocks/CU co-resident
__device__ __forceinline__ void qik_body(
    char* smemc, int which, int s, int mt,
    const float* __restrict__ x, const float* __restrict__ WIq, const float* __restrict__ WIk,
    float* __restrict__ part)
{
    float (*As)[132] = (float(*)[132])smemc;            // 8448 B
    float (*Bs)[132] = (float(*)[132])(smemc + 8448);   // 8448 B
    const float* B = which ? WIk : WIq;
    const int m0 = mt * 128;
    const int kb = s * 64;
    const int tid = threadIdx.x;
    const int tx = tid & 15, ty = tid >> 4;

    float acc[8][8];
#pragma unroll
    for (int i = 0; i < 8; ++i)
#pragma unroll
        for (int j = 0; j < 8; ++j) acc[i][j] = 0.f;

    const int sr = tid >> 1;
    const int sk = (tid & 1) * 8;
    const float* Ap = x + (size_t)(m0 + sr) * C_DIM + kb + sk;
    const float* Bp = B + (size_t)sr * C_DIM + kb + sk;

    for (int k0 = 0; k0 < 64; k0 += 16) {
        float4 a0 = *(const float4*)(Ap + k0);
        float4 a1 = *(const float4*)(Ap + k0 + 4);
        float4 b0 = *(const float4*)(Bp + k0);
        float4 b1 = *(const float4*)(Bp + k0 + 4);
        __syncthreads();
        As[sk + 0][sr] = a0.x; As[sk + 1][sr] = a0.y; As[sk + 2][sr] = a0.z; As[sk + 3][sr] = a0.w;
        As[sk + 4][sr] = a1.x; As[sk + 5][sr] = a1.y; As[sk + 6][sr] = a1.z; As[sk + 7][sr] = a1.w;
        Bs[sk + 0][sr] = b0.x; Bs[sk + 1][sr] = b0.y; Bs[sk + 2][sr] = b0.z; Bs[sk + 3][sr] = b0.w;
        Bs[sk + 4][sr] = b1.x; Bs[sk + 5][sr] = b1.y; Bs[sk + 6][sr] = b1.z; Bs[sk + 7][sr] = b1.w;
        __syncthreads();
#pragma unroll
        for (int kk = 0; kk < 16; ++kk) {
            float4 aA = *(const float4*)&As[kk][ty * 4];
            float4 aB = *(const float4*)&As[kk][64 + ty * 4];
            float4 bA = *(const float4*)&Bs[kk][tx * 4];
            float4 bB = *(const float4*)&Bs[kk][64 + tx * 4];
            float am[8] = {aA.x, aA.y, aA.z, aA.w, aB.x, aB.y, aB.z, aB.w};
            float bn[8] = {bA.x, bA.y, bA.z, bA.w, bB.x, bB.y, bB.z, bB.w};
#pragma unroll
            for (int i = 0; i < 8; ++i)
#pragma unroll
                for (int j = 0; j < 8; ++j) acc[i][j] = fmaf(am[i], bn[j], acc[i][j]);
        }
    }

    float* cp0 = part + (size_t)(which * 16 + s) * T_SEQ * 128;
#pragma unroll
    for (int ih = 0; ih < 2; ++ih)
#pragma unroll
        for (int i = 0; i < 4; ++i) {
            const int row = m0 + ih * 64 + ty * 4 + i;
            float* cp = cp0 + (size_t)row * 128;
            float4 v0 = make_float4(acc[ih*4+i][0], acc[ih*4+i][1], acc[ih*4+i][2], acc[ih*4+i][3]);
            float4 v1 = make_float4(acc[ih*4+i][4], acc[ih*4+i][5], acc[ih*4+i][6], acc[ih*4+i][7]);
            *(float4*)(cp + tx * 4) = v0;
            *(float4*)(cp + 64 + tx * 4) = v1;
        }
}

// ---------------- K1: qik_splitk16 (heavy, first) + rope_table + proj_w + convert
__global__ __launch_bounds__(256) void pre_kernel(
    const float* __restrict__ x,
    const float* __restrict__ WIq, const float* __restrict__ WIk, const float* __restrict__ WIw,
    const float* __restrict__ Wq, const float* __restrict__ Wk, const float* __restrict__ Wv,
    const float* __restrict__ Wgv, const float* __restrict__ Wgo, const float* __restrict__ Wo,
    unsigned short* __restrict__ xb, unsigned short* __restrict__ Wcatb,
    unsigned short* __restrict__ Wob,
    float* __restrict__ part, float* __restrict__ wsig,
    float* __restrict__ cost, float* __restrict__ sint)
{
    __shared__ __align__(16) char smem[16896];
    const int b = blockIdx.x;
    if (b < 512) {
        qik_body(smem, b & 1, (b >> 1) & 15, b >> 5, x, WIq, WIk, part);
    } else if (b < 768) {
        rope_table_body(b - 512, cost, sint);
    } else if (b < 896) {
        proj_w_body(b - 768, x, WIw, wsig);
    } else {
        convert_body(b - 896, x, Wq, Wk, Wv, Wgv, Wgo, Wo, xb, Wcatb, Wob);
    }
}

__global__ void qik_reduce_kernel(const float* __restrict__ part,
                                  float* __restrict__ qI, float* __restrict__ kI)
{
    const int idx = blockIdx.x * 256 + threadIdx.x;   // 0..524287
    const int which = idx >> 18;
    const int e = idx & 262143;
    const float* p = part + (size_t)which * 16 * T_SEQ * 128 + e;
    float s = 0.f;
#pragma unroll
    for (int j = 0; j < 16; ++j) s += p[(size_t)j * T_SEQ * 128];
    (which ? kI : qI)[e] = s;
}

// ---------------- impA body: causal-tiled f32 GEMM -> packed-triangular imp ----
__device__ __forceinline__ void impA_body(
    char* smemc,
    const float* __restrict__ qI, const float* __restrict__ kI,
    const float* __restrict__ wsig, const float* __restrict__ gate_bias,
    float* __restrict__ imp, int t, int hi)
{
    float (*As)[132] = (float(*)[132])smemc;             // 16896 B
    float (*Bs)[132] = (float(*)[132])(smemc + 16896);   // 16896 B
    int qi = (int)((sqrtf(8.f * (float)t + 1.f) - 1.f) * 0.5f);
    if ((qi + 1) * (qi + 2) / 2 <= t) qi++;
    if (qi * (qi + 1) / 2 > t) qi--;
    const int ki = t - qi * (qi + 1) / 2;
    const int m0 = qi * 128;

    const int tid = threadIdx.x;
    const int tx = tid & 15, ty = tid >> 4;

    {
        const int sr = tid >> 1;
        const int sk = (tid & 1) * 16;
        const float4* Ap = (const float4*)(qI + (size_t)(m0 + sr) * 128 + hi * 32 + sk);
        const float4* Bp = (const float4*)(kI + (size_t)(ki * 128 + sr) * 128 + hi * 32 + sk);
#pragma unroll
        for (int j4 = 0; j4 < 4; ++j4) {
            float4 a = Ap[j4], b = Bp[j4];
            As[sk + j4*4 + 0][sr] = a.x; As[sk + j4*4 + 1][sr] = a.y;
            As[sk + j4*4 + 2][sr] = a.z; As[sk + j4*4 + 3][sr] = a.w;
            Bs[sk + j4*4 + 0][sr] = b.x; Bs[sk + j4*4 + 1][sr] = b.y;
            Bs[sk + j4*4 + 2][sr] = b.z; Bs[sk + j4*4 + 3][sr] = b.w;
        }
    }
    __syncthreads();

    float acc[8][8];
#pragma unroll
    for (int i = 0; i < 8; ++i)
#pragma unroll
        for (int j = 0; j < 8; ++j) acc[i][j] = 0.f;

#pragma unroll
    for (int kk = 0; kk < 32; ++kk) {
        float4 aA = *(const float4*)&As[kk][ty * 4];
        float4 aB = *(const float4*)&As[kk][64 + ty * 4];
        float4 bA = *(const float4*)&Bs[kk][tx * 4];
        float4 bB = *(const float4*)&Bs[kk][64 + tx * 4];
        float am[8] = {aA.x, aA.y, aA.z, aA.w, aB.x, aB.y, aB.z, aB.w};
        float bn[8] = {bA.x, bA.y, bA.z, bA.w, bB.x, bB.y, bB.z, bB.w};
#pragma unroll
        for (int i = 0; i < 8; ++i)
#pragma unroll
            for (int j = 0; j < 8; ++j) acc[i][j] = fmaf(am[i], bn[j], acc[i][j]);
    }

    const float gb = gate_bias[hi];
    const size_t rw = (size_t)(qi + 1) * 128;
    float* impb = imp + (size_t)hi * IMPH + (size_t)16384 * (qi * (qi + 1) / 2) + ki * 128;
#pragma unroll
    for (int ih = 0; ih < 2; ++ih)
#pragma unroll
        for (int i = 0; i < 4; ++i) {
            const int rr = ih * 64 + ty * 4 + i;
            const float wr = wsig[(m0 + rr) * 4 + hi];
            float* cp = impb + (size_t)rr * rw;
            float4 v0, v1;
            v0.x = wr * sigf(acc[ih*4+i][0] + gb);
            v0.y = wr * sigf(acc[ih*4+i][1] + gb);
            v0.z = wr * sigf(acc[ih*4+i][2] + gb);
            v0.w = wr * sigf(acc[ih*4+i][3] + gb);
            v1.x = wr * sigf(acc[ih*4+i][4] + gb);
            v1.y = wr * sigf(acc[ih*4+i][5] + gb);
            v1.z = wr * sigf(acc[ih*4+i][6] + gb);
            v1.w = wr * sigf(acc[ih*4+i][7] + gb);
            *(float4*)(cp + tx * 4) = v0;
            *(float4*)(cp + 64 + tx * 4) = v1;
        }
}

// ---------------- K3: proj-GEMM (bf16 out) then impA (contiguous tiles) --------
__global__ __launch_bounds__(256) void mid_kernel(
    const unsigned short* __restrict__ xb, const unsigned short* __restrict__ Wcatb,
    unsigned short* __restrict__ lincatb,
    const float* __restrict__ qI, const float* __restrict__ kI,
    const float* __restrict__ wsig, const float* __restrict__ gate_bias,
    float* __restrict__ imp)
{
    __shared__ __align__(16) char smem[33792];
    const int b = blockIdx.x;
    if (b < 640) {
        gemm_body<true>(smem, xb, Wcatb, lincatb, NCAT, b % 40, b / 40);
    } else {
        const int bb = b - 640;
        impA_body(smem, qI, kI, wsig, gate_bias, imp, bb % 136, bb / 136);
    }
}

// ---------------- impB body: var -> k_t, threshold binary search, emission ----
template<int NC>
__device__ __forceinline__ void impB_body(
    const float* __restrict__ imp, const float* __restrict__ head_bias,
    unsigned short* __restrict__ sidxg, unsigned* __restrict__ cnts,
    int q, int hi, int lane)
{
    const int qc = q >> 6;   // last causal chunk (wave-uniform)
    const unsigned long long lmask_lt = (lane == 0) ? 0ull : ((~0ull) >> (64 - lane));

    const int qi = q >> 7;
    const size_t rw = (size_t)(qi + 1) * 128;
    const float* row = imp + (size_t)hi * IMPH +
                       (size_t)16384 * (qi * (qi + 1) / 2) + (size_t)(q - qi * 128) * rw;

    unsigned ordv[NC];
    double dsum = 0.0, dsq = 0.0;
#pragma unroll
    for (int i = 0; i < NC; ++i) {
        const int k = i * 64 + lane;
        unsigned vb = 0u;
        if (i <= qc) {
            const float v = row[k];
            const bool causal = (k <= q);
            const float vm = causal ? v : 0.f;
            dsum += (double)vm;
            dsq  += (double)vm * (double)vm;
            vb = causal ? __float_as_uint(v) : 0u;
        }
        if (i == 0 && lane < SINKN) vb = 0x7F800000u;
        ordv[i] = vb;
    }

#pragma unroll
    for (int off = 1; off < 64; off <<= 1) {
        dsum += __shfl_xor(dsum, off);
        dsq  += __shfl_xor(dsq, off);
    }

    int kts[4];
#pragma unroll
    for (int j = 0; j < 4; ++j) {
        const float sh = sigf(head_bias[hi * 4 + j]);
        const double mean = dsum / (double)T_SEQ;
        double var = dsq / (double)T_SEQ - mean * mean;
        if (var < 0.0) var = 0.0;
        const double vh = var * (double)sh * (double)sh;
        int kt = (int)floor(512.0 * vh);
        kt = kt < KMINV ? KMINV : (kt > KMAXV ? KMAXV : kt);
        kts[j] = kt;
    }

    unsigned vs[4]; int tt[4];
#pragma unroll
    for (int j = 0; j < 4; ++j) {
        bool dup = false;
#pragma unroll
        for (int p = 0; p < 4; ++p) {
            if (p < j && !dup && kts[p] == kts[j]) { vs[j] = vs[p]; tt[j] = tt[p]; dup = true; }
        }
        if (!dup) {
            const int kt = kts[j];
            unsigned X = 0;
#pragma unroll 1
            for (int b = 30; b >= 0; --b) {
                const unsigned Xt = X | (1u << b);
                int c = 0;
#pragma unroll
                for (int i = 0; i < NC; ++i)
                    c += (int)__popcll(__ballot(ordv[i] >= Xt));
                if (c >= kt) X = Xt;
            }
            int cg = 0;
#pragma unroll
            for (int i = 0; i < NC; ++i)
                cg += (int)__popcll(__ballot(ordv[i] > X));
            vs[j] = X; tt[j] = kt - cg;
        }
    }

    unsigned cnt = 0;
    unsigned short* sp = sidxg + ((size_t)hi * T_SEQ + q) * KMAXV;
    const bool uni = (kts[0] == kts[1]) && (kts[1] == kts[2]) && (kts[2] == kts[3]);

    if (uni) {
        int eqr = 0;
        const unsigned v0 = vs[0]; const int t0 = tt[0];
#pragma unroll
        for (int i = 0; i < NC; ++i) {
            const int k = i * 64 + lane;
            const unsigned x = ordv[i];
            const bool eq = (x == v0);
            const unsigned long long beq = __ballot(eq);
            const bool sel = (x > v0) || (eq && (eqr + (int)__popcll(beq & lmask_lt) < t0));
            eqr += (int)__popcll(beq);
            const bool valid = (k <= q) && sel;
            const unsigned long long bv = __ballot(valid);
            if (valid) {
                const unsigned pos = cnt + (unsigned)__popcll(bv & lmask_lt);
                if (pos < KMAXV) sp[pos] = (unsigned short)((unsigned)k | (0xFu << 11));
            }
            cnt += (unsigned)__popcll(bv);
        }
    } else {
        int eqr0 = 0, eqr1 = 0, eqr2 = 0, eqr3 = 0;
#pragma unroll
        for (int i = 0; i < NC; ++i) {
            const int k = i * 64 + lane;
            const unsigned x = ordv[i];
            unsigned mask = 0;
            {
                const bool eq = (x == vs[0]);
                const unsigned long long beq = __ballot(eq);
                const bool sel = (x > vs[0]) || (eq && (eqr0 + (int)__popcll(beq & lmask_lt) < tt[0]));
                eqr0 += (int)__popcll(beq);
                if (sel) mask |= 1u;
            }
            {
                const bool eq = (x == vs[1]);
                const unsigned long long beq = __ballot(eq);
                const bool sel = (x > vs[1]) || (eq && (eqr1 + (int)__popcll(beq & lmask_lt) < tt[1]));
                eqr1 += (int)__popcll(beq);
                if (sel) mask |= 2u;
            }
            {
                const bool eq = (x == vs[2]);
                const unsigned long long beq = __ballot(eq);
                const bool sel = (x > vs[2]) || (eq && (eqr2 + (int)__popcll(beq & lmask_lt) < tt[2]));
                eqr2 += (int)__popcll(beq);
                if (sel) mask |= 4u;
            }
            {
                const bool eq = (x == vs[3]);
                const unsigned long long beq = __ballot(eq);
                const bool sel = (x > vs[3]) || (eq && (eqr3 + (int)__popcll(beq & lmask_lt) < tt[3]));
                eqr3 += (int)__popcll(beq);
                if (sel) mask |= 8u;
            }
            const bool valid = (k <= q) && (mask != 0u);
            const unsigned long long bv = __ballot(valid);
            if (valid) {
                const unsigned pos = cnt + (unsigned)__popcll(bv & lmask_lt);
                if (pos < KMAXV) sp[pos] = (unsigned short)((unsigned)k | (mask << 11));
            }
            cnt += (unsigned)__popcll(bv);
        }
    }
    if (lane == 0) cnts[(size_t)hi * T_SEQ + q] = cnt < KMAXV ? cnt : KMAXV;
}

__device__ __forceinline__ void rope_v_body(
    int b, const unsigned short* __restrict__ lincatb,
    const float* __restrict__ cost, const float* __restrict__ sint,
    float* __restrict__ Q, unsigned short* __restrict__ Kb, unsigned short* __restrict__ Vb)
{
    const int idx = b * 256 + threadIdx.x;   // (t*16+h)*32 + i
    const int i = idx & 31;
    const int h = (idx >> 5) & 15;
    const int t = idx >> 9;
    const float cv = cost[t * 32 + i], sv = sint[t * 32 + i];
    const size_t src = (size_t)t * NCAT + h * HD + 2 * i;
    const ushort2 q2 = *(const ushort2*)(lincatb + src);
    const ushort2 k2 = *(const ushort2*)(lincatb + src + 1024);
    const ushort2 v2 = *(const ushort2*)(lincatb + src + 2048);
    const ushort2 g2 = *(const ushort2*)(lincatb + src + 3072);
    const float qx = bf16f(q2.x), qy = bf16f(q2.y);
    const float kx = bf16f(k2.x), ky = bf16f(k2.y);
    const float vx = bf16f(v2.x), vy = bf16f(v2.y);
    const float gx = bf16f(g2.x), gy = bf16f(g2.y);
    const size_t dst = ((size_t)h * T_SEQ + t) * HD;
    Q[dst + i]      = qx * cv - qy * sv;
    Q[dst + 32 + i] = qx * sv + qy * cv;
    Kb[dst + i]      = f2bf(kx * cv - ky * sv);
    Kb[dst + 32 + i] = f2bf(kx * sv + ky * cv);
    ushort2 vo;
    vo.x = f2bf(vx * sigf(gx));
    vo.y = f2bf(vy * sigf(gy));
    *(ushort2*)(Vb + dst + 2 * i) = vo;
}

// ---------------- K4: impB (LPT bands first) + rope_v -------------------------
__global__ __launch_bounds__(256) void sel_kernel(
    const float* __restrict__ imp, const float* __restrict__ head_bias,
    unsigned short* __restrict__ sidxg, unsigned* __restrict__ cnts,
    const unsigned short* __restrict__ lincatb,
    const float* __restrict__ cost, const float* __restrict__ sint,
    float* __restrict__ Q, unsigned short* __restrict__ Kb, unsigned short* __restrict__ Vb)
{
    const int b = blockIdx.x;
    if (b < 2048) {
        const int bx = b & 511;
        const int hi = b >> 9;
        const int wv = threadIdx.x >> 6;
        const int lane = threadIdx.x & 63;
        const int band = 7 - (bx >> 6);   // LPT: heaviest first
        const int bxx = bx & 63;
        const int q = band * 256 + bxx * 4 + wv;
        switch (band) {
            case 0:  impB_body< 4>(imp, head_bias, sidxg, cnts, q, hi, lane); break;
            case 1:  impB_body< 8>(imp, head_bias, sidxg, cnts, q, hi, lane); break;
            case 2:  impB_body<12>(imp, head_bias, sidxg, cnts, q, hi, lane); break;
            case 3:  impB_body<16>(imp, head_bias, sidxg, cnts, q, hi, lane); break;
            case 4:  impB_body<20>(imp, head_bias, sidxg, cnts, q, hi, lane); break;
            case 5:  impB_body<24>(imp, head_bias, sidxg, cnts, q, hi, lane); break;
            case 6:  impB_body<28>(imp, head_bias, sidxg, cnts, q, hi, lane); break;
            default: impB_body<32>(imp, head_bias, sidxg, cnts, q, hi, lane); break;
        }
    } else {
        rope_v_body(b - 2048, lincatb, cost, sint, Q, Kb, Vb);
    }
}

// ---------------- sparse gather attention: 2 queries per wave, bf16 K/V -------
__global__ __launch_bounds__(256) void attn_sparse_kernel(
    const float* __restrict__ Q, const unsigned short* __restrict__ Kb,
    const unsigned short* __restrict__ Vb,
    const unsigned short* __restrict__ sidx, const unsigned* __restrict__ cnts,
    const unsigned short* __restrict__ lincatb, unsigned short* __restrict__ ogb)
{
    const int orig = blockIdx.x + (blockIdx.y << 8);          // gridDim = (256,16)
    const int c = ((orig & 7) << 9) | (orig >> 3);            // XCD j -> heads 2j,2j+1
    const int h = c >> 8;
    const int qt = c & 255;
    const int hi = h >> 2, hj = h & 3;
    const int wv = threadIdx.x >> 6;
    const int lane = threadIdx.x & 63;
    const int qh = lane >> 5;         // query within pair
    const int l32 = lane & 31;
    const int kk = l32 >> 2;          // key slot 0..7
    const int dg = lane & 3;          // dim group 0..3
    const int q = qt * 8 + wv * 2 + qh;

    const size_t hq = (size_t)hi * T_SEQ + q;
    const int nv = (int)cnts[hq];
    const int nvm = max(nv, __shfl_xor(nv, 32));   // wave-uniform path choice
    const unsigned short* sp = sidx + hq * KMAXV;
    const unsigned short* Kh = Kb + (size_t)h * T_SEQ * HD + dg * 16;
    const unsigned short* Vh = Vb + (size_t)h * T_SEQ * HD + dg * 16;

    float4 qg[4];
    {
        const float4* qp = (const float4*)(Q + ((size_t)h * T_SEQ + q) * HD + dg * 16);
        qg[0] = qp[0]; qg[1] = qp[1]; qg[2] = qp[2]; qg[3] = qp[3];
    }

    float acc[16];
#pragma unroll
    for (int i = 0; i < 16; ++i) acc[i] = 0.f;
    float l = 0.f;

    if (nvm <= 32) {
        const ushort4 e4 = *(const ushort4*)(sp + kk * 4);
        const unsigned ev[4] = {e4.x, e4.y, e4.z, e4.w};

        float s[4]; int idxs[4];
#pragma unroll
        for (int sub = 0; sub < 4; ++sub) {
            const int kpos = kk * 4 + sub;
            const unsigned e = ev[sub];
            const bool ok = (kpos < nv) && ((e >> (11 + hj)) & 1u);
            const int iv = ok ? (int)(e & 0x7FFu) : 0;
            idxs[sub] = iv;
            const uint4* kr = (const uint4*)(Kh + (size_t)iv * HD);
            uint4 ka = kr[0], kb2 = kr[1];
            float da = 0.f, db = 0.f;
            da = fmaf(qg[0].x, bflo(ka.x), da); da = fmaf(qg[0].y, bfhi(ka.x), da);
            da = fmaf(qg[0].z, bflo(ka.y), da); da = fmaf(qg[0].w, bfhi(ka.y), da);
            db = fmaf(qg[1].x, bflo(ka.z), db); db = fmaf(qg[1].y, bfhi(ka.z), db);
            db = fmaf(qg[1].z, bflo(ka.w), db); db = fmaf(qg[1].w, bfhi(ka.w), db);
            da = fmaf(qg[2].x, bflo(kb2.x), da); da = fmaf(qg[2].y, bfhi(kb2.x), da);
            da = fmaf(qg[2].z, bflo(kb2.y), da); da = fmaf(qg[2].w, bfhi(kb2.y), da);
            db = fmaf(qg[3].x, bflo(kb2.z), db); db = fmaf(qg[3].y, bfhi(kb2.z), db);
            db = fmaf(qg[3].z, bflo(kb2.w), db); db = fmaf(qg[3].w, bfhi(kb2.w), db);
            float dot = da + db;
            dot += __shfl_xor(dot, 1);
            dot += __shfl_xor(dot, 2);
            s[sub] = ok ? dot * 0.125f : -INFINITY;
        }

        float cm = fmaxf(fmaxf(s[0], s[1]), fmaxf(s[2], s[3]));
        cm = fmaxf(cm, __shfl_xor(cm, 4));
        cm = fmaxf(cm, __shfl_xor(cm, 8));
        cm = fmaxf(cm, __shfl_xor(cm, 16));

        float p[4];
        float ls = 0.f;
#pragma unroll
        for (int sub = 0; sub < 4; ++sub) { p[sub] = expf(s[sub] - cm); ls += p[sub]; }
        ls += __shfl_xor(ls, 4);
        ls += __shfl_xor(ls, 8);
        ls += __shfl_xor(ls, 16);
        l = ls;
#pragma unroll
        for (int sub = 0; sub < 4; ++sub) {
            const float pv = p[sub];                         // 0 for masked
            const uint4* vr = (const uint4*)(Vh + (size_t)idxs[sub] * HD);
            uint4 va = vr[0], vb4 = vr[1];
            acc[0]  = fmaf(pv, bflo(va.x), acc[0]);   acc[1]  = fmaf(pv, bfhi(va.x), acc[1]);
            acc[2]  = fmaf(pv, bflo(va.y), acc[2]);   acc[3]  = fmaf(pv, bfhi(va.y), acc[3]);
            acc[4]  = fmaf(pv, bflo(va.z), acc[4]);   acc[5]  = fmaf(pv, bfhi(va.z), acc[5]);
            acc[6]  = fmaf(pv, bflo(va.w), acc[6]);   acc[7]  = fmaf(pv, bfhi(va.w), acc[7]);
            acc[8]  = fmaf(pv, bflo(vb4.x), acc[8]);  acc[9]  = fmaf(pv, bfhi(vb4.x), acc[9]);
            acc[10] = fmaf(pv, bflo(vb4.y), acc[10]); acc[11] = fmaf(pv, bfhi(vb4.y), acc[11]);
            acc[12] = fmaf(pv, bflo(vb4.z), acc[12]); acc[13] = fmaf(pv, bfhi(vb4.z), acc[13]);
            acc[14] = fmaf(pv, bflo(vb4.w), acc[14]); acc[15] = fmaf(pv, bfhi(vb4.w), acc[15]);
        }
    } else {
        float m = -INFINITY;
        for (int base = 0; base < nvm; base += 32) {
            const int nk = nv - base;
            const ushort4 e4 = *(const ushort4*)(sp + base + kk * 4);
            const unsigned ev[4] = {e4.x, e4.y, e4.z, e4.w};

            float s[4]; int idxs[4];
#pragma unroll
            for (int sub = 0; sub < 4; ++sub) {
                const int kpos = kk * 4 + sub;
                const unsigned e = ev[sub];
                const bool ok = (kpos < nk) && ((e >> (11 + hj)) & 1u);
                const int iv = ok ? (int)(e & 0x7FFu) : 0;
                idxs[sub] = iv;
                const uint4* kr = (const uint4*)(Kh + (size_t)iv * HD);
                uint4 ka = kr[0], kb2 = kr[1];
                float da = 0.f, db = 0.f;
                da = fmaf(qg[0].x, bflo(ka.x), da); da = fmaf(qg[0].y, bfhi(ka.x), da);
                da = fmaf(qg[0].z, bflo(ka.y), da); da = fmaf(qg[0].w, bfhi(ka.y), da);
                db = fmaf(qg[1].x, bflo(ka.z), db); db = fmaf(qg[1].y, bfhi(ka.z), db);
                db = fmaf(qg[1].z, bflo(ka.w), db); db = fmaf(qg[1].w, bfhi(ka.w), db);
                da = fmaf(qg[2].x, bflo(kb2.x), da); da = fmaf(qg[2].y, bfhi(kb2.x), da);
                da = fmaf(qg[2].z, bflo(kb2.y), da); da = fmaf(qg[2].w, bfhi(kb2.y), da);
                db = fmaf(qg[3].x, bflo(kb2.z), db); db = fmaf(qg[3].y, bfhi(kb2.z), db);
                db = fmaf(qg[3].z, bflo(kb2.w), db); db = fmaf(qg[3].w, bfhi(kb2.w), db);
                float dot = da + db;
                dot += __shfl_xor(dot, 1);
                dot += __shfl_xor(dot, 2);
                s[sub] = ok ? dot * 0.125f : -INFINITY;
            }

            float cm = fmaxf(fmaxf(s[0], s[1]), fmaxf(s[2], s[3]));
            cm = fmaxf(cm, __shfl_xor(cm, 4));
            cm = fmaxf(cm, __shfl_xor(cm, 8));
            cm = fmaxf(cm, __shfl_xor(cm, 16));
            const float mn = fmaxf(m, cm);
            if (mn > -INFINITY) {
                const float alpha = expf(m - mn);
                float p[4];
                float ls = 0.f;
#pragma unroll
                for (int sub = 0; sub < 4; ++sub) { p[sub] = expf(s[sub] - mn); ls += p[sub]; }
                ls += __shfl_xor(ls, 4);
                ls += __shfl_xor(ls, 8);
                ls += __shfl_xor(ls, 16);
                l = l * alpha + ls;
#pragma unroll
                for (int i = 0; i < 16; ++i) acc[i] *= alpha;
#pragma unroll
                for (int sub = 0; sub < 4; ++sub) {
                    const float pv = p[sub];
                    const uint4* vr = (const uint4*)(Vh + (size_t)idxs[sub] * HD);
                    uint4 va = vr[0], vb4 = vr[1];
                    acc[0]  = fmaf(pv, bflo(va.x), acc[0]);   acc[1]  = fmaf(pv, bfhi(va.x), acc[1]);
                    acc[2]  = fmaf(pv, bflo(va.y), acc[2]);   acc[3]  = fmaf(pv, bfhi(va.y), acc[3]);
                    acc[4]  = fmaf(pv, bflo(va.z), acc[4]);   acc[5]  = fmaf(pv, bfhi(va.z), acc[5]);
                    acc[6]  = fmaf(pv, bflo(va.w), acc[6]);   acc[7]  = fmaf(pv, bfhi(va.w), acc[7]);
                    acc[8]  = fmaf(pv, bflo(vb4.x), acc[8]);  acc[9]  = fmaf(pv, bfhi(vb4.x), acc[9]);
                    acc[10] = fmaf(pv, bflo(vb4.y), acc[10]); acc[11] = fmaf(pv, bfhi(vb4.y), acc[11]);
                    acc[12] = fmaf(pv, bflo(vb4.z), acc[12]); acc[13] = fmaf(pv, bfhi(vb4.z), acc[13]);
                    acc[14] = fmaf(pv, bflo(vb4.w), acc[14]); acc[15] = fmaf(pv, bfhi(vb4.w), acc[15]);
                }
                m = mn;
            }
        }
    }

#pragma unroll
    for (int i = 0; i < 16; ++i) {
        acc[i] += __shfl_xor(acc[i], 4);
        acc[i] += __shfl_xor(acc[i], 8);
        acc[i] += __shfl_xor(acc[i], 16);
    }
    const float invl = 1.f / l;
    float oval0 = acc[0], oval1 = acc[1];
#pragma unroll
    for (int i = 1; i < 8; ++i)
        if (kk == i) { oval0 = acc[2 * i]; oval1 = acc[2 * i + 1]; }
    const int d0 = dg * 16 + kk * 2;
    const ushort2 g2 = *(const ushort2*)(lincatb + (size_t)q * NCAT + 4096 + h * HD + d0);
    ushort2 o2;
    o2.x = f2bf(oval0 * invl * sigf(bf16f(g2.x)));
    o2.y = f2bf(oval1 * invl * sigf(bf16f(g2.y)));
    *(ushort2*)(ogb + (size_t)q * C_DIM + h * HD + d0) = o2;
}

extern "C" void kernel_launch(void* const* d_in, const int* in_sizes, int n_in,
                              void* d_out, int out_size, void* d_ws, size_t ws_size,
                              hipStream_t stream)
{
    const float* x   = (const float*)d_in[0];
    const float* WIq = (const float*)d_in[1];
    const float* WIk = (const float*)d_in[2];
    const float* WIw = (const float*)d_in[3];
    const float* gb  = (const float*)d_in[4];
    const float* hib = (const float*)d_in[5];
    const float* Wq  = (const float*)d_in[6];
    const float* Wk  = (const float*)d_in[7];
    const float* Wv  = (const float*)d_in[8];
    const float* Wgv = (const float*)d_in[9];
    const float* Wgo = (const float*)d_in[10];
    const float* Wo  = (const float*)d_in[11];
    float* out = (float*)d_out;

    char* ws = (char*)d_ws;
    const size_t MB = 1024 * 1024;
    float*    qI     = (float*)(ws + 0 * MB);                 // 1 MB
    float*    kI     = (float*)(ws + 1 * MB);                 // 1 MB
    float*    wsig   = (float*)(ws + 2 * MB);                 // 32 KB
    unsigned* cnts   = (unsigned*)(ws + 2 * MB + 64 * 1024);  // 32 KB
    float*    cost   = (float*)(ws + 2 * MB + 512 * 1024);    // 256 KB
    float*    sint   = (float*)(ws + 2 * MB + 768 * 1024);    // 256 KB
    float*    Q      = (float*)(ws + 3 * MB);                 // 8 MB  -> 11
    unsigned short* Kb = (unsigned short*)(ws + 11 * MB);     // 4 MB  -> 15
    unsigned short* Vb = (unsigned short*)(ws + 15 * MB);     // 4 MB  -> 19
    unsigned short* sidx = (unsigned short*)(ws + 19 * MB);   // 16 MB -> 35
    // region A (35..71): part (32 MB, K1 write / K2 read) -> imp (35.7 MB, K3 write / K4 read)
    float*    part    = (float*)(ws + 35 * MB);
    float*    imp     = (float*)(ws + 35 * MB);
    unsigned short* lincatb = (unsigned short*)(ws + 71 * MB);// 20 MB -> 91 (written K3)
    unsigned short* ogb   = (unsigned short*)(ws + 91 * MB);  // 4 MB  -> 95
    unsigned short* xb    = (unsigned short*)(ws + 95 * MB);  // 4 MB  -> 99
    unsigned short* Wcatb = (unsigned short*)(ws + 99 * MB);  // 10 MB -> 109
    unsigned short* Wob   = (unsigned short*)(ws + 109 * MB); // 2 MB  -> 111

    // K1: qik_splitk16 (heavy first, 2 blocks/CU) + rope_table + proj_w + convert_all
    pre_kernel<<<dim3(9088), 256, 0, stream>>>(
        x, WIq, WIk, WIw, Wq, Wk, Wv, Wgv, Wgo, Wo,
        xb, Wcatb, Wob, part, wsig, cost, sint);
    // K2
    qik_reduce_kernel<<<dim3(2048), 256, 0, stream>>>(part, qI, kI);
    // K3: proj-GEMM (bf16 out) then impA (contiguous GEMM tiles for L2 locality)
    mid_kernel<<<dim3(1184), 256, 0, stream>>>(
        xb, Wcatb, lincatb, qI, kI, wsig, gb, imp);
    // K4: impB + rope_v
    sel_kernel<<<dim3(6144), 256, 0, stream>>>(
        imp, hib, sidx, cnts, lincatb, cost, sint, Q, Kb, Vb);
    // attention + out-projection
    attn_sparse_kernel<<<dim3(256, 16), 256, 0, stream>>>(Q, Kb, Vb, sidx, cnts, lincatb, ogb);
    gemm_out_kernel<<<dim3(8, 16), 256, 0, stream>>>(ogb, Wob, out, C_DIM);
}

// Round 23
// 164.309 us; speedup vs baseline: 1.0117x; 1.0117x over previous
//
#include <hip/hip_runtime.h>
#include <math.h>

#define T_SEQ 2048
#define C_DIM 1024
#define NH    16
#define HD    64
#define HIN   4
#define DI    32
#define SINKN 4
#define KMINV 32
#define KMAXV 1024
#define NCAT  5120   // q|k|v|gv|go concatenated columns
#define IMPH  2228224 // packed-triangular imp floats per indexer head

typedef __bf16 bf16x8 __attribute__((ext_vector_type(8)));
typedef float  f32x4  __attribute__((ext_vector_type(4)));

__device__ __forceinline__ float sigf(float x) { return 1.f / (1.f + expf(-x)); }

__device__ __forceinline__ unsigned short f2bf(float f) {
    unsigned u = __float_as_uint(f);
    unsigned r = (u + 0x7FFFu + ((u >> 16) & 1u)) >> 16;   // RNE
    return (unsigned short)r;
}

__device__ __forceinline__ float bflo(unsigned u) { return __uint_as_float(u << 16); }
__device__ __forceinline__ float bfhi(unsigned u) { return __uint_as_float(u & 0xFFFF0000u); }
__device__ __forceinline__ float bf16f(unsigned short u) { return __uint_as_float((unsigned)u << 16); }

__device__ __forceinline__ void gload16(const unsigned short* g, unsigned short* l) {
    __builtin_amdgcn_global_load_lds(
        (const __attribute__((address_space(1))) unsigned int*)(const unsigned int*)g,
        (__attribute__((address_space(3))) unsigned int*)(unsigned int*)l,
        16, 0, 0);
}

// ---------------- bf16 MFMA GEMM body: C = A_bf16 @ B_bf16^T ------------------
template<bool OUT_BF16>
__device__ __forceinline__ void gemm_body(
    char* smemc,
    const unsigned short* __restrict__ A, const unsigned short* __restrict__ B,
    void* __restrict__ Cv, int ldc, int bx, int by)
{
    unsigned short* Asl = (unsigned short*)smemc;          // 16384 B
    unsigned short* Bsl = (unsigned short*)(smemc + 16384);// 16384 B
    const int K = C_DIM;
    const int tid = threadIdx.x;
    const int w = tid >> 6, lane = tid & 63;
    const int wm = w >> 1, wn = w & 1;
    const int m0 = by * 128, n0 = bx * 128;

    const f32x4 z4 = {0.f, 0.f, 0.f, 0.f};
    f32x4 acc[4][4];
#pragma unroll
    for (int i = 0; i < 4; ++i)
#pragma unroll
        for (int j = 0; j < 4; ++j) acc[i][j] = z4;

    const int lrow  = w * 8 + (lane >> 3);
    const int lslot = (lane & 7) ^ (lane >> 3);
    const unsigned short* Ag = A + (size_t)(m0 + lrow) * K + lslot * 8;
    const unsigned short* Bg = B + (size_t)(n0 + lrow) * K + lslot * 8;

    const int fr = lane & 15;
    const int kg = lane >> 4;

    for (int kt = 0; kt < K; kt += 64) {
        __syncthreads();
#pragma unroll
        for (int i = 0; i < 4; ++i) {
            gload16(Ag + (size_t)(i * 32) * K + kt, &Asl[(i * 32 + w * 8) * 64]);
            gload16(Bg + (size_t)(i * 32) * K + kt, &Bsl[(i * 32 + w * 8) * 64]);
        }
        __syncthreads();
#pragma unroll
        for (int ks = 0; ks < 2; ++ks) {
            bf16x8 af[4], bfr[4];
            const int aslot = ks * 4 + kg;
#pragma unroll
            for (int f = 0; f < 4; ++f) {
                const int arow = wm * 64 + f * 16 + fr;
                af[f] = *(const bf16x8*)&Asl[arow * 64 + ((aslot ^ (arow & 7)) * 8)];
                const int brow = wn * 64 + f * 16 + fr;
                bfr[f] = *(const bf16x8*)&Bsl[brow * 64 + ((aslot ^ (brow & 7)) * 8)];
            }
#pragma unroll
            for (int mi = 0; mi < 4; ++mi)
#pragma unroll
                for (int ni = 0; ni < 4; ++ni)
                    acc[mi][ni] = __builtin_amdgcn_mfma_f32_16x16x32_bf16(
                        af[mi], bfr[ni], acc[mi][ni], 0, 0, 0);
        }
    }

#pragma unroll
    for (int mi = 0; mi < 4; ++mi) {
        const int row = by * 128 + wm * 64 + mi * 16 + (lane >> 4) * 4;
#pragma unroll
        for (int ni = 0; ni < 4; ++ni) {
            const int col = bx * 128 + wn * 64 + ni * 16 + (lane & 15);
            if constexpr (OUT_BF16) {
                unsigned short* cp = (unsigned short*)Cv + (size_t)row * ldc + col;
#pragma unroll
                for (int r = 0; r < 4; ++r) cp[(size_t)r * ldc] = f2bf(acc[mi][ni][r]);
            } else {
                float* cp = (float*)Cv + (size_t)row * ldc + col;
#pragma unroll
                for (int r = 0; r < 4; ++r) cp[(size_t)r * ldc] = acc[mi][ni][r];
            }
        }
    }
}

// standalone final out-projection (f32 out)
__global__ __launch_bounds__(256) void gemm_out_kernel(
    const unsigned short* __restrict__ A, const unsigned short* __restrict__ B,
    float* __restrict__ C, int ldc)
{
    __shared__ __align__(16) char smem[32768];
    gemm_body<false>(smem, A, B, C, ldc, blockIdx.x, blockIdx.y);
}

// ---------------- component bodies ---------------------------------------------
__device__ __forceinline__ void convert_body(
    int b, const float* __restrict__ x,
    const float* __restrict__ Wq, const float* __restrict__ Wk, const float* __restrict__ Wv,
    const float* __restrict__ Wgv, const float* __restrict__ Wgo, const float* __restrict__ Wo,
    unsigned short* __restrict__ xb, unsigned short* __restrict__ Wcatb,
    unsigned short* __restrict__ Wob)
{
    const float* s; unsigned short* d; size_t off;
    if (b < 2048)      { s = x;  d = xb;  off = (size_t)b * 1024; }
    else if (b < 7168) {
        const int wsel = (b - 2048) >> 10;
        switch (wsel) {
            case 0: s = Wq;  break;
            case 1: s = Wk;  break;
            case 2: s = Wv;  break;
            case 3: s = Wgv; break;
            default: s = Wgo; break;
        }
        d = Wcatb + ((size_t)wsel << 20);
        off = (size_t)((b - 2048) & 1023) * 1024;
    } else             { s = Wo; d = Wob; off = (size_t)(b - 7168) * 1024; }

    const size_t i = off + threadIdx.x * 4;
    const float4 v = *(const float4*)(s + i);
    ushort4 o;
    o.x = f2bf(v.x); o.y = f2bf(v.y); o.z = f2bf(v.z); o.w = f2bf(v.w);
    *(ushort4*)(d + i) = o;
}

__device__ __forceinline__ void proj_w_body(
    int b, const float* __restrict__ x, const float* __restrict__ WIw,
    float* __restrict__ wsig)
{
    const int idx4 = b * 256 + threadIdx.x;
    const int part4 = idx4 & 3;
    const int oidx = idx4 >> 2;      // t*4 + hi
    const int t = oidx >> 2, hi = oidx & 3;
    const float4* xr = (const float4*)(x + (size_t)t * C_DIM + part4 * 256);
    const float4* wr = (const float4*)(WIw + (size_t)hi * C_DIM + part4 * 256);
    float s = 0.f;
#pragma unroll
    for (int i = 0; i < 64; ++i) {
        float4 a = xr[i], w4 = wr[i];
        s += a.x * w4.x + a.y * w4.y + a.z * w4.z + a.w * w4.w;
    }
    s += __shfl_xor(s, 1);
    s += __shfl_xor(s, 2);
    if (part4 == 0) wsig[oidx] = sigf(s);
}

__device__ __forceinline__ void rope_table_body(
    int b, float* __restrict__ cost, float* __restrict__ sint)
{
    const int idx = b * 256 + threadIdx.x;   // t*32 + i
    const int t = idx >> 5, i = idx & 31;
    const int j = (2 * i) & 31;
    const float invf = powf(10000.f, -(float)j / 32.f);
    const float f = (float)t * invf;
    float sv, cv;
    sincosf(f, &sv, &cv);
    cost[idx] = cv;
    sint[idx] = sv;
}

// split-K 8 (proven r21 config): kb = s*128, 8 K-iterations
__device__ __forceinline__ void qik_body(
    char* smemc, int which, int s, int mt,
    const float* __restrict__ x, const float* __restrict__ WIq, const float* __restrict__ WIk,
    float* __restrict__ part)
{
    float (*As)[132] = (float(*)[132])smemc;            // 8448 B
    float (*Bs)[132] = (float(*)[132])(smemc + 8448);   // 8448 B
    const float* B = which ? WIk : WIq;
    const int m0 = mt * 128;
    const int kb = s * 128;
    const int tid = threadIdx.x;
    const int tx = tid & 15, ty = tid >> 4;

    float acc[8][8];
#pragma unroll
    for (int i = 0; i < 8; ++i)
#pragma unroll
        for (int j = 0; j < 8; ++j) acc[i][j] = 0.f;

    const int sr = tid >> 1;
    const int sk = (tid & 1) * 8;
    const float* Ap = x + (size_t)(m0 + sr) * C_DIM + kb + sk;
    const float* Bp = B + (size_t)sr * C_DIM + kb + sk;

    for (int k0 = 0; k0 < 128; k0 += 16) {
        float4 a0 = *(const float4*)(Ap + k0);
        float4 a1 = *(const float4*)(Ap + k0 + 4);
        float4 b0 = *(const float4*)(Bp + k0);
        float4 b1 = *(const float4*)(Bp + k0 + 4);
        __syncthreads();
        As[sk + 0][sr] = a0.x; As[sk + 1][sr] = a0.y; As[sk + 2][sr] = a0.z; As[sk + 3][sr] = a0.w;
        As[sk + 4][sr] = a1.x; As[sk + 5][sr] = a1.y; As[sk + 6][sr] = a1.z; As[sk + 7][sr] = a1.w;
        Bs[sk + 0][sr] = b0.x; Bs[sk + 1][sr] = b0.y; Bs[sk + 2][sr] = b0.z; Bs[sk + 3][sr] = b0.w;
        Bs[sk + 4][sr] = b1.x; Bs[sk + 5][sr] = b1.y; Bs[sk + 6][sr] = b1.z; Bs[sk + 7][sr] = b1.w;
        __syncthreads();
#pragma unroll
        for (int kk = 0; kk < 16; ++kk) {
            float4 aA = *(const float4*)&As[kk][ty * 4];
            float4 aB = *(const float4*)&As[kk][64 + ty * 4];
            float4 bA = *(const float4*)&Bs[kk][tx * 4];
            float4 bB = *(const float4*)&Bs[kk][64 + tx * 4];
            float am[8] = {aA.x, aA.y, aA.z, aA.w, aB.x, aB.y, aB.z, aB.w};
            float bn[8] = {bA.x, bA.y, bA.z, bA.w, bB.x, bB.y, bB.z, bB.w};
#pragma unroll
            for (int i = 0; i < 8; ++i)
#pragma unroll
                for (int j = 0; j < 8; ++j) acc[i][j] = fmaf(am[i], bn[j], acc[i][j]);
        }
    }

    float* cp0 = part + (size_t)(which * 8 + s) * T_SEQ * 128;
#pragma unroll
    for (int ih = 0; ih < 2; ++ih)
#pragma unroll
        for (int i = 0; i < 4; ++i) {
            const int row = m0 + ih * 64 + ty * 4 + i;
            float* cp = cp0 + (size_t)row * 128;
            float4 v0 = make_float4(acc[ih*4+i][0], acc[ih*4+i][1], acc[ih*4+i][2], acc[ih*4+i][3]);
            float4 v1 = make_float4(acc[ih*4+i][4], acc[ih*4+i][5], acc[ih*4+i][6], acc[ih*4+i][7]);
            *(float4*)(cp + tx * 4) = v0;
            *(float4*)(cp + 64 + tx * 4) = v1;
        }
}

// ---------------- K1: qik_splitk8 (heavy, first) + rope_table + proj_w + convert
__global__ __launch_bounds__(256) void pre_kernel(
    const float* __restrict__ x,
    const float* __restrict__ WIq, const float* __restrict__ WIk, const float* __restrict__ WIw,
    const float* __restrict__ Wq, const float* __restrict__ Wk, const float* __restrict__ Wv,
    const float* __restrict__ Wgv, const float* __restrict__ Wgo, const float* __restrict__ Wo,
    unsigned short* __restrict__ xb, unsigned short* __restrict__ Wcatb,
    unsigned short* __restrict__ Wob,
    float* __restrict__ part, float* __restrict__ wsig,
    float* __restrict__ cost, float* __restrict__ sint)
{
    __shared__ __align__(16) char smem[16896];
    const int b = blockIdx.x;
    if (b < 256) {
        qik_body(smem, b & 1, (b >> 1) & 7, b >> 4, x, WIq, WIk, part);
    } else if (b < 512) {
        rope_table_body(b - 256, cost, sint);
    } else if (b < 640) {
        proj_w_body(b - 512, x, WIw, wsig);
    } else {
        convert_body(b - 640, x, Wq, Wk, Wv, Wgv, Wgo, Wo, xb, Wcatb, Wob);
    }
}

__global__ void qik_reduce_kernel(const float* __restrict__ part,
                                  float* __restrict__ qI, float* __restrict__ kI)
{
    const int idx = blockIdx.x * 256 + threadIdx.x;   // 0..524287
    const int which = idx >> 18;
    const int e = idx & 262143;
    const float* p = part + (size_t)which * 8 * T_SEQ * 128 + e;
    float s = 0.f;
#pragma unroll
    for (int j = 0; j < 8; ++j) s += p[(size_t)j * T_SEQ * 128];
    (which ? kI : qI)[e] = s;
}

// ---------------- impA body: causal-tiled f32 GEMM -> packed-triangular imp ----
__device__ __forceinline__ void impA_body(
    char* smemc,
    const float* __restrict__ qI, const float* __restrict__ kI,
    const float* __restrict__ wsig, const float* __restrict__ gate_bias,
    float* __restrict__ imp, int t, int hi)
{
    float (*As)[132] = (float(*)[132])smemc;             // 16896 B
    float (*Bs)[132] = (float(*)[132])(smemc + 16896);   // 16896 B
    int qi = (int)((sqrtf(8.f * (float)t + 1.f) - 1.f) * 0.5f);
    if ((qi + 1) * (qi + 2) / 2 <= t) qi++;
    if (qi * (qi + 1) / 2 > t) qi--;
    const int ki = t - qi * (qi + 1) / 2;
    const int m0 = qi * 128;

    const int tid = threadIdx.x;
    const int tx = tid & 15, ty = tid >> 4;

    {
        const int sr = tid >> 1;
        const int sk = (tid & 1) * 16;
        const float4* Ap = (const float4*)(qI + (size_t)(m0 + sr) * 128 + hi * 32 + sk);
        const float4* Bp = (const float4*)(kI + (size_t)(ki * 128 + sr) * 128 + hi * 32 + sk);
#pragma unroll
        for (int j4 = 0; j4 < 4; ++j4) {
            float4 a = Ap[j4], b = Bp[j4];
            As[sk + j4*4 + 0][sr] = a.x; As[sk + j4*4 + 1][sr] = a.y;
            As[sk + j4*4 + 2][sr] = a.z; As[sk + j4*4 + 3][sr] = a.w;
            Bs[sk + j4*4 + 0][sr] = b.x; Bs[sk + j4*4 + 1][sr] = b.y;
            Bs[sk + j4*4 + 2][sr] = b.z; Bs[sk + j4*4 + 3][sr] = b.w;
        }
    }
    __syncthreads();

    float acc[8][8];
#pragma unroll
    for (int i = 0; i < 8; ++i)
#pragma unroll
        for (int j = 0; j < 8; ++j) acc[i][j] = 0.f;

#pragma unroll
    for (int kk = 0; kk < 32; ++kk) {
        float4 aA = *(const float4*)&As[kk][ty * 4];
        float4 aB = *(const float4*)&As[kk][64 + ty * 4];
        float4 bA = *(const float4*)&Bs[kk][tx * 4];
        float4 bB = *(const float4*)&Bs[kk][64 + tx * 4];
        float am[8] = {aA.x, aA.y, aA.z, aA.w, aB.x, aB.y, aB.z, aB.w};
        float bn[8] = {bA.x, bA.y, bA.z, bA.w, bB.x, bB.y, bB.z, bB.w};
#pragma unroll
        for (int i = 0; i < 8; ++i)
#pragma unroll
            for (int j = 0; j < 8; ++j) acc[i][j] = fmaf(am[i], bn[j], acc[i][j]);
    }

    const float gb = gate_bias[hi];
    const size_t rw = (size_t)(qi + 1) * 128;
    float* impb = imp + (size_t)hi * IMPH + (size_t)16384 * (qi * (qi + 1) / 2) + ki * 128;
#pragma unroll
    for (int ih = 0; ih < 2; ++ih)
#pragma unroll
        for (int i = 0; i < 4; ++i) {
            const int rr = ih * 64 + ty * 4 + i;
            const float wr = wsig[(m0 + rr) * 4 + hi];
            float* cp = impb + (size_t)rr * rw;
            float4 v0, v1;
            v0.x = wr * sigf(acc[ih*4+i][0] + gb);
            v0.y = wr * sigf(acc[ih*4+i][1] + gb);
            v0.z = wr * sigf(acc[ih*4+i][2] + gb);
            v0.w = wr * sigf(acc[ih*4+i][3] + gb);
            v1.x = wr * sigf(acc[ih*4+i][4] + gb);
            v1.y = wr * sigf(acc[ih*4+i][5] + gb);
            v1.z = wr * sigf(acc[ih*4+i][6] + gb);
            v1.w = wr * sigf(acc[ih*4+i][7] + gb);
            *(float4*)(cp + tx * 4) = v0;
            *(float4*)(cp + 64 + tx * 4) = v1;
        }
}

// ---------------- K3: proj-GEMM (bf16 out) then impA (contiguous tiles) --------
__global__ __launch_bounds__(256) void mid_kernel(
    const unsigned short* __restrict__ xb, const unsigned short* __restrict__ Wcatb,
    unsigned short* __restrict__ lincatb,
    const float* __restrict__ qI, const float* __restrict__ kI,
    const float* __restrict__ wsig, const float* __restrict__ gate_bias,
    float* __restrict__ imp)
{
    __shared__ __align__(16) char smem[33792];
    const int b = blockIdx.x;
    if (b < 640) {
        gemm_body<true>(smem, xb, Wcatb, lincatb, NCAT, b % 40, b / 40);
    } else {
        const int bb = b - 640;
        impA_body(smem, qI, kI, wsig, gate_bias, imp, bb % 136, bb / 136);
    }
}

// ---------------- impB body: var -> k_t, threshold binary search, emission ----
template<int NC>
__device__ __forceinline__ void impB_body(
    const float* __restrict__ imp, const float* __restrict__ head_bias,
    unsigned short* __restrict__ sidxg, unsigned* __restrict__ cnts,
    int q, int hi, int lane)
{
    const int qc = q >> 6;   // last causal chunk (wave-uniform)
    const unsigned long long lmask_lt = (lane == 0) ? 0ull : ((~0ull) >> (64 - lane));

    const int qi = q >> 7;
    const size_t rw = (size_t)(qi + 1) * 128;
    const float* row = imp + (size_t)hi * IMPH +
                       (size_t)16384 * (qi * (qi + 1) / 2) + (size_t)(q - qi * 128) * rw;

    unsigned ordv[NC];
    double dsum = 0.0, dsq = 0.0;
#pragma unroll
    for (int i = 0; i < NC; ++i) {
        const int k = i * 64 + lane;
        unsigned vb = 0u;
        if (i <= qc) {
            const float v = row[k];
            const bool causal = (k <= q);
            const float vm = causal ? v : 0.f;
            dsum += (double)vm;
            dsq  += (double)vm * (double)vm;
            vb = causal ? __float_as_uint(v) : 0u;
        }
        if (i == 0 && lane < SINKN) vb = 0x7F800000u;
        ordv[i] = vb;
    }

#pragma unroll
    for (int off = 1; off < 64; off <<= 1) {
        dsum += __shfl_xor(dsum, off);
        dsq  += __shfl_xor(dsq, off);
    }

    int kts[4];
#pragma unroll
    for (int j = 0; j < 4; ++j) {
        const float sh = sigf(head_bias[hi * 4 + j]);
        const double mean = dsum / (double)T_SEQ;
        double var = dsq / (double)T_SEQ - mean * mean;
        if (var < 0.0) var = 0.0;
        const double vh = var * (double)sh * (double)sh;
        int kt = (int)floor(512.0 * vh);
        kt = kt < KMINV ? KMINV : (kt > KMAXV ? KMAXV : kt);
        kts[j] = kt;
    }

    unsigned vs[4]; int tt[4];
#pragma unroll
    for (int j = 0; j < 4; ++j) {
        bool dup = false;
#pragma unroll
        for (int p = 0; p < 4; ++p) {
            if (p < j && !dup && kts[p] == kts[j]) { vs[j] = vs[p]; tt[j] = tt[p]; dup = true; }
        }
        if (!dup) {
            const int kt = kts[j];
            unsigned X = 0;
#pragma unroll 1
            for (int b = 30; b >= 0; --b) {
                const unsigned Xt = X | (1u << b);
                int c = 0;
#pragma unroll
                for (int i = 0; i < NC; ++i)
                    c += (int)__popcll(__ballot(ordv[i] >= Xt));
                if (c >= kt) X = Xt;
            }
            int cg = 0;
#pragma unroll
            for (int i = 0; i < NC; ++i)
                cg += (int)__popcll(__ballot(ordv[i] > X));
            vs[j] = X; tt[j] = kt - cg;
        }
    }

    unsigned cnt = 0;
    unsigned short* sp = sidxg + ((size_t)hi * T_SEQ + q) * KMAXV;
    const bool uni = (kts[0] == kts[1]) && (kts[1] == kts[2]) && (kts[2] == kts[3]);

    if (uni) {
        int eqr = 0;
        const unsigned v0 = vs[0]; const int t0 = tt[0];
#pragma unroll
        for (int i = 0; i < NC; ++i) {
            const int k = i * 64 + lane;
            const unsigned x = ordv[i];
            const bool eq = (x == v0);
            const unsigned long long beq = __ballot(eq);
            const bool sel = (x > v0) || (eq && (eqr + (int)__popcll(beq & lmask_lt) < t0));
            eqr += (int)__popcll(beq);
            const bool valid = (k <= q) && sel;
            const unsigned long long bv = __ballot(valid);
            if (valid) {
                const unsigned pos = cnt + (unsigned)__popcll(bv & lmask_lt);
                if (pos < KMAXV) sp[pos] = (unsigned short)((unsigned)k | (0xFu << 11));
            }
            cnt += (unsigned)__popcll(bv);
        }
    } else {
        int eqr0 = 0, eqr1 = 0, eqr2 = 0, eqr3 = 0;
#pragma unroll
        for (int i = 0; i < NC; ++i) {
            const int k = i * 64 + lane;
            const unsigned x = ordv[i];
            unsigned mask = 0;
            {
                const bool eq = (x == vs[0]);
                const unsigned long long beq = __ballot(eq);
                const bool sel = (x > vs[0]) || (eq && (eqr0 + (int)__popcll(beq & lmask_lt) < tt[0]));
                eqr0 += (int)__popcll(beq);
                if (sel) mask |= 1u;
            }
            {
                const bool eq = (x == vs[1]);
                const unsigned long long beq = __ballot(eq);
                const bool sel = (x > vs[1]) || (eq && (eqr1 + (int)__popcll(beq & lmask_lt) < tt[1]));
                eqr1 += (int)__popcll(beq);
                if (sel) mask |= 2u;
            }
            {
                const bool eq = (x == vs[2]);
                const unsigned long long beq = __ballot(eq);
                const bool sel = (x > vs[2]) || (eq && (eqr2 + (int)__popcll(beq & lmask_lt) < tt[2]));
                eqr2 += (int)__popcll(beq);
                if (sel) mask |= 4u;
            }
            {
                const bool eq = (x == vs[3]);
                const unsigned long long beq = __ballot(eq);
                const bool sel = (x > vs[3]) || (eq && (eqr3 + (int)__popcll(beq & lmask_lt) < tt[3]));
                eqr3 += (int)__popcll(beq);
                if (sel) mask |= 8u;
            }
            const bool valid = (k <= q) && (mask != 0u);
            const unsigned long long bv = __ballot(valid);
            if (valid) {
                const unsigned pos = cnt + (unsigned)__popcll(bv & lmask_lt);
                if (pos < KMAXV) sp[pos] = (unsigned short)((unsigned)k | (mask << 11));
            }
            cnt += (unsigned)__popcll(bv);
        }
    }
    if (lane == 0) cnts[(size_t)hi * T_SEQ + q] = cnt < KMAXV ? cnt : KMAXV;
}

__device__ __forceinline__ void rope_v_body(
    int b, const unsigned short* __restrict__ lincatb,
    const float* __restrict__ cost, const float* __restrict__ sint,
    float* __restrict__ Q, unsigned short* __restrict__ Kb, unsigned short* __restrict__ Vb)
{
    const int idx = b * 256 + threadIdx.x;   // (t*16+h)*32 + i
    const int i = idx & 31;
    const int h = (idx >> 5) & 15;
    const int t = idx >> 9;
    const float cv = cost[t * 32 + i], sv = sint[t * 32 + i];
    const size_t src = (size_t)t * NCAT + h * HD + 2 * i;
    const ushort2 q2 = *(const ushort2*)(lincatb + src);
    const ushort2 k2 = *(const ushort2*)(lincatb + src + 1024);
    const ushort2 v2 = *(const ushort2*)(lincatb + src + 2048);
    const ushort2 g2 = *(const ushort2*)(lincatb + src + 3072);
    const float qx = bf16f(q2.x), qy = bf16f(q2.y);
    const float kx = bf16f(k2.x), ky = bf16f(k2.y);
    const float vx = bf16f(v2.x), vy = bf16f(v2.y);
    const float gx = bf16f(g2.x), gy = bf16f(g2.y);
    const size_t dst = ((size_t)h * T_SEQ + t) * HD;
    Q[dst + i]      = qx * cv - qy * sv;
    Q[dst + 32 + i] = qx * sv + qy * cv;
    Kb[dst + i]      = f2bf(kx * cv - ky * sv);
    Kb[dst + 32 + i] = f2bf(kx * sv + ky * cv);
    ushort2 vo;
    vo.x = f2bf(vx * sigf(gx));
    vo.y = f2bf(vy * sigf(gy));
    *(ushort2*)(Vb + dst + 2 * i) = vo;
}

// ---------------- K4: impB (LPT bands first) + rope_v -------------------------
__global__ __launch_bounds__(256) void sel_kernel(
    const float* __restrict__ imp, const float* __restrict__ head_bias,
    unsigned short* __restrict__ sidxg, unsigned* __restrict__ cnts,
    const unsigned short* __restrict__ lincatb,
    const float* __restrict__ cost, const float* __restrict__ sint,
    float* __restrict__ Q, unsigned short* __restrict__ Kb, unsigned short* __restrict__ Vb)
{
    const int b = blockIdx.x;
    if (b < 2048) {
        const int bx = b & 511;
        const int hi = b >> 9;
        const int wv = threadIdx.x >> 6;
        const int lane = threadIdx.x & 63;
        const int band = 7 - (bx >> 6);   // LPT: heaviest first
        const int bxx = bx & 63;
        const int q = band * 256 + bxx * 4 + wv;
        switch (band) {
            case 0:  impB_body< 4>(imp, head_bias, sidxg, cnts, q, hi, lane); break;
            case 1:  impB_body< 8>(imp, head_bias, sidxg, cnts, q, hi, lane); break;
            case 2:  impB_body<12>(imp, head_bias, sidxg, cnts, q, hi, lane); break;
            case 3:  impB_body<16>(imp, head_bias, sidxg, cnts, q, hi, lane); break;
            case 4:  impB_body<20>(imp, head_bias, sidxg, cnts, q, hi, lane); break;
            case 5:  impB_body<24>(imp, head_bias, sidxg, cnts, q, hi, lane); break;
            case 6:  impB_body<28>(imp, head_bias, sidxg, cnts, q, hi, lane); break;
            default: impB_body<32>(imp, head_bias, sidxg, cnts, q, hi, lane); break;
        }
    } else {
        rope_v_body(b - 2048, lincatb, cost, sint, Q, Kb, Vb);
    }
}

// ---------------- sparse gather attention: 2 queries per wave, bf16 K/V -------
__global__ __launch_bounds__(256) void attn_sparse_kernel(
    const float* __restrict__ Q, const unsigned short* __restrict__ Kb,
    const unsigned short* __restrict__ Vb,
    const unsigned short* __restrict__ sidx, const unsigned* __restrict__ cnts,
    const unsigned short* __restrict__ lincatb, unsigned short* __restrict__ ogb)
{
    const int orig = blockIdx.x + (blockIdx.y << 8);          // gridDim = (256,16)
    const int c = ((orig & 7) << 9) | (orig >> 3);            // XCD j -> heads 2j,2j+1
    const int h = c >> 8;
    const int qt = c & 255;
    const int hi = h >> 2, hj = h & 3;
    const int wv = threadIdx.x >> 6;
    const int lane = threadIdx.x & 63;
    const int qh = lane >> 5;         // query within pair
    const int l32 = lane & 31;
    const int kk = l32 >> 2;          // key slot 0..7
    const int dg = lane & 3;          // dim group 0..3
    const int q = qt * 8 + wv * 2 + qh;

    const size_t hq = (size_t)hi * T_SEQ + q;
    const int nv = (int)cnts[hq];
    const int nvm = max(nv, __shfl_xor(nv, 32));   // wave-uniform path choice
    const unsigned short* sp = sidx + hq * KMAXV;
    const unsigned short* Kh = Kb + (size_t)h * T_SEQ * HD + dg * 16;
    const unsigned short* Vh = Vb + (size_t)h * T_SEQ * HD + dg * 16;

    float4 qg[4];
    {
        const float4* qp = (const float4*)(Q + ((size_t)h * T_SEQ + q) * HD + dg * 16);
        qg[0] = qp[0]; qg[1] = qp[1]; qg[2] = qp[2]; qg[3] = qp[3];
    }

    float acc[16];
#pragma unroll
    for (int i = 0; i < 16; ++i) acc[i] = 0.f;
    float l = 0.f;

    if (nvm <= 32) {
        const ushort4 e4 = *(const ushort4*)(sp + kk * 4);
        const unsigned ev[4] = {e4.x, e4.y, e4.z, e4.w};

        float s[4]; int idxs[4];
#pragma unroll
        for (int sub = 0; sub < 4; ++sub) {
            const int kpos = kk * 4 + sub;
            const unsigned e = ev[sub];
            const bool ok = (kpos < nv) && ((e >> (11 + hj)) & 1u);
            const int iv = ok ? (int)(e & 0x7FFu) : 0;
            idxs[sub] = iv;
            const uint4* kr = (const uint4*)(Kh + (size_t)iv * HD);
            uint4 ka = kr[0], kb2 = kr[1];
            float da = 0.f, db = 0.f;
            da = fmaf(qg[0].x, bflo(ka.x), da); da = fmaf(qg[0].y, bfhi(ka.x), da);
            da = fmaf(qg[0].z, bflo(ka.y), da); da = fmaf(qg[0].w, bfhi(ka.y), da);
            db = fmaf(qg[1].x, bflo(ka.z), db); db = fmaf(qg[1].y, bfhi(ka.z), db);
            db = fmaf(qg[1].z, bflo(ka.w), db); db = fmaf(qg[1].w, bfhi(ka.w), db);
            da = fmaf(qg[2].x, bflo(kb2.x), da); da = fmaf(qg[2].y, bfhi(kb2.x), da);
            da = fmaf(qg[2].z, bflo(kb2.y), da); da = fmaf(qg[2].w, bfhi(kb2.y), da);
            db = fmaf(qg[3].x, bflo(kb2.z), db); db = fmaf(qg[3].y, bfhi(kb2.z), db);
            db = fmaf(qg[3].z, bflo(kb2.w), db); db = fmaf(qg[3].w, bfhi(kb2.w), db);
            float dot = da + db;
            dot += __shfl_xor(dot, 1);
            dot += __shfl_xor(dot, 2);
            s[sub] = ok ? dot * 0.125f : -INFINITY;
        }

        float cm = fmaxf(fmaxf(s[0], s[1]), fmaxf(s[2], s[3]));
        cm = fmaxf(cm, __shfl_xor(cm, 4));
        cm = fmaxf(cm, __shfl_xor(cm, 8));
        cm = fmaxf(cm, __shfl_xor(cm, 16));

        float p[4];
        float ls = 0.f;
#pragma unroll
        for (int sub = 0; sub < 4; ++sub) { p[sub] = expf(s[sub] - cm); ls += p[sub]; }
        ls += __shfl_xor(ls, 4);
        ls += __shfl_xor(ls, 8);
        ls += __shfl_xor(ls, 16);
        l = ls;
#pragma unroll
        for (int sub = 0; sub < 4; ++sub) {
            const float pv = p[sub];                         // 0 for masked
            const uint4* vr = (const uint4*)(Vh + (size_t)idxs[sub] * HD);
            uint4 va = vr[0], vb4 = vr[1];
            acc[0]  = fmaf(pv, bflo(va.x), acc[0]);   acc[1]  = fmaf(pv, bfhi(va.x), acc[1]);
            acc[2]  = fmaf(pv, bflo(va.y), acc[2]);   acc[3]  = fmaf(pv, bfhi(va.y), acc[3]);
            acc[4]  = fmaf(pv, bflo(va.z), acc[4]);   acc[5]  = fmaf(pv, bfhi(va.z), acc[5]);
            acc[6]  = fmaf(pv, bflo(va.w), acc[6]);   acc[7]  = fmaf(pv, bfhi(va.w), acc[7]);
            acc[8]  = fmaf(pv, bflo(vb4.x), acc[8]);  acc[9]  = fmaf(pv, bfhi(vb4.x), acc[9]);
            acc[10] = fmaf(pv, bflo(vb4.y), acc[10]); acc[11] = fmaf(pv, bfhi(vb4.y), acc[11]);
            acc[12] = fmaf(pv, bflo(vb4.z), acc[12]); acc[13] = fmaf(pv, bfhi(vb4.z), acc[13]);
            acc[14] = fmaf(pv, bflo(vb4.w), acc[14]); acc[15] = fmaf(pv, bfhi(vb4.w), acc[15]);
        }
    } else {
        float m = -INFINITY;
        for (int base = 0; base < nvm; base += 32) {
            const int nk = nv - base;
            const ushort4 e4 = *(const ushort4*)(sp + base + kk * 4);
            const unsigned ev[4] = {e4.x, e4.y, e4.z, e4.w};

            float s[4]; int idxs[4];
#pragma unroll
            for (int sub = 0; sub < 4; ++sub) {
                const int kpos = kk * 4 + sub;
                const unsigned e = ev[sub];
                const bool ok = (kpos < nk) && ((e >> (11 + hj)) & 1u);
                const int iv = ok ? (int)(e & 0x7FFu) : 0;
                idxs[sub] = iv;
                const uint4* kr = (const uint4*)(Kh + (size_t)iv * HD);
                uint4 ka = kr[0], kb2 = kr[1];
                float da = 0.f, db = 0.f;
                da = fmaf(qg[0].x, bflo(ka.x), da); da = fmaf(qg[0].y, bfhi(ka.x), da);
                da = fmaf(qg[0].z, bflo(ka.y), da); da = fmaf(qg[0].w, bfhi(ka.y), da);
                db = fmaf(qg[1].x, bflo(ka.z), db); db = fmaf(qg[1].y, bfhi(ka.z), db);
                db = fmaf(qg[1].z, bflo(ka.w), db); db = fmaf(qg[1].w, bfhi(ka.w), db);
                da = fmaf(qg[2].x, bflo(kb2.x), da); da = fmaf(qg[2].y, bfhi(kb2.x), da);
                da = fmaf(qg[2].z, bflo(kb2.y), da); da = fmaf(qg[2].w, bfhi(kb2.y), da);
                db = fmaf(qg[3].x, bflo(kb2.z), db); db = fmaf(qg[3].y, bfhi(kb2.z), db);
                db = fmaf(qg[3].z, bflo(kb2.w), db); db = fmaf(qg[3].w, bfhi(kb2.w), db);
                float dot = da + db;
                dot += __shfl_xor(dot, 1);
                dot += __shfl_xor(dot, 2);
                s[sub] = ok ? dot * 0.125f : -INFINITY;
            }

            float cm = fmaxf(fmaxf(s[0], s[1]), fmaxf(s[2], s[3]));
            cm = fmaxf(cm, __shfl_xor(cm, 4));
            cm = fmaxf(cm, __shfl_xor(cm, 8));
            cm = fmaxf(cm, __shfl_xor(cm, 16));
            const float mn = fmaxf(m, cm);
            if (mn > -INFINITY) {
                const float alpha = expf(m - mn);
                float p[4];
                float ls = 0.f;
#pragma unroll
                for (int sub = 0; sub < 4; ++sub) { p[sub] = expf(s[sub] - mn); ls += p[sub]; }
                ls += __shfl_xor(ls, 4);
                ls += __shfl_xor(ls, 8);
                ls += __shfl_xor(ls, 16);
                l = l * alpha + ls;
#pragma unroll
                for (int i = 0; i < 16; ++i) acc[i] *= alpha;
#pragma unroll
                for (int sub = 0; sub < 4; ++sub) {
                    const float pv = p[sub];
                    const uint4* vr = (const uint4*)(Vh + (size_t)idxs[sub] * HD);
                    uint4 va = vr[0], vb4 = vr[1];
                    acc[0]  = fmaf(pv, bflo(va.x), acc[0]);   acc[1]  = fmaf(pv, bfhi(va.x), acc[1]);
                    acc[2]  = fmaf(pv, bflo(va.y), acc[2]);   acc[3]  = fmaf(pv, bfhi(va.y), acc[3]);
                    acc[4]  = fmaf(pv, bflo(va.z), acc[4]);   acc[5]  = fmaf(pv, bfhi(va.z), acc[5]);
                    acc[6]  = fmaf(pv, bflo(va.w), acc[6]);   acc[7]  = fmaf(pv, bfhi(va.w), acc[7]);
                    acc[8]  = fmaf(pv, bflo(vb4.x), acc[8]);  acc[9]  = fmaf(pv, bfhi(vb4.x), acc[9]);
                    acc[10] = fmaf(pv, bflo(vb4.y), acc[10]); acc[11] = fmaf(pv, bfhi(vb4.y), acc[11]);
                    acc[12] = fmaf(pv, bflo(vb4.z), acc[12]); acc[13] = fmaf(pv, bfhi(vb4.z), acc[13]);
                    acc[14] = fmaf(pv, bflo(vb4.w), acc[14]); acc[15] = fmaf(pv, bfhi(vb4.w), acc[15]);
                }
                m = mn;
            }
        }
    }

#pragma unroll
    for (int i = 0; i < 16; ++i) {
        acc[i] += __shfl_xor(acc[i], 4);
        acc[i] += __shfl_xor(acc[i], 8);
        acc[i] += __shfl_xor(acc[i], 16);
    }
    const float invl = 1.f / l;
    float oval0 = acc[0], oval1 = acc[1];
#pragma unroll
    for (int i = 1; i < 8; ++i)
        if (kk == i) { oval0 = acc[2 * i]; oval1 = acc[2 * i + 1]; }
    const int d0 = dg * 16 + kk * 2;
    const ushort2 g2 = *(const ushort2*)(lincatb + (size_t)q * NCAT + 4096 + h * HD + d0);
    ushort2 o2;
    o2.x = f2bf(oval0 * invl * sigf(bf16f(g2.x)));
    o2.y = f2bf(oval1 * invl * sigf(bf16f(g2.y)));
    *(ushort2*)(ogb + (size_t)q * C_DIM + h * HD + d0) = o2;
}

extern "C" void kernel_launch(void* const* d_in, const int* in_sizes, int n_in,
                              void* d_out, int out_size, void* d_ws, size_t ws_size,
                              hipStream_t stream)
{
    const float* x   = (const float*)d_in[0];
    const float* WIq = (const float*)d_in[1];
    const float* WIk = (const float*)d_in[2];
    const float* WIw = (const float*)d_in[3];
    const float* gb  = (const float*)d_in[4];
    const float* hib = (const float*)d_in[5];
    const float* Wq  = (const float*)d_in[6];
    const float* Wk  = (const float*)d_in[7];
    const float* Wv  = (const float*)d_in[8];
    const float* Wgv = (const float*)d_in[9];
    const float* Wgo = (const float*)d_in[10];
    const float* Wo  = (const float*)d_in[11];
    float* out = (float*)d_out;

    char* ws = (char*)d_ws;
    const size_t MB = 1024 * 1024;
    float*    qI     = (float*)(ws + 0 * MB);                 // 1 MB
    float*    kI     = (float*)(ws + 1 * MB);                 // 1 MB
    float*    wsig   = (float*)(ws + 2 * MB);                 // 32 KB
    unsigned* cnts   = (unsigned*)(ws + 2 * MB + 64 * 1024);  // 32 KB
    float*    cost   = (float*)(ws + 2 * MB + 512 * 1024);    // 256 KB
    float*    sint   = (float*)(ws + 2 * MB + 768 * 1024);    // 256 KB
    float*    Q      = (float*)(ws + 3 * MB);                 // 8 MB  -> 11
    unsigned short* Kb = (unsigned short*)(ws + 11 * MB);     // 4 MB  -> 15
    unsigned short* Vb = (unsigned short*)(ws + 15 * MB);     // 4 MB  -> 19
    unsigned short* sidx = (unsigned short*)(ws + 19 * MB);   // 16 MB -> 35
    // region A (35..71): part (16 MB, K1 write / K2 read) -> imp (35.7 MB, K3 write / K4 read)
    float*    part    = (float*)(ws + 35 * MB);
    float*    imp     = (float*)(ws + 35 * MB);
    unsigned short* lincatb = (unsigned short*)(ws + 71 * MB);// 20 MB -> 91 (written K3)
    unsigned short* ogb   = (unsigned short*)(ws + 91 * MB);  // 4 MB  -> 95
    unsigned short* xb    = (unsigned short*)(ws + 95 * MB);  // 4 MB  -> 99
    unsigned short* Wcatb = (unsigned short*)(ws + 99 * MB);  // 10 MB -> 109
    unsigned short* Wob   = (unsigned short*)(ws + 109 * MB); // 2 MB  -> 111

    // K1: qik_splitk8 (heavy first) + rope_table + proj_w + convert_all
    pre_kernel<<<dim3(8832), 256, 0, stream>>>(
        x, WIq, WIk, WIw, Wq, Wk, Wv, Wgv, Wgo, Wo,
        xb, Wcatb, Wob, part, wsig, cost, sint);
    // K2
    qik_reduce_kernel<<<dim3(2048), 256, 0, stream>>>(part, qI, kI);
    // K3: proj-GEMM (bf16 out) then impA (contiguous GEMM tiles for L2 locality)
    mid_kernel<<<dim3(1184), 256, 0, stream>>>(
        xb, Wcatb, lincatb, qI, kI, wsig, gb, imp);
    // K4: impB + rope_v
    sel_kernel<<<dim3(6144), 256, 0, stream>>>(
        imp, hib, sidx, cnts, lincatb, cost, sint, Q, Kb, Vb);
    // attention + out-projection
    attn_sparse_kernel<<<dim3(256, 16), 256, 0, stream>>>(Q, Kb, Vb, sidx, cnts, lincatb, ogb);
    gemm_out_kernel<<<dim3(8, 16), 256, 0, stream>>>(ogb, Wob, out, C_DIM);
}

// Round 24
// 160.587 us; speedup vs baseline: 1.0351x; 1.0232x over previous
//
#include <hip/hip_runtime.h>
#include <math.h>

#define T_SEQ 2048
#define C_DIM 1024
#define NH    16
#define HD    64
#define HIN   4
#define DI    32
#define SINKN 4
#define KMINV 32
#define KMAXV 1024
#define NCAT  5120   // q|k|v|gv|go concatenated columns
#define IMPH  2228224 // packed-triangular imp floats per indexer head

typedef __bf16 bf16x8 __attribute__((ext_vector_type(8)));
typedef float  f32x4  __attribute__((ext_vector_type(4)));

__device__ __forceinline__ float sigf(float x) { return 1.f / (1.f + expf(-x)); }

__device__ __forceinline__ unsigned short f2bf(float f) {
    unsigned u = __float_as_uint(f);
    unsigned r = (u + 0x7FFFu + ((u >> 16) & 1u)) >> 16;   // RNE
    return (unsigned short)r;
}

__device__ __forceinline__ float bflo(unsigned u) { return __uint_as_float(u << 16); }
__device__ __forceinline__ float bfhi(unsigned u) { return __uint_as_float(u & 0xFFFF0000u); }
__device__ __forceinline__ float bf16f(unsigned short u) { return __uint_as_float((unsigned)u << 16); }

__device__ __forceinline__ void gload16(const unsigned short* g, unsigned short* l) {
    __builtin_amdgcn_global_load_lds(
        (const __attribute__((address_space(1))) unsigned int*)(const unsigned int*)g,
        (__attribute__((address_space(3))) unsigned int*)(unsigned int*)l,
        16, 0, 0);
}

// ---------------- bf16 MFMA GEMM body: C = A_bf16 @ B_bf16^T ------------------
template<bool OUT_BF16>
__device__ __forceinline__ void gemm_body(
    char* smemc,
    const unsigned short* __restrict__ A, const unsigned short* __restrict__ B,
    void* __restrict__ Cv, int ldc, int bx, int by)
{
    unsigned short* Asl = (unsigned short*)smemc;          // 16384 B
    unsigned short* Bsl = (unsigned short*)(smemc + 16384);// 16384 B
    const int K = C_DIM;
    const int tid = threadIdx.x;
    const int w = tid >> 6, lane = tid & 63;
    const int wm = w >> 1, wn = w & 1;
    const int m0 = by * 128, n0 = bx * 128;

    const f32x4 z4 = {0.f, 0.f, 0.f, 0.f};
    f32x4 acc[4][4];
#pragma unroll
    for (int i = 0; i < 4; ++i)
#pragma unroll
        for (int j = 0; j < 4; ++j) acc[i][j] = z4;

    const int lrow  = w * 8 + (lane >> 3);
    const int lslot = (lane & 7) ^ (lane >> 3);
    const unsigned short* Ag = A + (size_t)(m0 + lrow) * K + lslot * 8;
    const unsigned short* Bg = B + (size_t)(n0 + lrow) * K + lslot * 8;

    const int fr = lane & 15;
    const int kg = lane >> 4;

    for (int kt = 0; kt < K; kt += 64) {
        __syncthreads();
#pragma unroll
        for (int i = 0; i < 4; ++i) {
            gload16(Ag + (size_t)(i * 32) * K + kt, &Asl[(i * 32 + w * 8) * 64]);
            gload16(Bg + (size_t)(i * 32) * K + kt, &Bsl[(i * 32 + w * 8) * 64]);
        }
        __syncthreads();
#pragma unroll
        for (int ks = 0; ks < 2; ++ks) {
            bf16x8 af[4], bfr[4];
            const int aslot = ks * 4 + kg;
#pragma unroll
            for (int f = 0; f < 4; ++f) {
                const int arow = wm * 64 + f * 16 + fr;
                af[f] = *(const bf16x8*)&Asl[arow * 64 + ((aslot ^ (arow & 7)) * 8)];
                const int brow = wn * 64 + f * 16 + fr;
                bfr[f] = *(const bf16x8*)&Bsl[brow * 64 + ((aslot ^ (brow & 7)) * 8)];
            }
#pragma unroll
            for (int mi = 0; mi < 4; ++mi)
#pragma unroll
                for (int ni = 0; ni < 4; ++ni)
                    acc[mi][ni] = __builtin_amdgcn_mfma_f32_16x16x32_bf16(
                        af[mi], bfr[ni], acc[mi][ni], 0, 0, 0);
        }
    }

#pragma unroll
    for (int mi = 0; mi < 4; ++mi) {
        const int row = by * 128 + wm * 64 + mi * 16 + (lane >> 4) * 4;
#pragma unroll
        for (int ni = 0; ni < 4; ++ni) {
            const int col = bx * 128 + wn * 64 + ni * 16 + (lane & 15);
            if constexpr (OUT_BF16) {
                unsigned short* cp = (unsigned short*)Cv + (size_t)row * ldc + col;
#pragma unroll
                for (int r = 0; r < 4; ++r) cp[(size_t)r * ldc] = f2bf(acc[mi][ni][r]);
            } else {
                float* cp = (float*)Cv + (size_t)row * ldc + col;
#pragma unroll
                for (int r = 0; r < 4; ++r) cp[(size_t)r * ldc] = acc[mi][ni][r];
            }
        }
    }
}

// standalone final out-projection (f32 out)
__global__ __launch_bounds__(256) void gemm_out_kernel(
    const unsigned short* __restrict__ A, const unsigned short* __restrict__ B,
    float* __restrict__ C, int ldc)
{
    __shared__ __align__(16) char smem[32768];
    gemm_body<false>(smem, A, B, C, ldc, blockIdx.x, blockIdx.y);
}

// ---------------- component bodies ---------------------------------------------
__device__ __forceinline__ void convert_body(
    int b, const float* __restrict__ x,
    const float* __restrict__ Wq, const float* __restrict__ Wk, const float* __restrict__ Wv,
    const float* __restrict__ Wgv, const float* __restrict__ Wgo, const float* __restrict__ Wo,
    unsigned short* __restrict__ xb, unsigned short* __restrict__ Wcatb,
    unsigned short* __restrict__ Wob)
{
    const float* s; unsigned short* d; size_t off;
    if (b < 2048)      { s = x;  d = xb;  off = (size_t)b * 1024; }
    else if (b < 7168) {
        const int wsel = (b - 2048) >> 10;
        switch (wsel) {
            case 0: s = Wq;  break;
            case 1: s = Wk;  break;
            case 2: s = Wv;  break;
            case 3: s = Wgv; break;
            default: s = Wgo; break;
        }
        d = Wcatb + ((size_t)wsel << 20);
        off = (size_t)((b - 2048) & 1023) * 1024;
    } else             { s = Wo; d = Wob; off = (size_t)(b - 7168) * 1024; }

    const size_t i = off + threadIdx.x * 4;
    const float4 v = *(const float4*)(s + i);
    ushort4 o;
    o.x = f2bf(v.x); o.y = f2bf(v.y); o.z = f2bf(v.z); o.w = f2bf(v.w);
    *(ushort4*)(d + i) = o;
}

__device__ __forceinline__ void proj_w_body(
    int b, const float* __restrict__ x, const float* __restrict__ WIw,
    float* __restrict__ wsig)
{
    const int idx4 = b * 256 + threadIdx.x;
    const int part4 = idx4 & 3;
    const int oidx = idx4 >> 2;      // t*4 + hi
    const int t = oidx >> 2, hi = oidx & 3;
    const float4* xr = (const float4*)(x + (size_t)t * C_DIM + part4 * 256);
    const float4* wr = (const float4*)(WIw + (size_t)hi * C_DIM + part4 * 256);
    float s = 0.f;
#pragma unroll
    for (int i = 0; i < 64; ++i) {
        float4 a = xr[i], w4 = wr[i];
        s += a.x * w4.x + a.y * w4.y + a.z * w4.z + a.w * w4.w;
    }
    s += __shfl_xor(s, 1);
    s += __shfl_xor(s, 2);
    if (part4 == 0) wsig[oidx] = sigf(s);
}

__device__ __forceinline__ void rope_table_body(
    int b, float* __restrict__ cost, float* __restrict__ sint)
{
    const int idx = b * 256 + threadIdx.x;   // t*32 + i
    const int t = idx >> 5, i = idx & 31;
    const int j = (2 * i) & 31;
    const float invf = powf(10000.f, -(float)j / 32.f);
    const float f = (float)t * invf;
    float sv, cv;
    sincosf(f, &sv, &cv);
    cost[idx] = cv;
    sint[idx] = sv;
}

// split-K 8 + split-M 64: 32 mt x 2 which x 8 s = 512 blocks (2/CU).
// Summation order per output element is BITWISE IDENTICAL to the r21 kernel
// (same k-chunk, same kk order, same fmaf chain) - only thread->row mapping
// changes, so absmax is guaranteed unchanged (unlike the r22 K-split).
__device__ __forceinline__ void qik_body(
    char* smemc, int which, int s, int mt,
    const float* __restrict__ x, const float* __restrict__ WIq, const float* __restrict__ WIk,
    float* __restrict__ part)
{
    float (*As)[68]  = (float(*)[68])smemc;              // 16*68*4  = 4352 B
    float (*Bs)[132] = (float(*)[132])(smemc + 4352);    // 16*132*4 = 8448 B
    const float* B = which ? WIk : WIq;
    const int m0 = mt * 64;
    const int kb = s * 128;
    const int tid = threadIdx.x;
    const int tx = tid & 15, ty = tid >> 4;

    float acc[4][8];
#pragma unroll
    for (int i = 0; i < 4; ++i)
#pragma unroll
        for (int j = 0; j < 8; ++j) acc[i][j] = 0.f;

    const int srA = tid >> 2;            // 0..63
    const int skA = (tid & 3) * 4;       // 0,4,8,12
    const int srB = tid >> 1;            // 0..127
    const int skB = (tid & 1) * 8;       // 0,8
    const float* Ap = x + (size_t)(m0 + srA) * C_DIM + kb + skA;
    const float* Bp = B + (size_t)srB * C_DIM + kb + skB;

    for (int k0 = 0; k0 < 128; k0 += 16) {
        float4 a0 = *(const float4*)(Ap + k0);
        float4 b0 = *(const float4*)(Bp + k0);
        float4 b1 = *(const float4*)(Bp + k0 + 4);
        __syncthreads();
        As[skA + 0][srA] = a0.x; As[skA + 1][srA] = a0.y;
        As[skA + 2][srA] = a0.z; As[skA + 3][srA] = a0.w;
        Bs[skB + 0][srB] = b0.x; Bs[skB + 1][srB] = b0.y; Bs[skB + 2][srB] = b0.z; Bs[skB + 3][srB] = b0.w;
        Bs[skB + 4][srB] = b1.x; Bs[skB + 5][srB] = b1.y; Bs[skB + 6][srB] = b1.z; Bs[skB + 7][srB] = b1.w;
        __syncthreads();
#pragma unroll
        for (int kk = 0; kk < 16; ++kk) {
            float4 aA = *(const float4*)&As[kk][ty * 4];
            float4 bA = *(const float4*)&Bs[kk][tx * 4];
            float4 bB = *(const float4*)&Bs[kk][64 + tx * 4];
            float am[4] = {aA.x, aA.y, aA.z, aA.w};
            float bn[8] = {bA.x, bA.y, bA.z, bA.w, bB.x, bB.y, bB.z, bB.w};
#pragma unroll
            for (int i = 0; i < 4; ++i)
#pragma unroll
                for (int j = 0; j < 8; ++j) acc[i][j] = fmaf(am[i], bn[j], acc[i][j]);
        }
    }

    float* cp0 = part + (size_t)(which * 8 + s) * T_SEQ * 128;
#pragma unroll
    for (int i = 0; i < 4; ++i) {
        const int row = m0 + ty * 4 + i;
        float* cp = cp0 + (size_t)row * 128;
        float4 v0 = make_float4(acc[i][0], acc[i][1], acc[i][2], acc[i][3]);
        float4 v1 = make_float4(acc[i][4], acc[i][5], acc[i][6], acc[i][7]);
        *(float4*)(cp + tx * 4) = v0;
        *(float4*)(cp + 64 + tx * 4) = v1;
    }
}

// ---------------- K1: qik_splitk8_m64 (heavy, first) + rope_table + proj_w + convert
__global__ __launch_bounds__(256) void pre_kernel(
    const float* __restrict__ x,
    const float* __restrict__ WIq, const float* __restrict__ WIk, const float* __restrict__ WIw,
    const float* __restrict__ Wq, const float* __restrict__ Wk, const float* __restrict__ Wv,
    const float* __restrict__ Wgv, const float* __restrict__ Wgo, const float* __restrict__ Wo,
    unsigned short* __restrict__ xb, unsigned short* __restrict__ Wcatb,
    unsigned short* __restrict__ Wob,
    float* __restrict__ part, float* __restrict__ wsig,
    float* __restrict__ cost, float* __restrict__ sint)
{
    __shared__ __align__(16) char smem[16896];
    const int b = blockIdx.x;
    if (b < 512) {
        qik_body(smem, b & 1, (b >> 1) & 7, b >> 4, x, WIq, WIk, part);
    } else if (b < 768) {
        rope_table_body(b - 512, cost, sint);
    } else if (b < 896) {
        proj_w_body(b - 768, x, WIw, wsig);
    } else {
        convert_body(b - 896, x, Wq, Wk, Wv, Wgv, Wgo, Wo, xb, Wcatb, Wob);
    }
}

__global__ void qik_reduce_kernel(const float* __restrict__ part,
                                  float* __restrict__ qI, float* __restrict__ kI)
{
    const int idx = blockIdx.x * 256 + threadIdx.x;   // 0..524287
    const int which = idx >> 18;
    const int e = idx & 262143;
    const float* p = part + (size_t)which * 8 * T_SEQ * 128 + e;
    float s = 0.f;
#pragma unroll
    for (int j = 0; j < 8; ++j) s += p[(size_t)j * T_SEQ * 128];
    (which ? kI : qI)[e] = s;
}

// ---------------- impA body: causal-tiled f32 GEMM -> packed-triangular imp ----
__device__ __forceinline__ void impA_body(
    char* smemc,
    const float* __restrict__ qI, const float* __restrict__ kI,
    const float* __restrict__ wsig, const float* __restrict__ gate_bias,
    float* __restrict__ imp, int t, int hi)
{
    float (*As)[132] = (float(*)[132])smemc;             // 16896 B
    float (*Bs)[132] = (float(*)[132])(smemc + 16896);   // 16896 B
    int qi = (int)((sqrtf(8.f * (float)t + 1.f) - 1.f) * 0.5f);
    if ((qi + 1) * (qi + 2) / 2 <= t) qi++;
    if (qi * (qi + 1) / 2 > t) qi--;
    const int ki = t - qi * (qi + 1) / 2;
    const int m0 = qi * 128;

    const int tid = threadIdx.x;
    const int tx = tid & 15, ty = tid >> 4;

    {
        const int sr = tid >> 1;
        const int sk = (tid & 1) * 16;
        const float4* Ap = (const float4*)(qI + (size_t)(m0 + sr) * 128 + hi * 32 + sk);
        const float4* Bp = (const float4*)(kI + (size_t)(ki * 128 + sr) * 128 + hi * 32 + sk);
#pragma unroll
        for (int j4 = 0; j4 < 4; ++j4) {
            float4 a = Ap[j4], b = Bp[j4];
            As[sk + j4*4 + 0][sr] = a.x; As[sk + j4*4 + 1][sr] = a.y;
            As[sk + j4*4 + 2][sr] = a.z; As[sk + j4*4 + 3][sr] = a.w;
            Bs[sk + j4*4 + 0][sr] = b.x; Bs[sk + j4*4 + 1][sr] = b.y;
            Bs[sk + j4*4 + 2][sr] = b.z; Bs[sk + j4*4 + 3][sr] = b.w;
        }
    }
    __syncthreads();

    float acc[8][8];
#pragma unroll
    for (int i = 0; i < 8; ++i)
#pragma unroll
        for (int j = 0; j < 8; ++j) acc[i][j] = 0.f;

#pragma unroll
    for (int kk = 0; kk < 32; ++kk) {
        float4 aA = *(const float4*)&As[kk][ty * 4];
        float4 aB = *(const float4*)&As[kk][64 + ty * 4];
        float4 bA = *(const float4*)&Bs[kk][tx * 4];
        float4 bB = *(const float4*)&Bs[kk][64 + tx * 4];
        float am[8] = {aA.x, aA.y, aA.z, aA.w, aB.x, aB.y, aB.z, aB.w};
        float bn[8] = {bA.x, bA.y, bA.z, bA.w, bB.x, bB.y, bB.z, bB.w};
#pragma unroll
        for (int i = 0; i < 8; ++i)
#pragma unroll
            for (int j = 0; j < 8; ++j) acc[i][j] = fmaf(am[i], bn[j], acc[i][j]);
    }

    const float gb = gate_bias[hi];
    const size_t rw = (size_t)(qi + 1) * 128;
    float* impb = imp + (size_t)hi * IMPH + (size_t)16384 * (qi * (qi + 1) / 2) + ki * 128;
#pragma unroll
    for (int ih = 0; ih < 2; ++ih)
#pragma unroll
        for (int i = 0; i < 4; ++i) {
            const int rr = ih * 64 + ty * 4 + i;
            const float wr = wsig[(m0 + rr) * 4 + hi];
            float* cp = impb + (size_t)rr * rw;
            float4 v0, v1;
            v0.x = wr * sigf(acc[ih*4+i][0] + gb);
            v0.y = wr * sigf(acc[ih*4+i][1] + gb);
            v0.z = wr * sigf(acc[ih*4+i][2] + gb);
            v0.w = wr * sigf(acc[ih*4+i][3] + gb);
            v1.x = wr * sigf(acc[ih*4+i][4] + gb);
            v1.y = wr * sigf(acc[ih*4+i][5] + gb);
            v1.z = wr * sigf(acc[ih*4+i][6] + gb);
            v1.w = wr * sigf(acc[ih*4+i][7] + gb);
            *(float4*)(cp + tx * 4) = v0;
            *(float4*)(cp + 64 + tx * 4) = v1;
        }
}

// ---------------- K3: proj-GEMM (bf16 out) then impA (contiguous tiles) --------
__global__ __launch_bounds__(256) void mid_kernel(
    const unsigned short* __restrict__ xb, const unsigned short* __restrict__ Wcatb,
    unsigned short* __restrict__ lincatb,
    const float* __restrict__ qI, const float* __restrict__ kI,
    const float* __restrict__ wsig, const float* __restrict__ gate_bias,
    float* __restrict__ imp)
{
    __shared__ __align__(16) char smem[33792];
    const int b = blockIdx.x;
    if (b < 640) {
        gemm_body<true>(smem, xb, Wcatb, lincatb, NCAT, b % 40, b / 40);
    } else {
        const int bb = b - 640;
        impA_body(smem, qI, kI, wsig, gate_bias, imp, bb % 136, bb / 136);
    }
}

// ---------------- impB body: var -> k_t, threshold binary search, emission ----
template<int NC>
__device__ __forceinline__ void impB_body(
    const float* __restrict__ imp, const float* __restrict__ head_bias,
    unsigned short* __restrict__ sidxg, unsigned* __restrict__ cnts,
    int q, int hi, int lane)
{
    const int qc = q >> 6;   // last causal chunk (wave-uniform)
    const unsigned long long lmask_lt = (lane == 0) ? 0ull : ((~0ull) >> (64 - lane));

    const int qi = q >> 7;
    const size_t rw = (size_t)(qi + 1) * 128;
    const float* row = imp + (size_t)hi * IMPH +
                       (size_t)16384 * (qi * (qi + 1) / 2) + (size_t)(q - qi * 128) * rw;

    unsigned ordv[NC];
    double dsum = 0.0, dsq = 0.0;
#pragma unroll
    for (int i = 0; i < NC; ++i) {
        const int k = i * 64 + lane;
        unsigned vb = 0u;
        if (i <= qc) {
            const float v = row[k];
            const bool causal = (k <= q);
            const float vm = causal ? v : 0.f;
            dsum += (double)vm;
            dsq  += (double)vm * (double)vm;
            vb = causal ? __float_as_uint(v) : 0u;
        }
        if (i == 0 && lane < SINKN) vb = 0x7F800000u;
        ordv[i] = vb;
    }

#pragma unroll
    for (int off = 1; off < 64; off <<= 1) {
        dsum += __shfl_xor(dsum, off);
        dsq  += __shfl_xor(dsq, off);
    }

    int kts[4];
#pragma unroll
    for (int j = 0; j < 4; ++j) {
        const float sh = sigf(head_bias[hi * 4 + j]);
        const double mean = dsum / (double)T_SEQ;
        double var = dsq / (double)T_SEQ - mean * mean;
        if (var < 0.0) var = 0.0;
        const double vh = var * (double)sh * (double)sh;
        int kt = (int)floor(512.0 * vh);
        kt = kt < KMINV ? KMINV : (kt > KMAXV ? KMAXV : kt);
        kts[j] = kt;
    }

    unsigned vs[4]; int tt[4];
#pragma unroll
    for (int j = 0; j < 4; ++j) {
        bool dup = false;
#pragma unroll
        for (int p = 0; p < 4; ++p) {
            if (p < j && !dup && kts[p] == kts[j]) { vs[j] = vs[p]; tt[j] = tt[p]; dup = true; }
        }
        if (!dup) {
            const int kt = kts[j];
            unsigned X = 0;
#pragma unroll 1
            for (int b = 30; b >= 0; --b) {
                const unsigned Xt = X | (1u << b);
                int c = 0;
#pragma unroll
                for (int i = 0; i < NC; ++i)
                    c += (int)__popcll(__ballot(ordv[i] >= Xt));
                if (c >= kt) X = Xt;
            }
            int cg = 0;
#pragma unroll
            for (int i = 0; i < NC; ++i)
                cg += (int)__popcll(__ballot(ordv[i] > X));
            vs[j] = X; tt[j] = kt - cg;
        }
    }

    unsigned cnt = 0;
    unsigned short* sp = sidxg + ((size_t)hi * T_SEQ + q) * KMAXV;
    const bool uni = (kts[0] == kts[1]) && (kts[1] == kts[2]) && (kts[2] == kts[3]);

    if (uni) {
        int eqr = 0;
        const unsigned v0 = vs[0]; const int t0 = tt[0];
#pragma unroll
        for (int i = 0; i < NC; ++i) {
            const int k = i * 64 + lane;
            const unsigned x = ordv[i];
            const bool eq = (x == v0);
            const unsigned long long beq = __ballot(eq);
            const bool sel = (x > v0) || (eq && (eqr + (int)__popcll(beq & lmask_lt) < t0));
            eqr += (int)__popcll(beq);
            const bool valid = (k <= q) && sel;
            const unsigned long long bv = __ballot(valid);
            if (valid) {
                const unsigned pos = cnt + (unsigned)__popcll(bv & lmask_lt);
                if (pos < KMAXV) sp[pos] = (unsigned short)((unsigned)k | (0xFu << 11));
            }
            cnt += (unsigned)__popcll(bv);
        }
    } else {
        int eqr0 = 0, eqr1 = 0, eqr2 = 0, eqr3 = 0;
#pragma unroll
        for (int i = 0; i < NC; ++i) {
            const int k = i * 64 + lane;
            const unsigned x = ordv[i];
            unsigned mask = 0;
            {
                const bool eq = (x == vs[0]);
                const unsigned long long beq = __ballot(eq);
                const bool sel = (x > vs[0]) || (eq && (eqr0 + (int)__popcll(beq & lmask_lt) < tt[0]));
                eqr0 += (int)__popcll(beq);
                if (sel) mask |= 1u;
            }
            {
                const bool eq = (x == vs[1]);
                const unsigned long long beq = __ballot(eq);
                const bool sel = (x > vs[1]) || (eq && (eqr1 + (int)__popcll(beq & lmask_lt) < tt[1]));
                eqr1 += (int)__popcll(beq);
                if (sel) mask |= 2u;
            }
            {
                const bool eq = (x == vs[2]);
                const unsigned long long beq = __ballot(eq);
                const bool sel = (x > vs[2]) || (eq && (eqr2 + (int)__popcll(beq & lmask_lt) < tt[2]));
                eqr2 += (int)__popcll(beq);
                if (sel) mask |= 4u;
            }
            {
                const bool eq = (x == vs[3]);
                const unsigned long long beq = __ballot(eq);
                const bool sel = (x > vs[3]) || (eq && (eqr3 + (int)__popcll(beq & lmask_lt) < tt[3]));
                eqr3 += (int)__popcll(beq);
                if (sel) mask |= 8u;
            }
            const bool valid = (k <= q) && (mask != 0u);
            const unsigned long long bv = __ballot(valid);
            if (valid) {
                const unsigned pos = cnt + (unsigned)__popcll(bv & lmask_lt);
                if (pos < KMAXV) sp[pos] = (unsigned short)((unsigned)k | (mask << 11));
            }
            cnt += (unsigned)__popcll(bv);
        }
    }
    if (lane == 0) cnts[(size_t)hi * T_SEQ + q] = cnt < KMAXV ? cnt : KMAXV;
}

__device__ __forceinline__ void rope_v_body(
    int b, const unsigned short* __restrict__ lincatb,
    const float* __restrict__ cost, const float* __restrict__ sint,
    float* __restrict__ Q, unsigned short* __restrict__ Kb, unsigned short* __restrict__ Vb)
{
    const int idx = b * 256 + threadIdx.x;   // (t*16+h)*32 + i
    const int i = idx & 31;
    const int h = (idx >> 5) & 15;
    const int t = idx >> 9;
    const float cv = cost[t * 32 + i], sv = sint[t * 32 + i];
    const size_t src = (size_t)t * NCAT + h * HD + 2 * i;
    const ushort2 q2 = *(const ushort2*)(lincatb + src);
    const ushort2 k2 = *(const ushort2*)(lincatb + src + 1024);
    const ushort2 v2 = *(const ushort2*)(lincatb + src + 2048);
    const ushort2 g2 = *(const ushort2*)(lincatb + src + 3072);
    const float qx = bf16f(q2.x), qy = bf16f(q2.y);
    const float kx = bf16f(k2.x), ky = bf16f(k2.y);
    const float vx = bf16f(v2.x), vy = bf16f(v2.y);
    const float gx = bf16f(g2.x), gy = bf16f(g2.y);
    const size_t dst = ((size_t)h * T_SEQ + t) * HD;
    Q[dst + i]      = qx * cv - qy * sv;
    Q[dst + 32 + i] = qx * sv + qy * cv;
    Kb[dst + i]      = f2bf(kx * cv - ky * sv);
    Kb[dst + 32 + i] = f2bf(kx * sv + ky * cv);
    ushort2 vo;
    vo.x = f2bf(vx * sigf(gx));
    vo.y = f2bf(vy * sigf(gy));
    *(ushort2*)(Vb + dst + 2 * i) = vo;
}

// ---------------- K4: impB (LPT bands first) + rope_v -------------------------
__global__ __launch_bounds__(256) void sel_kernel(
    const float* __restrict__ imp, const float* __restrict__ head_bias,
    unsigned short* __restrict__ sidxg, unsigned* __restrict__ cnts,
    const unsigned short* __restrict__ lincatb,
    const float* __restrict__ cost, const float* __restrict__ sint,
    float* __restrict__ Q, unsigned short* __restrict__ Kb, unsigned short* __restrict__ Vb)
{
    const int b = blockIdx.x;
    if (b < 2048) {
        const int bx = b & 511;
        const int hi = b >> 9;
        const int wv = threadIdx.x >> 6;
        const int lane = threadIdx.x & 63;
        const int band = 7 - (bx >> 6);   // LPT: heaviest first
        const int bxx = bx & 63;
        const int q = band * 256 + bxx * 4 + wv;
        switch (band) {
            case 0:  impB_body< 4>(imp, head_bias, sidxg, cnts, q, hi, lane); break;
            case 1:  impB_body< 8>(imp, head_bias, sidxg, cnts, q, hi, lane); break;
            case 2:  impB_body<12>(imp, head_bias, sidxg, cnts, q, hi, lane); break;
            case 3:  impB_body<16>(imp, head_bias, sidxg, cnts, q, hi, lane); break;
            case 4:  impB_body<20>(imp, head_bias, sidxg, cnts, q, hi, lane); break;
            case 5:  impB_body<24>(imp, head_bias, sidxg, cnts, q, hi, lane); break;
            case 6:  impB_body<28>(imp, head_bias, sidxg, cnts, q, hi, lane); break;
            default: impB_body<32>(imp, head_bias, sidxg, cnts, q, hi, lane); break;
        }
    } else {
        rope_v_body(b - 2048, lincatb, cost, sint, Q, Kb, Vb);
    }
}

// ---------------- sparse gather attention: 2 queries per wave, bf16 K/V -------
__global__ __launch_bounds__(256) void attn_sparse_kernel(
    const float* __restrict__ Q, const unsigned short* __restrict__ Kb,
    const unsigned short* __restrict__ Vb,
    const unsigned short* __restrict__ sidx, const unsigned* __restrict__ cnts,
    const unsigned short* __restrict__ lincatb, unsigned short* __restrict__ ogb)
{
    const int orig = blockIdx.x + (blockIdx.y << 8);          // gridDim = (256,16)
    const int c = ((orig & 7) << 9) | (orig >> 3);            // XCD j -> heads 2j,2j+1
    const int h = c >> 8;
    const int qt = c & 255;
    const int hi = h >> 2, hj = h & 3;
    const int wv = threadIdx.x >> 6;
    const int lane = threadIdx.x & 63;
    const int qh = lane >> 5;         // query within pair
    const int l32 = lane & 31;
    const int kk = l32 >> 2;          // key slot 0..7
    const int dg = lane & 3;          // dim group 0..3
    const int q = qt * 8 + wv * 2 + qh;

    const size_t hq = (size_t)hi * T_SEQ + q;
    const int nv = (int)cnts[hq];
    const int nvm = max(nv, __shfl_xor(nv, 32));   // wave-uniform path choice
    const unsigned short* sp = sidx + hq * KMAXV;
    const unsigned short* Kh = Kb + (size_t)h * T_SEQ * HD + dg * 16;
    const unsigned short* Vh = Vb + (size_t)h * T_SEQ * HD + dg * 16;

    float4 qg[4];
    {
        const float4* qp = (const float4*)(Q + ((size_t)h * T_SEQ + q) * HD + dg * 16);
        qg[0] = qp[0]; qg[1] = qp[1]; qg[2] = qp[2]; qg[3] = qp[3];
    }

    float acc[16];
#pragma unroll
    for (int i = 0; i < 16; ++i) acc[i] = 0.f;
    float l = 0.f;

    if (nvm <= 32) {
        const ushort4 e4 = *(const ushort4*)(sp + kk * 4);
        const unsigned ev[4] = {e4.x, e4.y, e4.z, e4.w};

        float s[4]; int idxs[4];
#pragma unroll
        for (int sub = 0; sub < 4; ++sub) {
            const int kpos = kk * 4 + sub;
            const unsigned e = ev[sub];
            const bool ok = (kpos < nv) && ((e >> (11 + hj)) & 1u);
            const int iv = ok ? (int)(e & 0x7FFu) : 0;
            idxs[sub] = iv;
            const uint4* kr = (const uint4*)(Kh + (size_t)iv * HD);
            uint4 ka = kr[0], kb2 = kr[1];
            float da = 0.f, db = 0.f;
            da = fmaf(qg[0].x, bflo(ka.x), da); da = fmaf(qg[0].y, bfhi(ka.x), da);
            da = fmaf(qg[0].z, bflo(ka.y), da); da = fmaf(qg[0].w, bfhi(ka.y), da);
            db = fmaf(qg[1].x, bflo(ka.z), db); db = fmaf(qg[1].y, bfhi(ka.z), db);
            db = fmaf(qg[1].z, bflo(ka.w), db); db = fmaf(qg[1].w, bfhi(ka.w), db);
            da = fmaf(qg[2].x, bflo(kb2.x), da); da = fmaf(qg[2].y, bfhi(kb2.x), da);
            da = fmaf(qg[2].z, bflo(kb2.y), da); da = fmaf(qg[2].w, bfhi(kb2.y), da);
            db = fmaf(qg[3].x, bflo(kb2.z), db); db = fmaf(qg[3].y, bfhi(kb2.z), db);
            db = fmaf(qg[3].z, bflo(kb2.w), db); db = fmaf(qg[3].w, bfhi(kb2.w), db);
            float dot = da + db;
            dot += __shfl_xor(dot, 1);
            dot += __shfl_xor(dot, 2);
            s[sub] = ok ? dot * 0.125f : -INFINITY;
        }

        float cm = fmaxf(fmaxf(s[0], s[1]), fmaxf(s[2], s[3]));
        cm = fmaxf(cm, __shfl_xor(cm, 4));
        cm = fmaxf(cm, __shfl_xor(cm, 8));
        cm = fmaxf(cm, __shfl_xor(cm, 16));

        float p[4];
        float ls = 0.f;
#pragma unroll
        for (int sub = 0; sub < 4; ++sub) { p[sub] = expf(s[sub] - cm); ls += p[sub]; }
        ls += __shfl_xor(ls, 4);
        ls += __shfl_xor(ls, 8);
        ls += __shfl_xor(ls, 16);
        l = ls;
#pragma unroll
        for (int sub = 0; sub < 4; ++sub) {
            const float pv = p[sub];                         // 0 for masked
            const uint4* vr = (const uint4*)(Vh + (size_t)idxs[sub] * HD);
            uint4 va = vr[0], vb4 = vr[1];
            acc[0]  = fmaf(pv, bflo(va.x), acc[0]);   acc[1]  = fmaf(pv, bfhi(va.x), acc[1]);
            acc[2]  = fmaf(pv, bflo(va.y), acc[2]);   acc[3]  = fmaf(pv, bfhi(va.y), acc[3]);
            acc[4]  = fmaf(pv, bflo(va.z), acc[4]);   acc[5]  = fmaf(pv, bfhi(va.z), acc[5]);
            acc[6]  = fmaf(pv, bflo(va.w), acc[6]);   acc[7]  = fmaf(pv, bfhi(va.w), acc[7]);
            acc[8]  = fmaf(pv, bflo(vb4.x), acc[8]);  acc[9]  = fmaf(pv, bfhi(vb4.x), acc[9]);
            acc[10] = fmaf(pv, bflo(vb4.y), acc[10]); acc[11] = fmaf(pv, bfhi(vb4.y), acc[11]);
            acc[12] = fmaf(pv, bflo(vb4.z), acc[12]); acc[13] = fmaf(pv, bfhi(vb4.z), acc[13]);
            acc[14] = fmaf(pv, bflo(vb4.w), acc[14]); acc[15] = fmaf(pv, bfhi(vb4.w), acc[15]);
        }
    } else {
        float m = -INFINITY;
        for (int base = 0; base < nvm; base += 32) {
            const int nk = nv - base;
            const ushort4 e4 = *(const ushort4*)(sp + base + kk * 4);
            const unsigned ev[4] = {e4.x, e4.y, e4.z, e4.w};

            float s[4]; int idxs[4];
#pragma unroll
            for (int sub = 0; sub < 4; ++sub) {
                const int kpos = kk * 4 + sub;
                const unsigned e = ev[sub];
                const bool ok = (kpos < nk) && ((e >> (11 + hj)) & 1u);
                const int iv = ok ? (int)(e & 0x7FFu) : 0;
                idxs[sub] = iv;
                const uint4* kr = (const uint4*)(Kh + (size_t)iv * HD);
                uint4 ka = kr[0], kb2 = kr[1];
                float da = 0.f, db = 0.f;
                da = fmaf(qg[0].x, bflo(ka.x), da); da = fmaf(qg[0].y, bfhi(ka.x), da);
                da = fmaf(qg[0].z, bflo(ka.y), da); da = fmaf(qg[0].w, bfhi(ka.y), da);
                db = fmaf(qg[1].x, bflo(ka.z), db); db = fmaf(qg[1].y, bfhi(ka.z), db);
                db = fmaf(qg[1].z, bflo(ka.w), db); db = fmaf(qg[1].w, bfhi(ka.w), db);
                da = fmaf(qg[2].x, bflo(kb2.x), da); da = fmaf(qg[2].y, bfhi(kb2.x), da);
                da = fmaf(qg[2].z, bflo(kb2.y), da); da = fmaf(qg[2].w, bfhi(kb2.y), da);
                db = fmaf(qg[3].x, bflo(kb2.z), db); db = fmaf(qg[3].y, bfhi(kb2.z), db);
                db = fmaf(qg[3].z, bflo(kb2.w), db); db = fmaf(qg[3].w, bfhi(kb2.w), db);
                float dot = da + db;
                dot += __shfl_xor(dot, 1);
                dot += __shfl_xor(dot, 2);
                s[sub] = ok ? dot * 0.125f : -INFINITY;
            }

            float cm = fmaxf(fmaxf(s[0], s[1]), fmaxf(s[2], s[3]));
            cm = fmaxf(cm, __shfl_xor(cm, 4));
            cm = fmaxf(cm, __shfl_xor(cm, 8));
            cm = fmaxf(cm, __shfl_xor(cm, 16));
            const float mn = fmaxf(m, cm);
            if (mn > -INFINITY) {
                const float alpha = expf(m - mn);
                float p[4];
                float ls = 0.f;
#pragma unroll
                for (int sub = 0; sub < 4; ++sub) { p[sub] = expf(s[sub] - mn); ls += p[sub]; }
                ls += __shfl_xor(ls, 4);
                ls += __shfl_xor(ls, 8);
                ls += __shfl_xor(ls, 16);
                l = l * alpha + ls;
#pragma unroll
                for (int i = 0; i < 16; ++i) acc[i] *= alpha;
#pragma unroll
                for (int sub = 0; sub < 4; ++sub) {
                    const float pv = p[sub];
                    const uint4* vr = (const uint4*)(Vh + (size_t)idxs[sub] * HD);
                    uint4 va = vr[0], vb4 = vr[1];
                    acc[0]  = fmaf(pv, bflo(va.x), acc[0]);   acc[1]  = fmaf(pv, bfhi(va.x), acc[1]);
                    acc[2]  = fmaf(pv, bflo(va.y), acc[2]);   acc[3]  = fmaf(pv, bfhi(va.y), acc[3]);
                    acc[4]  = fmaf(pv, bflo(va.z), acc[4]);   acc[5]  = fmaf(pv, bfhi(va.z), acc[5]);
                    acc[6]  = fmaf(pv, bflo(va.w), acc[6]);   acc[7]  = fmaf(pv, bfhi(va.w), acc[7]);
                    acc[8]  = fmaf(pv, bflo(vb4.x), acc[8]);  acc[9]  = fmaf(pv, bfhi(vb4.x), acc[9]);
                    acc[10] = fmaf(pv, bflo(vb4.y), acc[10]); acc[11] = fmaf(pv, bfhi(vb4.y), acc[11]);
                    acc[12] = fmaf(pv, bflo(vb4.z), acc[12]); acc[13] = fmaf(pv, bfhi(vb4.z), acc[13]);
                    acc[14] = fmaf(pv, bflo(vb4.w), acc[14]); acc[15] = fmaf(pv, bfhi(vb4.w), acc[15]);
                }
                m = mn;
            }
        }
    }

#pragma unroll
    for (int i = 0; i < 16; ++i) {
        acc[i] += __shfl_xor(acc[i], 4);
        acc[i] += __shfl_xor(acc[i], 8);
        acc[i] += __shfl_xor(acc[i], 16);
    }
    const float invl = 1.f / l;
    float oval0 = acc[0], oval1 = acc[1];
#pragma unroll
    for (int i = 1; i < 8; ++i)
        if (kk == i) { oval0 = acc[2 * i]; oval1 = acc[2 * i + 1]; }
    const int d0 = dg * 16 + kk * 2;
    const ushort2 g2 = *(const ushort2*)(lincatb + (size_t)q * NCAT + 4096 + h * HD + d0);
    ushort2 o2;
    o2.x = f2bf(oval0 * invl * sigf(bf16f(g2.x)));
    o2.y = f2bf(oval1 * invl * sigf(bf16f(g2.y)));
    *(ushort2*)(ogb + (size_t)q * C_DIM + h * HD + d0) = o2;
}

extern "C" void kernel_launch(void* const* d_in, const int* in_sizes, int n_in,
                              void* d_out, int out_size, void* d_ws, size_t ws_size,
                              hipStream_t stream)
{
    const float* x   = (const float*)d_in[0];
    const float* WIq = (const float*)d_in[1];
    const float* WIk = (const float*)d_in[2];
    const float* WIw = (const float*)d_in[3];
    const float* gb  = (const float*)d_in[4];
    const float* hib = (const float*)d_in[5];
    const float* Wq  = (const float*)d_in[6];
    const float* Wk  = (const float*)d_in[7];
    const float* Wv  = (const float*)d_in[8];
    const float* Wgv = (const float*)d_in[9];
    const float* Wgo = (const float*)d_in[10];
    const float* Wo  = (const float*)d_in[11];
    float* out = (float*)d_out;

    char* ws = (char*)d_ws;
    const size_t MB = 1024 * 1024;
    float*    qI     = (float*)(ws + 0 * MB);                 // 1 MB
    float*    kI     = (float*)(ws + 1 * MB);                 // 1 MB
    float*    wsig   = (float*)(ws + 2 * MB);                 // 32 KB
    unsigned* cnts   = (unsigned*)(ws + 2 * MB + 64 * 1024);  // 32 KB
    float*    cost   = (float*)(ws + 2 * MB + 512 * 1024);    // 256 KB
    float*    sint   = (float*)(ws + 2 * MB + 768 * 1024);    // 256 KB
    float*    Q      = (float*)(ws + 3 * MB);                 // 8 MB  -> 11
    unsigned short* Kb = (unsigned short*)(ws + 11 * MB);     // 4 MB  -> 15
    unsigned short* Vb = (unsigned short*)(ws + 15 * MB);     // 4 MB  -> 19
    unsigned short* sidx = (unsigned short*)(ws + 19 * MB);   // 16 MB -> 35
    // region A (35..71): part (16 MB, K1 write / K2 read) -> imp (35.7 MB, K3 write / K4 read)
    float*    part    = (float*)(ws + 35 * MB);
    float*    imp     = (float*)(ws + 35 * MB);
    unsigned short* lincatb = (unsigned short*)(ws + 71 * MB);// 20 MB -> 91 (written K3)
    unsigned short* ogb   = (unsigned short*)(ws + 91 * MB);  // 4 MB  -> 95
    unsigned short* xb    = (unsigned short*)(ws + 95 * MB);  // 4 MB  -> 99
    unsigned short* Wcatb = (unsigned short*)(ws + 99 * MB);  // 10 MB -> 109
    unsigned short* Wob   = (unsigned short*)(ws + 109 * MB); // 2 MB  -> 111

    // K1: qik_splitk8_m64 (heavy first, 2 blocks/CU) + rope_table + proj_w + convert_all
    pre_kernel<<<dim3(9088), 256, 0, stream>>>(
        x, WIq, WIk, WIw, Wq, Wk, Wv, Wgv, Wgo, Wo,
        xb, Wcatb, Wob, part, wsig, cost, sint);
    // K2
    qik_reduce_kernel<<<dim3(2048), 256, 0, stream>>>(part, qI, kI);
    // K3: proj-GEMM (bf16 out) then impA (contiguous GEMM tiles for L2 locality)
    mid_kernel<<<dim3(1184), 256, 0, stream>>>(
        xb, Wcatb, lincatb, qI, kI, wsig, gb, imp);
    // K4: impB + rope_v
    sel_kernel<<<dim3(6144), 256, 0, stream>>>(
        imp, hib, sidx, cnts, lincatb, cost, sint, Q, Kb, Vb);
    // attention + out-projection
    attn_sparse_kernel<<<dim3(256, 16), 256, 0, stream>>>(Q, Kb, Vb, sidx, cnts, lincatb, ogb);
    gemm_out_kernel<<<dim3(8, 16), 256, 0, stream>>>(ogb, Wob, out, C_DIM);
}

// Round 25
// 159.736 us; speedup vs baseline: 1.0406x; 1.0053x over previous
//
#include <hip/hip_runtime.h>
#include <math.h>

#define T_SEQ 2048
#define C_DIM 1024
#define NH    16
#define HD    64
#define HIN   4
#define DI    32
#define SINKN 4
#define KMINV 32
#define KMAXV 1024
#define NCAT  5120   // q|k|v|gv|go concatenated columns
#define IMPH  2228224 // packed-triangular imp floats per indexer head

typedef __bf16 bf16x8 __attribute__((ext_vector_type(8)));
typedef float  f32x4  __attribute__((ext_vector_type(4)));

__device__ __forceinline__ float sigf(float x) { return 1.f / (1.f + expf(-x)); }

__device__ __forceinline__ unsigned short f2bf(float f) {
    unsigned u = __float_as_uint(f);
    unsigned r = (u + 0x7FFFu + ((u >> 16) & 1u)) >> 16;   // RNE
    return (unsigned short)r;
}

__device__ __forceinline__ float bflo(unsigned u) { return __uint_as_float(u << 16); }
__device__ __forceinline__ float bfhi(unsigned u) { return __uint_as_float(u & 0xFFFF0000u); }
__device__ __forceinline__ float bf16f(unsigned short u) { return __uint_as_float((unsigned)u << 16); }

__device__ __forceinline__ void gload16(const unsigned short* g, unsigned short* l) {
    __builtin_amdgcn_global_load_lds(
        (const __attribute__((address_space(1))) unsigned int*)(const unsigned int*)g,
        (__attribute__((address_space(3))) unsigned int*)(unsigned int*)l,
        16, 0, 0);
}

// ---------------- bf16 MFMA GEMM body: C = A_bf16 @ B_bf16^T (128x128 tile) ---
template<bool OUT_BF16>
__device__ __forceinline__ void gemm_body(
    char* smemc,
    const unsigned short* __restrict__ A, const unsigned short* __restrict__ B,
    void* __restrict__ Cv, int ldc, int bx, int by)
{
    unsigned short* Asl = (unsigned short*)smemc;          // 16384 B
    unsigned short* Bsl = (unsigned short*)(smemc + 16384);// 16384 B
    const int K = C_DIM;
    const int tid = threadIdx.x;
    const int w = tid >> 6, lane = tid & 63;
    const int wm = w >> 1, wn = w & 1;
    const int m0 = by * 128, n0 = bx * 128;

    const f32x4 z4 = {0.f, 0.f, 0.f, 0.f};
    f32x4 acc[4][4];
#pragma unroll
    for (int i = 0; i < 4; ++i)
#pragma unroll
        for (int j = 0; j < 4; ++j) acc[i][j] = z4;

    const int lrow  = w * 8 + (lane >> 3);
    const int lslot = (lane & 7) ^ (lane >> 3);
    const unsigned short* Ag = A + (size_t)(m0 + lrow) * K + lslot * 8;
    const unsigned short* Bg = B + (size_t)(n0 + lrow) * K + lslot * 8;

    const int fr = lane & 15;
    const int kg = lane >> 4;

    for (int kt = 0; kt < K; kt += 64) {
        __syncthreads();
#pragma unroll
        for (int i = 0; i < 4; ++i) {
            gload16(Ag + (size_t)(i * 32) * K + kt, &Asl[(i * 32 + w * 8) * 64]);
            gload16(Bg + (size_t)(i * 32) * K + kt, &Bsl[(i * 32 + w * 8) * 64]);
        }
        __syncthreads();
#pragma unroll
        for (int ks = 0; ks < 2; ++ks) {
            bf16x8 af[4], bfr[4];
            const int aslot = ks * 4 + kg;
#pragma unroll
            for (int f = 0; f < 4; ++f) {
                const int arow = wm * 64 + f * 16 + fr;
                af[f] = *(const bf16x8*)&Asl[arow * 64 + ((aslot ^ (arow & 7)) * 8)];
                const int brow = wn * 64 + f * 16 + fr;
                bfr[f] = *(const bf16x8*)&Bsl[brow * 64 + ((aslot ^ (brow & 7)) * 8)];
            }
#pragma unroll
            for (int mi = 0; mi < 4; ++mi)
#pragma unroll
                for (int ni = 0; ni < 4; ++ni)
                    acc[mi][ni] = __builtin_amdgcn_mfma_f32_16x16x32_bf16(
                        af[mi], bfr[ni], acc[mi][ni], 0, 0, 0);
        }
    }

#pragma unroll
    for (int mi = 0; mi < 4; ++mi) {
        const int row = by * 128 + wm * 64 + mi * 16 + (lane >> 4) * 4;
#pragma unroll
        for (int ni = 0; ni < 4; ++ni) {
            const int col = bx * 128 + wn * 64 + ni * 16 + (lane & 15);
            if constexpr (OUT_BF16) {
                unsigned short* cp = (unsigned short*)Cv + (size_t)row * ldc + col;
#pragma unroll
                for (int r = 0; r < 4; ++r) cp[(size_t)r * ldc] = f2bf(acc[mi][ni][r]);
            } else {
                float* cp = (float*)Cv + (size_t)row * ldc + col;
#pragma unroll
                for (int r = 0; r < 4; ++r) cp[(size_t)r * ldc] = acc[mi][ni][r];
            }
        }
    }
}

// ---------------- out-projection body: 128x64 tile, f32 out --------------------
// Grid (16,16) = 256 blocks -> 1 block/CU (the 128x128 version left half the
// machine idle at 128 blocks). Per-output K-accumulation chain is bitwise
// identical to gemm_body (same kt/ks/MFMA order) - only column mapping changes.
__device__ __forceinline__ void gemm_out_body(
    char* smemc,
    const unsigned short* __restrict__ A, const unsigned short* __restrict__ B,
    float* __restrict__ C, int ldc, int bx, int by)
{
    unsigned short* Asl = (unsigned short*)smemc;          // 128*64*2 = 16384 B
    unsigned short* Bsl = (unsigned short*)(smemc + 16384);// 64*64*2  =  8192 B
    const int K = C_DIM;
    const int tid = threadIdx.x;
    const int w = tid >> 6, lane = tid & 63;
    const int wm = w >> 1, wn = w & 1;
    const int m0 = by * 128, n0 = bx * 64;

    const f32x4 z4 = {0.f, 0.f, 0.f, 0.f};
    f32x4 acc[4][2];
#pragma unroll
    for (int i = 0; i < 4; ++i)
#pragma unroll
        for (int j = 0; j < 2; ++j) acc[i][j] = z4;

    const int lrow  = w * 8 + (lane >> 3);
    const int lslot = (lane & 7) ^ (lane >> 3);
    const unsigned short* Ag = A + (size_t)(m0 + lrow) * K + lslot * 8;
    const unsigned short* Bg = B + (size_t)(n0 + lrow) * K + lslot * 8;

    const int fr = lane & 15;
    const int kg = lane >> 4;

    for (int kt = 0; kt < K; kt += 64) {
        __syncthreads();
#pragma unroll
        for (int i = 0; i < 4; ++i)
            gload16(Ag + (size_t)(i * 32) * K + kt, &Asl[(i * 32 + w * 8) * 64]);
#pragma unroll
        for (int i = 0; i < 2; ++i)
            gload16(Bg + (size_t)(i * 32) * K + kt, &Bsl[(i * 32 + w * 8) * 64]);
        __syncthreads();
#pragma unroll
        for (int ks = 0; ks < 2; ++ks) {
            bf16x8 af[4], bfr[2];
            const int aslot = ks * 4 + kg;
#pragma unroll
            for (int f = 0; f < 4; ++f) {
                const int arow = wm * 64 + f * 16 + fr;
                af[f] = *(const bf16x8*)&Asl[arow * 64 + ((aslot ^ (arow & 7)) * 8)];
            }
#pragma unroll
            for (int f = 0; f < 2; ++f) {
                const int brow = wn * 32 + f * 16 + fr;
                bfr[f] = *(const bf16x8*)&Bsl[brow * 64 + ((aslot ^ (brow & 7)) * 8)];
            }
#pragma unroll
            for (int mi = 0; mi < 4; ++mi)
#pragma unroll
                for (int ni = 0; ni < 2; ++ni)
                    acc[mi][ni] = __builtin_amdgcn_mfma_f32_16x16x32_bf16(
                        af[mi], bfr[ni], acc[mi][ni], 0, 0, 0);
        }
    }

#pragma unroll
    for (int mi = 0; mi < 4; ++mi) {
        const int row = m0 + wm * 64 + mi * 16 + (lane >> 4) * 4;
#pragma unroll
        for (int ni = 0; ni < 2; ++ni) {
            const int col = n0 + wn * 32 + ni * 16 + (lane & 15);
            float* cp = C + (size_t)row * ldc + col;
#pragma unroll
            for (int r = 0; r < 4; ++r) cp[(size_t)r * ldc] = acc[mi][ni][r];
        }
    }
}

// standalone final out-projection (f32 out), 256 blocks
__global__ __launch_bounds__(256) void gemm_out_kernel(
    const unsigned short* __restrict__ A, const unsigned short* __restrict__ B,
    float* __restrict__ C, int ldc)
{
    __shared__ __align__(16) char smem[24576];
    gemm_out_body(smem, A, B, C, ldc, blockIdx.x, blockIdx.y);
}

// ---------------- component bodies ---------------------------------------------
__device__ __forceinline__ void convert_body(
    int b, const float* __restrict__ x,
    const float* __restrict__ Wq, const float* __restrict__ Wk, const float* __restrict__ Wv,
    const float* __restrict__ Wgv, const float* __restrict__ Wgo, const float* __restrict__ Wo,
    unsigned short* __restrict__ xb, unsigned short* __restrict__ Wcatb,
    unsigned short* __restrict__ Wob)
{
    const float* s; unsigned short* d; size_t off;
    if (b < 2048)      { s = x;  d = xb;  off = (size_t)b * 1024; }
    else if (b < 7168) {
        const int wsel = (b - 2048) >> 10;
        switch (wsel) {
            case 0: s = Wq;  break;
            case 1: s = Wk;  break;
            case 2: s = Wv;  break;
            case 3: s = Wgv; break;
            default: s = Wgo; break;
        }
        d = Wcatb + ((size_t)wsel << 20);
        off = (size_t)((b - 2048) & 1023) * 1024;
    } else             { s = Wo; d = Wob; off = (size_t)(b - 7168) * 1024; }

    const size_t i = off + threadIdx.x * 4;
    const float4 v = *(const float4*)(s + i);
    ushort4 o;
    o.x = f2bf(v.x); o.y = f2bf(v.y); o.z = f2bf(v.z); o.w = f2bf(v.w);
    *(ushort4*)(d + i) = o;
}

__device__ __forceinline__ void proj_w_body(
    int b, const float* __restrict__ x, const float* __restrict__ WIw,
    float* __restrict__ wsig)
{
    const int idx4 = b * 256 + threadIdx.x;
    const int part4 = idx4 & 3;
    const int oidx = idx4 >> 2;      // t*4 + hi
    const int t = oidx >> 2, hi = oidx & 3;
    const float4* xr = (const float4*)(x + (size_t)t * C_DIM + part4 * 256);
    const float4* wr = (const float4*)(WIw + (size_t)hi * C_DIM + part4 * 256);
    float s = 0.f;
#pragma unroll
    for (int i = 0; i < 64; ++i) {
        float4 a = xr[i], w4 = wr[i];
        s += a.x * w4.x + a.y * w4.y + a.z * w4.z + a.w * w4.w;
    }
    s += __shfl_xor(s, 1);
    s += __shfl_xor(s, 2);
    if (part4 == 0) wsig[oidx] = sigf(s);
}

__device__ __forceinline__ void rope_table_body(
    int b, float* __restrict__ cost, float* __restrict__ sint)
{
    const int idx = b * 256 + threadIdx.x;   // t*32 + i
    const int t = idx >> 5, i = idx & 31;
    const int j = (2 * i) & 31;
    const float invf = powf(10000.f, -(float)j / 32.f);
    const float f = (float)t * invf;
    float sv, cv;
    sincosf(f, &sv, &cv);
    cost[idx] = cv;
    sint[idx] = sv;
}

// split-K 8 + split-M 64: 32 mt x 2 which x 8 s = 512 blocks (2/CU).
__device__ __forceinline__ void qik_body(
    char* smemc, int which, int s, int mt,
    const float* __restrict__ x, const float* __restrict__ WIq, const float* __restrict__ WIk,
    float* __restrict__ part)
{
    float (*As)[68]  = (float(*)[68])smemc;              // 16*68*4  = 4352 B
    float (*Bs)[132] = (float(*)[132])(smemc + 4352);    // 16*132*4 = 8448 B
    const float* B = which ? WIk : WIq;
    const int m0 = mt * 64;
    const int kb = s * 128;
    const int tid = threadIdx.x;
    const int tx = tid & 15, ty = tid >> 4;

    float acc[4][8];
#pragma unroll
    for (int i = 0; i < 4; ++i)
#pragma unroll
        for (int j = 0; j < 8; ++j) acc[i][j] = 0.f;

    const int srA = tid >> 2;            // 0..63
    const int skA = (tid & 3) * 4;       // 0,4,8,12
    const int srB = tid >> 1;            // 0..127
    const int skB = (tid & 1) * 8;       // 0,8
    const float* Ap = x + (size_t)(m0 + srA) * C_DIM + kb + skA;
    const float* Bp = B + (size_t)srB * C_DIM + kb + skB;

    for (int k0 = 0; k0 < 128; k0 += 16) {
        float4 a0 = *(const float4*)(Ap + k0);
        float4 b0 = *(const float4*)(Bp + k0);
        float4 b1 = *(const float4*)(Bp + k0 + 4);
        __syncthreads();
        As[skA + 0][srA] = a0.x; As[skA + 1][srA] = a0.y;
        As[skA + 2][srA] = a0.z; As[skA + 3][srA] = a0.w;
        Bs[skB + 0][srB] = b0.x; Bs[skB + 1][srB] = b0.y; Bs[skB + 2][srB] = b0.z; Bs[skB + 3][srB] = b0.w;
        Bs[skB + 4][srB] = b1.x; Bs[skB + 5][srB] = b1.y; Bs[skB + 6][srB] = b1.z; Bs[skB + 7][srB] = b1.w;
        __syncthreads();
#pragma unroll
        for (int kk = 0; kk < 16; ++kk) {
            float4 aA = *(const float4*)&As[kk][ty * 4];
            float4 bA = *(const float4*)&Bs[kk][tx * 4];
            float4 bB = *(const float4*)&Bs[kk][64 + tx * 4];
            float am[4] = {aA.x, aA.y, aA.z, aA.w};
            float bn[8] = {bA.x, bA.y, bA.z, bA.w, bB.x, bB.y, bB.z, bB.w};
#pragma unroll
            for (int i = 0; i < 4; ++i)
#pragma unroll
                for (int j = 0; j < 8; ++j) acc[i][j] = fmaf(am[i], bn[j], acc[i][j]);
        }
    }

    float* cp0 = part + (size_t)(which * 8 + s) * T_SEQ * 128;
#pragma unroll
    for (int i = 0; i < 4; ++i) {
        const int row = m0 + ty * 4 + i;
        float* cp = cp0 + (size_t)row * 128;
        float4 v0 = make_float4(acc[i][0], acc[i][1], acc[i][2], acc[i][3]);
        float4 v1 = make_float4(acc[i][4], acc[i][5], acc[i][6], acc[i][7]);
        *(float4*)(cp + tx * 4) = v0;
        *(float4*)(cp + 64 + tx * 4) = v1;
    }
}

// ---------------- K1: qik_splitk8_m64 (heavy, first) + rope_table + proj_w + convert
__global__ __launch_bounds__(256) void pre_kernel(
    const float* __restrict__ x,
    const float* __restrict__ WIq, const float* __restrict__ WIk, const float* __restrict__ WIw,
    const float* __restrict__ Wq, const float* __restrict__ Wk, const float* __restrict__ Wv,
    const float* __restrict__ Wgv, const float* __restrict__ Wgo, const float* __restrict__ Wo,
    unsigned short* __restrict__ xb, unsigned short* __restrict__ Wcatb,
    unsigned short* __restrict__ Wob,
    float* __restrict__ part, float* __restrict__ wsig,
    float* __restrict__ cost, float* __restrict__ sint)
{
    __shared__ __align__(16) char smem[16896];
    const int b = blockIdx.x;
    if (b < 512) {
        qik_body(smem, b & 1, (b >> 1) & 7, b >> 4, x, WIq, WIk, part);
    } else if (b < 768) {
        rope_table_body(b - 512, cost, sint);
    } else if (b < 896) {
        proj_w_body(b - 768, x, WIw, wsig);
    } else {
        convert_body(b - 896, x, Wq, Wk, Wv, Wgv, Wgo, Wo, xb, Wcatb, Wob);
    }
}

__global__ void qik_reduce_kernel(const float* __restrict__ part,
                                  float* __restrict__ qI, float* __restrict__ kI)
{
    const int idx = blockIdx.x * 256 + threadIdx.x;   // 0..524287
    const int which = idx >> 18;
    const int e = idx & 262143;
    const float* p = part + (size_t)which * 8 * T_SEQ * 128 + e;
    float s = 0.f;
#pragma unroll
    for (int j = 0; j < 8; ++j) s += p[(size_t)j * T_SEQ * 128];
    (which ? kI : qI)[e] = s;
}

// ---------------- impA body: causal-tiled f32 GEMM -> packed-triangular imp ----
__device__ __forceinline__ void impA_body(
    char* smemc,
    const float* __restrict__ qI, const float* __restrict__ kI,
    const float* __restrict__ wsig, const float* __restrict__ gate_bias,
    float* __restrict__ imp, int t, int hi)
{
    float (*As)[132] = (float(*)[132])smemc;             // 16896 B
    float (*Bs)[132] = (float(*)[132])(smemc + 16896);   // 16896 B
    int qi = (int)((sqrtf(8.f * (float)t + 1.f) - 1.f) * 0.5f);
    if ((qi + 1) * (qi + 2) / 2 <= t) qi++;
    if (qi * (qi + 1) / 2 > t) qi--;
    const int ki = t - qi * (qi + 1) / 2;
    const int m0 = qi * 128;

    const int tid = threadIdx.x;
    const int tx = tid & 15, ty = tid >> 4;

    {
        const int sr = tid >> 1;
        const int sk = (tid & 1) * 16;
        const float4* Ap = (const float4*)(qI + (size_t)(m0 + sr) * 128 + hi * 32 + sk);
        const float4* Bp = (const float4*)(kI + (size_t)(ki * 128 + sr) * 128 + hi * 32 + sk);
#pragma unroll
        for (int j4 = 0; j4 < 4; ++j4) {
            float4 a = Ap[j4], b = Bp[j4];
            As[sk + j4*4 + 0][sr] = a.x; As[sk + j4*4 + 1][sr] = a.y;
            As[sk + j4*4 + 2][sr] = a.z; As[sk + j4*4 + 3][sr] = a.w;
            Bs[sk + j4*4 + 0][sr] = b.x; Bs[sk + j4*4 + 1][sr] = b.y;
            Bs[sk + j4*4 + 2][sr] = b.z; Bs[sk + j4*4 + 3][sr] = b.w;
        }
    }
    __syncthreads();

    float acc[8][8];
#pragma unroll
    for (int i = 0; i < 8; ++i)
#pragma unroll
        for (int j = 0; j < 8; ++j) acc[i][j] = 0.f;

#pragma unroll
    for (int kk = 0; kk < 32; ++kk) {
        float4 aA = *(const float4*)&As[kk][ty * 4];
        float4 aB = *(const float4*)&As[kk][64 + ty * 4];
        float4 bA = *(const float4*)&Bs[kk][tx * 4];
        float4 bB = *(const float4*)&Bs[kk][64 + tx * 4];
        float am[8] = {aA.x, aA.y, aA.z, aA.w, aB.x, aB.y, aB.z, aB.w};
        float bn[8] = {bA.x, bA.y, bA.z, bA.w, bB.x, bB.y, bB.z, bB.w};
#pragma unroll
        for (int i = 0; i < 8; ++i)
#pragma unroll
            for (int j = 0; j < 8; ++j) acc[i][j] = fmaf(am[i], bn[j], acc[i][j]);
    }

    const float gb = gate_bias[hi];
    const size_t rw = (size_t)(qi + 1) * 128;
    float* impb = imp + (size_t)hi * IMPH + (size_t)16384 * (qi * (qi + 1) / 2) + ki * 128;
#pragma unroll
    for (int ih = 0; ih < 2; ++ih)
#pragma unroll
        for (int i = 0; i < 4; ++i) {
            const int rr = ih * 64 + ty * 4 + i;
            const float wr = wsig[(m0 + rr) * 4 + hi];
            float* cp = impb + (size_t)rr * rw;
            float4 v0, v1;
            v0.x = wr * sigf(acc[ih*4+i][0] + gb);
            v0.y = wr * sigf(acc[ih*4+i][1] + gb);
            v0.z = wr * sigf(acc[ih*4+i][2] + gb);
            v0.w = wr * sigf(acc[ih*4+i][3] + gb);
            v1.x = wr * sigf(acc[ih*4+i][4] + gb);
            v1.y = wr * sigf(acc[ih*4+i][5] + gb);
            v1.z = wr * sigf(acc[ih*4+i][6] + gb);
            v1.w = wr * sigf(acc[ih*4+i][7] + gb);
            *(float4*)(cp + tx * 4) = v0;
            *(float4*)(cp + 64 + tx * 4) = v1;
        }
}

// ---------------- K3: proj-GEMM (bf16 out) then impA (contiguous tiles) --------
__global__ __launch_bounds__(256) void mid_kernel(
    const unsigned short* __restrict__ xb, const unsigned short* __restrict__ Wcatb,
    unsigned short* __restrict__ lincatb,
    const float* __restrict__ qI, const float* __restrict__ kI,
    const float* __restrict__ wsig, const float* __restrict__ gate_bias,
    float* __restrict__ imp)
{
    __shared__ __align__(16) char smem[33792];
    const int b = blockIdx.x;
    if (b < 640) {
        gemm_body<true>(smem, xb, Wcatb, lincatb, NCAT, b % 40, b / 40);
    } else {
        const int bb = b - 640;
        impA_body(smem, qI, kI, wsig, gate_bias, imp, bb % 136, bb / 136);
    }
}

// ---------------- impB body: var -> k_t, threshold binary search, emission ----
template<int NC>
__device__ __forceinline__ void impB_body(
    const float* __restrict__ imp, const float* __restrict__ head_bias,
    unsigned short* __restrict__ sidxg, unsigned* __restrict__ cnts,
    int q, int hi, int lane)
{
    const int qc = q >> 6;   // last causal chunk (wave-uniform)
    const unsigned long long lmask_lt = (lane == 0) ? 0ull : ((~0ull) >> (64 - lane));

    const int qi = q >> 7;
    const size_t rw = (size_t)(qi + 1) * 128;
    const float* row = imp + (size_t)hi * IMPH +
                       (size_t)16384 * (qi * (qi + 1) / 2) + (size_t)(q - qi * 128) * rw;

    unsigned ordv[NC];
    double dsum = 0.0, dsq = 0.0;
#pragma unroll
    for (int i = 0; i < NC; ++i) {
        const int k = i * 64 + lane;
        unsigned vb = 0u;
        if (i <= qc) {
            const float v = row[k];
            const bool causal = (k <= q);
            const float vm = causal ? v : 0.f;
            dsum += (double)vm;
            dsq  += (double)vm * (double)vm;
            vb = causal ? __float_as_uint(v) : 0u;
        }
        if (i == 0 && lane < SINKN) vb = 0x7F800000u;
        ordv[i] = vb;
    }

#pragma unroll
    for (int off = 1; off < 64; off <<= 1) {
        dsum += __shfl_xor(dsum, off);
        dsq  += __shfl_xor(dsq, off);
    }

    int kts[4];
#pragma unroll
    for (int j = 0; j < 4; ++j) {
        const float sh = sigf(head_bias[hi * 4 + j]);
        const double mean = dsum / (double)T_SEQ;
        double var = dsq / (double)T_SEQ - mean * mean;
        if (var < 0.0) var = 0.0;
        const double vh = var * (double)sh * (double)sh;
        int kt = (int)floor(512.0 * vh);
        kt = kt < KMINV ? KMINV : (kt > KMAXV ? KMAXV : kt);
        kts[j] = kt;
    }

    unsigned vs[4]; int tt[4];
#pragma unroll
    for (int j = 0; j < 4; ++j) {
        bool dup = false;
#pragma unroll
        for (int p = 0; p < 4; ++p) {
            if (p < j && !dup && kts[p] == kts[j]) { vs[j] = vs[p]; tt[j] = tt[p]; dup = true; }
        }
        if (!dup) {
            const int kt = kts[j];
            unsigned X = 0;
#pragma unroll 1
            for (int b = 30; b >= 0; --b) {
                const unsigned Xt = X | (1u << b);
                int c = 0;
#pragma unroll
                for (int i = 0; i < NC; ++i)
                    c += (int)__popcll(__ballot(ordv[i] >= Xt));
                if (c >= kt) X = Xt;
            }
            int cg = 0;
#pragma unroll
            for (int i = 0; i < NC; ++i)
                cg += (int)__popcll(__ballot(ordv[i] > X));
            vs[j] = X; tt[j] = kt - cg;
        }
    }

    unsigned cnt = 0;
    unsigned short* sp = sidxg + ((size_t)hi * T_SEQ + q) * KMAXV;
    const bool uni = (kts[0] == kts[1]) && (kts[1] == kts[2]) && (kts[2] == kts[3]);

    if (uni) {
        int eqr = 0;
        const unsigned v0 = vs[0]; const int t0 = tt[0];
#pragma unroll
        for (int i = 0; i < NC; ++i) {
            const int k = i * 64 + lane;
            const unsigned x = ordv[i];
            const bool eq = (x == v0);
            const unsigned long long beq = __ballot(eq);
            const bool sel = (x > v0) || (eq && (eqr + (int)__popcll(beq & lmask_lt) < t0));
            eqr += (int)__popcll(beq);
            const bool valid = (k <= q) && sel;
            const unsigned long long bv = __ballot(valid);
            if (valid) {
                const unsigned pos = cnt + (unsigned)__popcll(bv & lmask_lt);
                if (pos < KMAXV) sp[pos] = (unsigned short)((unsigned)k | (0xFu << 11));
            }
            cnt += (unsigned)__popcll(bv);
        }
    } else {
        int eqr0 = 0, eqr1 = 0, eqr2 = 0, eqr3 = 0;
#pragma unroll
        for (int i = 0; i < NC; ++i) {
            const int k = i * 64 + lane;
            const unsigned x = ordv[i];
            unsigned mask = 0;
            {
                const bool eq = (x == vs[0]);
                const unsigned long long beq = __ballot(eq);
                const bool sel = (x > vs[0]) || (eq && (eqr0 + (int)__popcll(beq & lmask_lt) < tt[0]));
                eqr0 += (int)__popcll(beq);
                if (sel) mask |= 1u;
            }
            {
                const bool eq = (x == vs[1]);
                const unsigned long long beq = __ballot(eq);
                const bool sel = (x > vs[1]) || (eq && (eqr1 + (int)__popcll(beq & lmask_lt) < tt[1]));
                eqr1 += (int)__popcll(beq);
                if (sel) mask |= 2u;
            }
            {
                const bool eq = (x == vs[2]);
                const unsigned long long beq = __ballot(eq);
                const bool sel = (x > vs[2]) || (eq && (eqr2 + (int)__popcll(beq & lmask_lt) < tt[2]));
                eqr2 += (int)__popcll(beq);
                if (sel) mask |= 4u;
            }
            {
                const bool eq = (x == vs[3]);
                const unsigned long long beq = __ballot(eq);
                const bool sel = (x > vs[3]) || (eq && (eqr3 + (int)__popcll(beq & lmask_lt) < tt[3]));
                eqr3 += (int)__popcll(beq);
                if (sel) mask |= 8u;
            }
            const bool valid = (k <= q) && (mask != 0u);
            const unsigned long long bv = __ballot(valid);
            if (valid) {
                const unsigned pos = cnt + (unsigned)__popcll(bv & lmask_lt);
                if (pos < KMAXV) sp[pos] = (unsigned short)((unsigned)k | (mask << 11));
            }
            cnt += (unsigned)__popcll(bv);
        }
    }
    if (lane == 0) cnts[(size_t)hi * T_SEQ + q] = cnt < KMAXV ? cnt : KMAXV;
}

__device__ __forceinline__ void rope_v_body(
    int b, const unsigned short* __restrict__ lincatb,
    const float* __restrict__ cost, const float* __restrict__ sint,
    float* __restrict__ Q, unsigned short* __restrict__ Kb, unsigned short* __restrict__ Vb)
{
    const int idx = b * 256 + threadIdx.x;   // (t*16+h)*32 + i
    const int i = idx & 31;
    const int h = (idx >> 5) & 15;
    const int t = idx >> 9;
    const float cv = cost[t * 32 + i], sv = sint[t * 32 + i];
    const size_t src = (size_t)t * NCAT + h * HD + 2 * i;
    const ushort2 q2 = *(const ushort2*)(lincatb + src);
    const ushort2 k2 = *(const ushort2*)(lincatb + src + 1024);
    const ushort2 v2 = *(const ushort2*)(lincatb + src + 2048);
    const ushort2 g2 = *(const ushort2*)(lincatb + src + 3072);
    const float qx = bf16f(q2.x), qy = bf16f(q2.y);
    const float kx = bf16f(k2.x), ky = bf16f(k2.y);
    const float vx = bf16f(v2.x), vy = bf16f(v2.y);
    const float gx = bf16f(g2.x), gy = bf16f(g2.y);
    const size_t dst = ((size_t)h * T_SEQ + t) * HD;
    Q[dst + i]      = qx * cv - qy * sv;
    Q[dst + 32 + i] = qx * sv + qy * cv;
    Kb[dst + i]      = f2bf(kx * cv - ky * sv);
    Kb[dst + 32 + i] = f2bf(kx * sv + ky * cv);
    ushort2 vo;
    vo.x = f2bf(vx * sigf(gx));
    vo.y = f2bf(vy * sigf(gy));
    *(ushort2*)(Vb + dst + 2 * i) = vo;
}

// ---------------- K4: impB (LPT bands first) + rope_v -------------------------
__global__ __launch_bounds__(256) void sel_kernel(
    const float* __restrict__ imp, const float* __restrict__ head_bias,
    unsigned short* __restrict__ sidxg, unsigned* __restrict__ cnts,
    const unsigned short* __restrict__ lincatb,
    const float* __restrict__ cost, const float* __restrict__ sint,
    float* __restrict__ Q, unsigned short* __restrict__ Kb, unsigned short* __restrict__ Vb)
{
    const int b = blockIdx.x;
    if (b < 2048) {
        const int bx = b & 511;
        const int hi = b >> 9;
        const int wv = threadIdx.x >> 6;
        const int lane = threadIdx.x & 63;
        const int band = 7 - (bx >> 6);   // LPT: heaviest first
        const int bxx = bx & 63;
        const int q = band * 256 + bxx * 4 + wv;
        switch (band) {
            case 0:  impB_body< 4>(imp, head_bias, sidxg, cnts, q, hi, lane); break;
            case 1:  impB_body< 8>(imp, head_bias, sidxg, cnts, q, hi, lane); break;
            case 2:  impB_body<12>(imp, head_bias, sidxg, cnts, q, hi, lane); break;
            case 3:  impB_body<16>(imp, head_bias, sidxg, cnts, q, hi, lane); break;
            case 4:  impB_body<20>(imp, head_bias, sidxg, cnts, q, hi, lane); break;
            case 5:  impB_body<24>(imp, head_bias, sidxg, cnts, q, hi, lane); break;
            case 6:  impB_body<28>(imp, head_bias, sidxg, cnts, q, hi, lane); break;
            default: impB_body<32>(imp, head_bias, sidxg, cnts, q, hi, lane); break;
        }
    } else {
        rope_v_body(b - 2048, lincatb, cost, sint, Q, Kb, Vb);
    }
}

// ---------------- sparse gather attention: 2 queries per wave, bf16 K/V -------
__global__ __launch_bounds__(256) void attn_sparse_kernel(
    const float* __restrict__ Q, const unsigned short* __restrict__ Kb,
    const unsigned short* __restrict__ Vb,
    const unsigned short* __restrict__ sidx, const unsigned* __restrict__ cnts,
    const unsigned short* __restrict__ lincatb, unsigned short* __restrict__ ogb)
{
    const int orig = blockIdx.x + (blockIdx.y << 8);          // gridDim = (256,16)
    const int c = ((orig & 7) << 9) | (orig >> 3);            // XCD j -> heads 2j,2j+1
    const int h = c >> 8;
    const int qt = c & 255;
    const int hi = h >> 2, hj = h & 3;
    const int wv = threadIdx.x >> 6;
    const int lane = threadIdx.x & 63;
    const int qh = lane >> 5;         // query within pair
    const int l32 = lane & 31;
    const int kk = l32 >> 2;          // key slot 0..7
    const int dg = lane & 3;          // dim group 0..3
    const int q = qt * 8 + wv * 2 + qh;

    const size_t hq = (size_t)hi * T_SEQ + q;
    const int nv = (int)cnts[hq];
    const int nvm = max(nv, __shfl_xor(nv, 32));   // wave-uniform path choice
    const unsigned short* sp = sidx + hq * KMAXV;
    const unsigned short* Kh = Kb + (size_t)h * T_SEQ * HD + dg * 16;
    const unsigned short* Vh = Vb + (size_t)h * T_SEQ * HD + dg * 16;

    float4 qg[4];
    {
        const float4* qp = (const float4*)(Q + ((size_t)h * T_SEQ + q) * HD + dg * 16);
        qg[0] = qp[0]; qg[1] = qp[1]; qg[2] = qp[2]; qg[3] = qp[3];
    }

    float acc[16];
#pragma unroll
    for (int i = 0; i < 16; ++i) acc[i] = 0.f;
    float l = 0.f;

    if (nvm <= 32) {
        const ushort4 e4 = *(const ushort4*)(sp + kk * 4);
        const unsigned ev[4] = {e4.x, e4.y, e4.z, e4.w};

        float s[4]; int idxs[4];
#pragma unroll
        for (int sub = 0; sub < 4; ++sub) {
            const int kpos = kk * 4 + sub;
            const unsigned e = ev[sub];
            const bool ok = (kpos < nv) && ((e >> (11 + hj)) & 1u);
            const int iv = ok ? (int)(e & 0x7FFu) : 0;
            idxs[sub] = iv;
            const uint4* kr = (const uint4*)(Kh + (size_t)iv * HD);
            uint4 ka = kr[0], kb2 = kr[1];
            float da = 0.f, db = 0.f;
            da = fmaf(qg[0].x, bflo(ka.x), da); da = fmaf(qg[0].y, bfhi(ka.x), da);
            da = fmaf(qg[0].z, bflo(ka.y), da); da = fmaf(qg[0].w, bfhi(ka.y), da);
            db = fmaf(qg[1].x, bflo(ka.z), db); db = fmaf(qg[1].y, bfhi(ka.z), db);
            db = fmaf(qg[1].z, bflo(ka.w), db); db = fmaf(qg[1].w, bfhi(ka.w), db);
            da = fmaf(qg[2].x, bflo(kb2.x), da); da = fmaf(qg[2].y, bfhi(kb2.x), da);
            da = fmaf(qg[2].z, bflo(kb2.y), da); da = fmaf(qg[2].w, bfhi(kb2.y), da);
            db = fmaf(qg[3].x, bflo(kb2.z), db); db = fmaf(qg[3].y, bfhi(kb2.z), db);
            db = fmaf(qg[3].z, bflo(kb2.w), db); db = fmaf(qg[3].w, bfhi(kb2.w), db);
            float dot = da + db;
            dot += __shfl_xor(dot, 1);
            dot += __shfl_xor(dot, 2);
            s[sub] = ok ? dot * 0.125f : -INFINITY;
        }

        float cm = fmaxf(fmaxf(s[0], s[1]), fmaxf(s[2], s[3]));
        cm = fmaxf(cm, __shfl_xor(cm, 4));
        cm = fmaxf(cm, __shfl_xor(cm, 8));
        cm = fmaxf(cm, __shfl_xor(cm, 16));

        float p[4];
        float ls = 0.f;
#pragma unroll
        for (int sub = 0; sub < 4; ++sub) { p[sub] = expf(s[sub] - cm); ls += p[sub]; }
        ls += __shfl_xor(ls, 4);
        ls += __shfl_xor(ls, 8);
        ls += __shfl_xor(ls, 16);
        l = ls;
#pragma unroll
        for (int sub = 0; sub < 4; ++sub) {
            const float pv = p[sub];                         // 0 for masked
            const uint4* vr = (const uint4*)(Vh + (size_t)idxs[sub] * HD);
            uint4 va = vr[0], vb4 = vr[1];
            acc[0]  = fmaf(pv, bflo(va.x), acc[0]);   acc[1]  = fmaf(pv, bfhi(va.x), acc[1]);
            acc[2]  = fmaf(pv, bflo(va.y), acc[2]);   acc[3]  = fmaf(pv, bfhi(va.y), acc[3]);
            acc[4]  = fmaf(pv, bflo(va.z), acc[4]);   acc[5]  = fmaf(pv, bfhi(va.z), acc[5]);
            acc[6]  = fmaf(pv, bflo(va.w), acc[6]);   acc[7]  = fmaf(pv, bfhi(va.w), acc[7]);
            acc[8]  = fmaf(pv, bflo(vb4.x), acc[8]);  acc[9]  = fmaf(pv, bfhi(vb4.x), acc[9]);
            acc[10] = fmaf(pv, bflo(vb4.y), acc[10]); acc[11] = fmaf(pv, bfhi(vb4.y), acc[11]);
            acc[12] = fmaf(pv, bflo(vb4.z), acc[12]); acc[13] = fmaf(pv, bfhi(vb4.z), acc[13]);
            acc[14] = fmaf(pv, bflo(vb4.w), acc[14]); acc[15] = fmaf(pv, bfhi(vb4.w), acc[15]);
        }
    } else {
        float m = -INFINITY;
        for (int base = 0; base < nvm; base += 32) {
            const int nk = nv - base;
            const ushort4 e4 = *(const ushort4*)(sp + base + kk * 4);
            const unsigned ev[4] = {e4.x, e4.y, e4.z, e4.w};

            float s[4]; int idxs[4];
#pragma unroll
            for (int sub = 0; sub < 4; ++sub) {
                const int kpos = kk * 4 + sub;
                const unsigned e = ev[sub];
                const bool ok = (kpos < nk) && ((e >> (11 + hj)) & 1u);
                const int iv = ok ? (int)(e & 0x7FFu) : 0;
                idxs[sub] = iv;
                const uint4* kr = (const uint4*)(Kh + (size_t)iv * HD);
                uint4 ka = kr[0], kb2 = kr[1];
                float da = 0.f, db = 0.f;
                da = fmaf(qg[0].x, bflo(ka.x), da); da = fmaf(qg[0].y, bfhi(ka.x), da);
                da = fmaf(qg[0].z, bflo(ka.y), da); da = fmaf(qg[0].w, bfhi(ka.y), da);
                db = fmaf(qg[1].x, bflo(ka.z), db); db = fmaf(qg[1].y, bfhi(ka.z), db);
                db = fmaf(qg[1].z, bflo(ka.w), db); db = fmaf(qg[1].w, bfhi(ka.w), db);
                da = fmaf(qg[2].x, bflo(kb2.x), da); da = fmaf(qg[2].y, bfhi(kb2.x), da);
                da = fmaf(qg[2].z, bflo(kb2.y), da); da = fmaf(qg[2].w, bfhi(kb2.y), da);
                db = fmaf(qg[3].x, bflo(kb2.z), db); db = fmaf(qg[3].y, bfhi(kb2.z), db);
                db = fmaf(qg[3].z, bflo(kb2.w), db); db = fmaf(qg[3].w, bfhi(kb2.w), db);
                float dot = da + db;
                dot += __shfl_xor(dot, 1);
                dot += __shfl_xor(dot, 2);
                s[sub] = ok ? dot * 0.125f : -INFINITY;
            }

            float cm = fmaxf(fmaxf(s[0], s[1]), fmaxf(s[2], s[3]));
            cm = fmaxf(cm, __shfl_xor(cm, 4));
            cm = fmaxf(cm, __shfl_xor(cm, 8));
            cm = fmaxf(cm, __shfl_xor(cm, 16));
            const float mn = fmaxf(m, cm);
            if (mn > -INFINITY) {
                const float alpha = expf(m - mn);
                float p[4];
                float ls = 0.f;
#pragma unroll
                for (int sub = 0; sub < 4; ++sub) { p[sub] = expf(s[sub] - mn); ls += p[sub]; }
                ls += __shfl_xor(ls, 4);
                ls += __shfl_xor(ls, 8);
                ls += __shfl_xor(ls, 16);
                l = l * alpha + ls;
#pragma unroll
                for (int i = 0; i < 16; ++i) acc[i] *= alpha;
#pragma unroll
                for (int sub = 0; sub < 4; ++sub) {
                    const float pv = p[sub];
                    const uint4* vr = (const uint4*)(Vh + (size_t)idxs[sub] * HD);
                    uint4 va = vr[0], vb4 = vr[1];
                    acc[0]  = fmaf(pv, bflo(va.x), acc[0]);   acc[1]  = fmaf(pv, bfhi(va.x), acc[1]);
                    acc[2]  = fmaf(pv, bflo(va.y), acc[2]);   acc[3]  = fmaf(pv, bfhi(va.y), acc[3]);
                    acc[4]  = fmaf(pv, bflo(va.z), acc[4]);   acc[5]  = fmaf(pv, bfhi(va.z), acc[5]);
                    acc[6]  = fmaf(pv, bflo(va.w), acc[6]);   acc[7]  = fmaf(pv, bfhi(va.w), acc[7]);
                    acc[8]  = fmaf(pv, bflo(vb4.x), acc[8]);  acc[9]  = fmaf(pv, bfhi(vb4.x), acc[9]);
                    acc[10] = fmaf(pv, bflo(vb4.y), acc[10]); acc[11] = fmaf(pv, bfhi(vb4.y), acc[11]);
                    acc[12] = fmaf(pv, bflo(vb4.z), acc[12]); acc[13] = fmaf(pv, bfhi(vb4.z), acc[13]);
                    acc[14] = fmaf(pv, bflo(vb4.w), acc[14]); acc[15] = fmaf(pv, bfhi(vb4.w), acc[15]);
                }
                m = mn;
            }
        }
    }

#pragma unroll
    for (int i = 0; i < 16; ++i) {
        acc[i] += __shfl_xor(acc[i], 4);
        acc[i] += __shfl_xor(acc[i], 8);
        acc[i] += __shfl_xor(acc[i], 16);
    }
    const float invl = 1.f / l;
    float oval0 = acc[0], oval1 = acc[1];
#pragma unroll
    for (int i = 1; i < 8; ++i)
        if (kk == i) { oval0 = acc[2 * i]; oval1 = acc[2 * i + 1]; }
    const int d0 = dg * 16 + kk * 2;
    const ushort2 g2 = *(const ushort2*)(lincatb + (size_t)q * NCAT + 4096 + h * HD + d0);
    ushort2 o2;
    o2.x = f2bf(oval0 * invl * sigf(bf16f(g2.x)));
    o2.y = f2bf(oval1 * invl * sigf(bf16f(g2.y)));
    *(ushort2*)(ogb + (size_t)q * C_DIM + h * HD + d0) = o2;
}

extern "C" void kernel_launch(void* const* d_in, const int* in_sizes, int n_in,
                              void* d_out, int out_size, void* d_ws, size_t ws_size,
                              hipStream_t stream)
{
    const float* x   = (const float*)d_in[0];
    const float* WIq = (const float*)d_in[1];
    const float* WIk = (const float*)d_in[2];
    const float* WIw = (const float*)d_in[3];
    const float* gb  = (const float*)d_in[4];
    const float* hib = (const float*)d_in[5];
    const float* Wq  = (const float*)d_in[6];
    const float* Wk  = (const float*)d_in[7];
    const float* Wv  = (const float*)d_in[8];
    const float* Wgv = (const float*)d_in[9];
    const float* Wgo = (const float*)d_in[10];
    const float* Wo  = (const float*)d_in[11];
    float* out = (float*)d_out;

    char* ws = (char*)d_ws;
    const size_t MB = 1024 * 1024;
    float*    qI     = (float*)(ws + 0 * MB);                 // 1 MB
    float*    kI     = (float*)(ws + 1 * MB);                 // 1 MB
    float*    wsig   = (float*)(ws + 2 * MB);                 // 32 KB
    unsigned* cnts   = (unsigned*)(ws + 2 * MB + 64 * 1024);  // 32 KB
    float*    cost   = (float*)(ws + 2 * MB + 512 * 1024);    // 256 KB
    float*    sint   = (float*)(ws + 2 * MB + 768 * 1024);    // 256 KB
    float*    Q      = (float*)(ws + 3 * MB);                 // 8 MB  -> 11
    unsigned short* Kb = (unsigned short*)(ws + 11 * MB);     // 4 MB  -> 15
    unsigned short* Vb = (unsigned short*)(ws + 15 * MB);     // 4 MB  -> 19
    unsigned short* sidx = (unsigned short*)(ws + 19 * MB);   // 16 MB -> 35
    // region A (35..71): part (16 MB, K1 write / K2 read) -> imp (35.7 MB, K3 write / K4 read)
    float*    part    = (float*)(ws + 35 * MB);
    float*    imp     = (float*)(ws + 35 * MB);
    unsigned short* lincatb = (unsigned short*)(ws + 71 * MB);// 20 MB -> 91 (written K3)
    unsigned short* ogb   = (unsigned short*)(ws + 91 * MB);  // 4 MB  -> 95
    unsigned short* xb    = (unsigned short*)(ws + 95 * MB);  // 4 MB  -> 99
    unsigned short* Wcatb = (unsigned short*)(ws + 99 * MB);  // 10 MB -> 109
    unsigned short* Wob   = (unsigned short*)(ws + 109 * MB); // 2 MB  -> 111

    // K1: qik_splitk8_m64 (heavy first, 2 blocks/CU) + rope_table + proj_w + convert_all
    pre_kernel<<<dim3(9088), 256, 0, stream>>>(
        x, WIq, WIk, WIw, Wq, Wk, Wv, Wgv, Wgo, Wo,
        xb, Wcatb, Wob, part, wsig, cost, sint);
    // K2
    qik_reduce_kernel<<<dim3(2048), 256, 0, stream>>>(part, qI, kI);
    // K3: proj-GEMM (bf16 out) then impA (contiguous GEMM tiles for L2 locality)
    mid_kernel<<<dim3(1184), 256, 0, stream>>>(
        xb, Wcatb, lincatb, qI, kI, wsig, gb, imp);
    // K4: impB + rope_v
    sel_kernel<<<dim3(6144), 256, 0, stream>>>(
        imp, hib, sidx, cnts, lincatb, cost, sint, Q, Kb, Vb);
    // attention + out-projection
    attn_sparse_kernel<<<dim3(256, 16), 256, 0, stream>>>(Q, Kb, Vb, sidx, cnts, lincatb, ogb);
    // out-projection: 128x64 tiles, 256 blocks = 1/CU (was 128 blocks = 0.5/CU)
    gemm_out_kernel<<<dim3(16, 16), 256, 0, stream>>>(ogb, Wob, out, C_DIM);
}

// Round 26
// 158.752 us; speedup vs baseline: 1.0471x; 1.0062x over previous
//
#include <hip/hip_runtime.h>
#include <math.h>

#define T_SEQ 2048
#define C_DIM 1024
#define NH    16
#define HD    64
#define HIN   4
#define DI    32
#define SINKN 4
#define KMINV 32
#define KMAXV 1024
#define NCAT  5120   // q|k|v|gv|go concatenated columns
#define IMPH  2228224 // packed-triangular imp floats per indexer head

typedef __bf16 bf16x8 __attribute__((ext_vector_type(8)));
typedef float  f32x4  __attribute__((ext_vector_type(4)));

__device__ __forceinline__ float sigf(float x) { return 1.f / (1.f + expf(-x)); }

__device__ __forceinline__ unsigned short f2bf(float f) {
    unsigned u = __float_as_uint(f);
    unsigned r = (u + 0x7FFFu + ((u >> 16) & 1u)) >> 16;   // RNE
    return (unsigned short)r;
}

__device__ __forceinline__ float bflo(unsigned u) { return __uint_as_float(u << 16); }
__device__ __forceinline__ float bfhi(unsigned u) { return __uint_as_float(u & 0xFFFF0000u); }
__device__ __forceinline__ float bf16f(unsigned short u) { return __uint_as_float((unsigned)u << 16); }

__device__ __forceinline__ void gload16(const unsigned short* g, unsigned short* l) {
    __builtin_amdgcn_global_load_lds(
        (const __attribute__((address_space(1))) unsigned int*)(const unsigned int*)g,
        (__attribute__((address_space(3))) unsigned int*)(unsigned int*)l,
        16, 0, 0);
}

// ---------------- bf16 MFMA GEMM body: C = A_bf16 @ B_bf16^T (128x128 tile) ---
template<bool OUT_BF16>
__device__ __forceinline__ void gemm_body(
    char* smemc,
    const unsigned short* __restrict__ A, const unsigned short* __restrict__ B,
    void* __restrict__ Cv, int ldc, int bx, int by)
{
    unsigned short* Asl = (unsigned short*)smemc;          // 16384 B
    unsigned short* Bsl = (unsigned short*)(smemc + 16384);// 16384 B
    const int K = C_DIM;
    const int tid = threadIdx.x;
    const int w = tid >> 6, lane = tid & 63;
    const int wm = w >> 1, wn = w & 1;
    const int m0 = by * 128, n0 = bx * 128;

    const f32x4 z4 = {0.f, 0.f, 0.f, 0.f};
    f32x4 acc[4][4];
#pragma unroll
    for (int i = 0; i < 4; ++i)
#pragma unroll
        for (int j = 0; j < 4; ++j) acc[i][j] = z4;

    const int lrow  = w * 8 + (lane >> 3);
    const int lslot = (lane & 7) ^ (lane >> 3);
    const unsigned short* Ag = A + (size_t)(m0 + lrow) * K + lslot * 8;
    const unsigned short* Bg = B + (size_t)(n0 + lrow) * K + lslot * 8;

    const int fr = lane & 15;
    const int kg = lane >> 4;

    for (int kt = 0; kt < K; kt += 64) {
        __syncthreads();
#pragma unroll
        for (int i = 0; i < 4; ++i) {
            gload16(Ag + (size_t)(i * 32) * K + kt, &Asl[(i * 32 + w * 8) * 64]);
            gload16(Bg + (size_t)(i * 32) * K + kt, &Bsl[(i * 32 + w * 8) * 64]);
        }
        __syncthreads();
#pragma unroll
        for (int ks = 0; ks < 2; ++ks) {
            bf16x8 af[4], bfr[4];
            const int aslot = ks * 4 + kg;
#pragma unroll
            for (int f = 0; f < 4; ++f) {
                const int arow = wm * 64 + f * 16 + fr;
                af[f] = *(const bf16x8*)&Asl[arow * 64 + ((aslot ^ (arow & 7)) * 8)];
                const int brow = wn * 64 + f * 16 + fr;
                bfr[f] = *(const bf16x8*)&Bsl[brow * 64 + ((aslot ^ (brow & 7)) * 8)];
            }
#pragma unroll
            for (int mi = 0; mi < 4; ++mi)
#pragma unroll
                for (int ni = 0; ni < 4; ++ni)
                    acc[mi][ni] = __builtin_amdgcn_mfma_f32_16x16x32_bf16(
                        af[mi], bfr[ni], acc[mi][ni], 0, 0, 0);
        }
    }

#pragma unroll
    for (int mi = 0; mi < 4; ++mi) {
        const int row = by * 128 + wm * 64 + mi * 16 + (lane >> 4) * 4;
#pragma unroll
        for (int ni = 0; ni < 4; ++ni) {
            const int col = bx * 128 + wn * 64 + ni * 16 + (lane & 15);
            if constexpr (OUT_BF16) {
                unsigned short* cp = (unsigned short*)Cv + (size_t)row * ldc + col;
#pragma unroll
                for (int r = 0; r < 4; ++r) cp[(size_t)r * ldc] = f2bf(acc[mi][ni][r]);
            } else {
                float* cp = (float*)Cv + (size_t)row * ldc + col;
#pragma unroll
                for (int r = 0; r < 4; ++r) cp[(size_t)r * ldc] = acc[mi][ni][r];
            }
        }
    }
}

// ---------------- out-projection body: 128x64 tile, f32 out --------------------
__device__ __forceinline__ void gemm_out_body(
    char* smemc,
    const unsigned short* __restrict__ A, const unsigned short* __restrict__ B,
    float* __restrict__ C, int ldc, int bx, int by)
{
    unsigned short* Asl = (unsigned short*)smemc;          // 128*64*2 = 16384 B
    unsigned short* Bsl = (unsigned short*)(smemc + 16384);// 64*64*2  =  8192 B
    const int K = C_DIM;
    const int tid = threadIdx.x;
    const int w = tid >> 6, lane = tid & 63;
    const int wm = w >> 1, wn = w & 1;
    const int m0 = by * 128, n0 = bx * 64;

    const f32x4 z4 = {0.f, 0.f, 0.f, 0.f};
    f32x4 acc[4][2];
#pragma unroll
    for (int i = 0; i < 4; ++i)
#pragma unroll
        for (int j = 0; j < 2; ++j) acc[i][j] = z4;

    const int lrow  = w * 8 + (lane >> 3);
    const int lslot = (lane & 7) ^ (lane >> 3);
    const unsigned short* Ag = A + (size_t)(m0 + lrow) * K + lslot * 8;
    const unsigned short* Bg = B + (size_t)(n0 + lrow) * K + lslot * 8;

    const int fr = lane & 15;
    const int kg = lane >> 4;

    for (int kt = 0; kt < K; kt += 64) {
        __syncthreads();
#pragma unroll
        for (int i = 0; i < 4; ++i)
            gload16(Ag + (size_t)(i * 32) * K + kt, &Asl[(i * 32 + w * 8) * 64]);
#pragma unroll
        for (int i = 0; i < 2; ++i)
            gload16(Bg + (size_t)(i * 32) * K + kt, &Bsl[(i * 32 + w * 8) * 64]);
        __syncthreads();
#pragma unroll
        for (int ks = 0; ks < 2; ++ks) {
            bf16x8 af[4], bfr[2];
            const int aslot = ks * 4 + kg;
#pragma unroll
            for (int f = 0; f < 4; ++f) {
                const int arow = wm * 64 + f * 16 + fr;
                af[f] = *(const bf16x8*)&Asl[arow * 64 + ((aslot ^ (arow & 7)) * 8)];
            }
#pragma unroll
            for (int f = 0; f < 2; ++f) {
                const int brow = wn * 32 + f * 16 + fr;
                bfr[f] = *(const bf16x8*)&Bsl[brow * 64 + ((aslot ^ (brow & 7)) * 8)];
            }
#pragma unroll
            for (int mi = 0; mi < 4; ++mi)
#pragma unroll
                for (int ni = 0; ni < 2; ++ni)
                    acc[mi][ni] = __builtin_amdgcn_mfma_f32_16x16x32_bf16(
                        af[mi], bfr[ni], acc[mi][ni], 0, 0, 0);
        }
    }

#pragma unroll
    for (int mi = 0; mi < 4; ++mi) {
        const int row = m0 + wm * 64 + mi * 16 + (lane >> 4) * 4;
#pragma unroll
        for (int ni = 0; ni < 2; ++ni) {
            const int col = n0 + wn * 32 + ni * 16 + (lane & 15);
            float* cp = C + (size_t)row * ldc + col;
#pragma unroll
            for (int r = 0; r < 4; ++r) cp[(size_t)r * ldc] = acc[mi][ni][r];
        }
    }
}

// standalone final out-projection (f32 out), 256 blocks 1D, XCD-swizzled
__global__ __launch_bounds__(256) void gemm_out_kernel(
    const unsigned short* __restrict__ A, const unsigned short* __restrict__ B,
    float* __restrict__ C, int ldc)
{
    __shared__ __align__(16) char smem[24576];
    const int b = blockIdx.x;                 // 256 = 8 x 32
    const int swz = (b & 7) * 32 + (b >> 3);  // contiguous chunk per XCD
    gemm_out_body(smem, A, B, C, ldc, swz & 15, swz >> 4);
}

// ---------------- component bodies ---------------------------------------------
__device__ __forceinline__ void convert_body(
    int b, const float* __restrict__ x,
    const float* __restrict__ Wq, const float* __restrict__ Wk, const float* __restrict__ Wv,
    const float* __restrict__ Wgv, const float* __restrict__ Wgo, const float* __restrict__ Wo,
    unsigned short* __restrict__ xb, unsigned short* __restrict__ Wcatb,
    unsigned short* __restrict__ Wob)
{
    const float* s; unsigned short* d; size_t off;
    if (b < 2048)      { s = x;  d = xb;  off = (size_t)b * 1024; }
    else if (b < 7168) {
        const int wsel = (b - 2048) >> 10;
        switch (wsel) {
            case 0: s = Wq;  break;
            case 1: s = Wk;  break;
            case 2: s = Wv;  break;
            case 3: s = Wgv; break;
            default: s = Wgo; break;
        }
        d = Wcatb + ((size_t)wsel << 20);
        off = (size_t)((b - 2048) & 1023) * 1024;
    } else             { s = Wo; d = Wob; off = (size_t)(b - 7168) * 1024; }

    const size_t i = off + threadIdx.x * 4;
    const float4 v = *(const float4*)(s + i);
    ushort4 o;
    o.x = f2bf(v.x); o.y = f2bf(v.y); o.z = f2bf(v.z); o.w = f2bf(v.w);
    *(ushort4*)(d + i) = o;
}

__device__ __forceinline__ void proj_w_body(
    int b, const float* __restrict__ x, const float* __restrict__ WIw,
    float* __restrict__ wsig)
{
    const int idx4 = b * 256 + threadIdx.x;
    const int part4 = idx4 & 3;
    const int oidx = idx4 >> 2;      // t*4 + hi
    const int t = oidx >> 2, hi = oidx & 3;
    const float4* xr = (const float4*)(x + (size_t)t * C_DIM + part4 * 256);
    const float4* wr = (const float4*)(WIw + (size_t)hi * C_DIM + part4 * 256);
    float s = 0.f;
#pragma unroll
    for (int i = 0; i < 64; ++i) {
        float4 a = xr[i], w4 = wr[i];
        s += a.x * w4.x + a.y * w4.y + a.z * w4.z + a.w * w4.w;
    }
    s += __shfl_xor(s, 1);
    s += __shfl_xor(s, 2);
    if (part4 == 0) wsig[oidx] = sigf(s);
}

__device__ __forceinline__ void rope_table_body(
    int b, float* __restrict__ cost, float* __restrict__ sint)
{
    const int idx = b * 256 + threadIdx.x;   // t*32 + i
    const int t = idx >> 5, i = idx & 31;
    const int j = (2 * i) & 31;
    const float invf = powf(10000.f, -(float)j / 32.f);
    const float f = (float)t * invf;
    float sv, cv;
    sincosf(f, &sv, &cv);
    cost[idx] = cv;
    sint[idx] = sv;
}

// split-K 8 + split-M 64: 32 mt x 2 which x 8 s = 512 blocks (2/CU).
__device__ __forceinline__ void qik_body(
    char* smemc, int which, int s, int mt,
    const float* __restrict__ x, const float* __restrict__ WIq, const float* __restrict__ WIk,
    float* __restrict__ part)
{
    float (*As)[68]  = (float(*)[68])smemc;              // 16*68*4  = 4352 B
    float (*Bs)[132] = (float(*)[132])(smemc + 4352);    // 16*132*4 = 8448 B
    const float* B = which ? WIk : WIq;
    const int m0 = mt * 64;
    const int kb = s * 128;
    const int tid = threadIdx.x;
    const int tx = tid & 15, ty = tid >> 4;

    float acc[4][8];
#pragma unroll
    for (int i = 0; i < 4; ++i)
#pragma unroll
        for (int j = 0; j < 8; ++j) acc[i][j] = 0.f;

    const int srA = tid >> 2;            // 0..63
    const int skA = (tid & 3) * 4;       // 0,4,8,12
    const int srB = tid >> 1;            // 0..127
    const int skB = (tid & 1) * 8;       // 0,8
    const float* Ap = x + (size_t)(m0 + srA) * C_DIM + kb + skA;
    const float* Bp = B + (size_t)srB * C_DIM + kb + skB;

    for (int k0 = 0; k0 < 128; k0 += 16) {
        float4 a0 = *(const float4*)(Ap + k0);
        float4 b0 = *(const float4*)(Bp + k0);
        float4 b1 = *(const float4*)(Bp + k0 + 4);
        __syncthreads();
        As[skA + 0][srA] = a0.x; As[skA + 1][srA] = a0.y;
        As[skA + 2][srA] = a0.z; As[skA + 3][srA] = a0.w;
        Bs[skB + 0][srB] = b0.x; Bs[skB + 1][srB] = b0.y; Bs[skB + 2][srB] = b0.z; Bs[skB + 3][srB] = b0.w;
        Bs[skB + 4][srB] = b1.x; Bs[skB + 5][srB] = b1.y; Bs[skB + 6][srB] = b1.z; Bs[skB + 7][srB] = b1.w;
        __syncthreads();
#pragma unroll
        for (int kk = 0; kk < 16; ++kk) {
            float4 aA = *(const float4*)&As[kk][ty * 4];
            float4 bA = *(const float4*)&Bs[kk][tx * 4];
            float4 bB = *(const float4*)&Bs[kk][64 + tx * 4];
            float am[4] = {aA.x, aA.y, aA.z, aA.w};
            float bn[8] = {bA.x, bA.y, bA.z, bA.w, bB.x, bB.y, bB.z, bB.w};
#pragma unroll
            for (int i = 0; i < 4; ++i)
#pragma unroll
                for (int j = 0; j < 8; ++j) acc[i][j] = fmaf(am[i], bn[j], acc[i][j]);
        }
    }

    float* cp0 = part + (size_t)(which * 8 + s) * T_SEQ * 128;
#pragma unroll
    for (int i = 0; i < 4; ++i) {
        const int row = m0 + ty * 4 + i;
        float* cp = cp0 + (size_t)row * 128;
        float4 v0 = make_float4(acc[i][0], acc[i][1], acc[i][2], acc[i][3]);
        float4 v1 = make_float4(acc[i][4], acc[i][5], acc[i][6], acc[i][7]);
        *(float4*)(cp + tx * 4) = v0;
        *(float4*)(cp + 64 + tx * 4) = v1;
    }
}

// ---------------- K1: qik_splitk8_m64 (heavy, first) + rope_table + proj_w + convert
__global__ __launch_bounds__(256) void pre_kernel(
    const float* __restrict__ x,
    const float* __restrict__ WIq, const float* __restrict__ WIk, const float* __restrict__ WIw,
    const float* __restrict__ Wq, const float* __restrict__ Wk, const float* __restrict__ Wv,
    const float* __restrict__ Wgv, const float* __restrict__ Wgo, const float* __restrict__ Wo,
    unsigned short* __restrict__ xb, unsigned short* __restrict__ Wcatb,
    unsigned short* __restrict__ Wob,
    float* __restrict__ part, float* __restrict__ wsig,
    float* __restrict__ cost, float* __restrict__ sint)
{
    __shared__ __align__(16) char smem[16896];
    const int b = blockIdx.x;
    if (b < 512) {
        // XCD swizzle (512 = 8 x 64): same-mt blocks (sharing x panels) per XCD
        const int swz = (b & 7) * 64 + (b >> 3);
        qik_body(smem, swz & 1, (swz >> 1) & 7, swz >> 4, x, WIq, WIk, part);
    } else if (b < 768) {
        rope_table_body(b - 512, cost, sint);
    } else if (b < 896) {
        proj_w_body(b - 768, x, WIw, wsig);
    } else {
        convert_body(b - 896, x, Wq, Wk, Wv, Wgv, Wgo, Wo, xb, Wcatb, Wob);
    }
}

__global__ void qik_reduce_kernel(const float* __restrict__ part,
                                  float* __restrict__ qI, float* __restrict__ kI)
{
    const int idx = blockIdx.x * 256 + threadIdx.x;   // 0..524287
    const int which = idx >> 18;
    const int e = idx & 262143;
    const float* p = part + (size_t)which * 8 * T_SEQ * 128 + e;
    float s = 0.f;
#pragma unroll
    for (int j = 0; j < 8; ++j) s += p[(size_t)j * T_SEQ * 128];
    (which ? kI : qI)[e] = s;
}

// ---------------- impA body: causal-tiled f32 GEMM -> packed-triangular imp ----
__device__ __forceinline__ void impA_body(
    char* smemc,
    const float* __restrict__ qI, const float* __restrict__ kI,
    const float* __restrict__ wsig, const float* __restrict__ gate_bias,
    float* __restrict__ imp, int t, int hi)
{
    float (*As)[132] = (float(*)[132])smemc;             // 16896 B
    float (*Bs)[132] = (float(*)[132])(smemc + 16896);   // 16896 B
    int qi = (int)((sqrtf(8.f * (float)t + 1.f) - 1.f) * 0.5f);
    if ((qi + 1) * (qi + 2) / 2 <= t) qi++;
    if (qi * (qi + 1) / 2 > t) qi--;
    const int ki = t - qi * (qi + 1) / 2;
    const int m0 = qi * 128;

    const int tid = threadIdx.x;
    const int tx = tid & 15, ty = tid >> 4;

    {
        const int sr = tid >> 1;
        const int sk = (tid & 1) * 16;
        const float4* Ap = (const float4*)(qI + (size_t)(m0 + sr) * 128 + hi * 32 + sk);
        const float4* Bp = (const float4*)(kI + (size_t)(ki * 128 + sr) * 128 + hi * 32 + sk);
#pragma unroll
        for (int j4 = 0; j4 < 4; ++j4) {
            float4 a = Ap[j4], b = Bp[j4];
            As[sk + j4*4 + 0][sr] = a.x; As[sk + j4*4 + 1][sr] = a.y;
            As[sk + j4*4 + 2][sr] = a.z; As[sk + j4*4 + 3][sr] = a.w;
            Bs[sk + j4*4 + 0][sr] = b.x; Bs[sk + j4*4 + 1][sr] = b.y;
            Bs[sk + j4*4 + 2][sr] = b.z; Bs[sk + j4*4 + 3][sr] = b.w;
        }
    }
    __syncthreads();

    float acc[8][8];
#pragma unroll
    for (int i = 0; i < 8; ++i)
#pragma unroll
        for (int j = 0; j < 8; ++j) acc[i][j] = 0.f;

#pragma unroll
    for (int kk = 0; kk < 32; ++kk) {
        float4 aA = *(const float4*)&As[kk][ty * 4];
        float4 aB = *(const float4*)&As[kk][64 + ty * 4];
        float4 bA = *(const float4*)&Bs[kk][tx * 4];
        float4 bB = *(const float4*)&Bs[kk][64 + tx * 4];
        float am[8] = {aA.x, aA.y, aA.z, aA.w, aB.x, aB.y, aB.z, aB.w};
        float bn[8] = {bA.x, bA.y, bA.z, bA.w, bB.x, bB.y, bB.z, bB.w};
#pragma unroll
        for (int i = 0; i < 8; ++i)
#pragma unroll
            for (int j = 0; j < 8; ++j) acc[i][j] = fmaf(am[i], bn[j], acc[i][j]);
    }

    const float gb = gate_bias[hi];
    const size_t rw = (size_t)(qi + 1) * 128;
    float* impb = imp + (size_t)hi * IMPH + (size_t)16384 * (qi * (qi + 1) / 2) + ki * 128;
#pragma unroll
    for (int ih = 0; ih < 2; ++ih)
#pragma unroll
        for (int i = 0; i < 4; ++i) {
            const int rr = ih * 64 + ty * 4 + i;
            const float wr = wsig[(m0 + rr) * 4 + hi];
            float* cp = impb + (size_t)rr * rw;
            float4 v0, v1;
            v0.x = wr * sigf(acc[ih*4+i][0] + gb);
            v0.y = wr * sigf(acc[ih*4+i][1] + gb);
            v0.z = wr * sigf(acc[ih*4+i][2] + gb);
            v0.w = wr * sigf(acc[ih*4+i][3] + gb);
            v1.x = wr * sigf(acc[ih*4+i][4] + gb);
            v1.y = wr * sigf(acc[ih*4+i][5] + gb);
            v1.z = wr * sigf(acc[ih*4+i][6] + gb);
            v1.w = wr * sigf(acc[ih*4+i][7] + gb);
            *(float4*)(cp + tx * 4) = v0;
            *(float4*)(cp + 64 + tx * 4) = v1;
        }
}

// ---------------- K3: proj-GEMM (bf16 out) then impA, both XCD-swizzled --------
__global__ __launch_bounds__(256) void mid_kernel(
    const unsigned short* __restrict__ xb, const unsigned short* __restrict__ Wcatb,
    unsigned short* __restrict__ lincatb,
    const float* __restrict__ qI, const float* __restrict__ kI,
    const float* __restrict__ wsig, const float* __restrict__ gate_bias,
    float* __restrict__ imp)
{
    __shared__ __align__(16) char smem[33792];
    const int b = blockIdx.x;
    if (b < 640) {
        // XCD swizzle (640 = 8 x 80): contiguous tile chunk per XCD -> A/B panel
        // reuse in that XCD's private L2 (keeps r19's contiguous-phase order).
        const int g = (b & 7) * 80 + (b >> 3);
        gemm_body<true>(smem, xb, Wcatb, lincatb, NCAT, g % 40, g / 40);
    } else {
        const int bb = b - 640;
        // XCD swizzle (544 = 8 x 68)
        const int a = (bb & 7) * 68 + (bb >> 3);
        impA_body(smem, qI, kI, wsig, gate_bias, imp, a % 136, a / 136);
    }
}

// ---------------- impB body: var -> k_t, threshold binary search, emission ----
template<int NC>
__device__ __forceinline__ void impB_body(
    const float* __restrict__ imp, const float* __restrict__ head_bias,
    unsigned short* __restrict__ sidxg, unsigned* __restrict__ cnts,
    int q, int hi, int lane)
{
    const int qc = q >> 6;   // last causal chunk (wave-uniform)
    const unsigned long long lmask_lt = (lane == 0) ? 0ull : ((~0ull) >> (64 - lane));

    const int qi = q >> 7;
    const size_t rw = (size_t)(qi + 1) * 128;
    const float* row = imp + (size_t)hi * IMPH +
                       (size_t)16384 * (qi * (qi + 1) / 2) + (size_t)(q - qi * 128) * rw;

    unsigned ordv[NC];
    double dsum = 0.0, dsq = 0.0;
#pragma unroll
    for (int i = 0; i < NC; ++i) {
        const int k = i * 64 + lane;
        unsigned vb = 0u;
        if (i <= qc) {
            const float v = row[k];
            const bool causal = (k <= q);
            const float vm = causal ? v : 0.f;
            dsum += (double)vm;
            dsq  += (double)vm * (double)vm;
            vb = causal ? __float_as_uint(v) : 0u;
        }
        if (i == 0 && lane < SINKN) vb = 0x7F800000u;
        ordv[i] = vb;
    }

#pragma unroll
    for (int off = 1; off < 64; off <<= 1) {
        dsum += __shfl_xor(dsum, off);
        dsq  += __shfl_xor(dsq, off);
    }

    int kts[4];
#pragma unroll
    for (int j = 0; j < 4; ++j) {
        const float sh = sigf(head_bias[hi * 4 + j]);
        const double mean = dsum / (double)T_SEQ;
        double var = dsq / (double)T_SEQ - mean * mean;
        if (var < 0.0) var = 0.0;
        const double vh = var * (double)sh * (double)sh;
        int kt = (int)floor(512.0 * vh);
        kt = kt < KMINV ? KMINV : (kt > KMAXV ? KMAXV : kt);
        kts[j] = kt;
    }

    unsigned vs[4]; int tt[4];
#pragma unroll
    for (int j = 0; j < 4; ++j) {
        bool dup = false;
#pragma unroll
        for (int p = 0; p < 4; ++p) {
            if (p < j && !dup && kts[p] == kts[j]) { vs[j] = vs[p]; tt[j] = tt[p]; dup = true; }
        }
        if (!dup) {
            const int kt = kts[j];
            unsigned X = 0;
#pragma unroll 1
            for (int b = 30; b >= 0; --b) {
                const unsigned Xt = X | (1u << b);
                int c = 0;
#pragma unroll
                for (int i = 0; i < NC; ++i)
                    c += (int)__popcll(__ballot(ordv[i] >= Xt));
                if (c >= kt) X = Xt;
            }
            int cg = 0;
#pragma unroll
            for (int i = 0; i < NC; ++i)
                cg += (int)__popcll(__ballot(ordv[i] > X));
            vs[j] = X; tt[j] = kt - cg;
        }
    }

    unsigned cnt = 0;
    unsigned short* sp = sidxg + ((size_t)hi * T_SEQ + q) * KMAXV;
    const bool uni = (kts[0] == kts[1]) && (kts[1] == kts[2]) && (kts[2] == kts[3]);

    if (uni) {
        int eqr = 0;
        const unsigned v0 = vs[0]; const int t0 = tt[0];
#pragma unroll
        for (int i = 0; i < NC; ++i) {
            const int k = i * 64 + lane;
            const unsigned x = ordv[i];
            const bool eq = (x == v0);
            const unsigned long long beq = __ballot(eq);
            const bool sel = (x > v0) || (eq && (eqr + (int)__popcll(beq & lmask_lt) < t0));
            eqr += (int)__popcll(beq);
            const bool valid = (k <= q) && sel;
            const unsigned long long bv = __ballot(valid);
            if (valid) {
                const unsigned pos = cnt + (unsigned)__popcll(bv & lmask_lt);
                if (pos < KMAXV) sp[pos] = (unsigned short)((unsigned)k | (0xFu << 11));
            }
            cnt += (unsigned)__popcll(bv);
        }
    } else {
        int eqr0 = 0, eqr1 = 0, eqr2 = 0, eqr3 = 0;
#pragma unroll
        for (int i = 0; i < NC; ++i) {
            const int k = i * 64 + lane;
            const unsigned x = ordv[i];
            unsigned mask = 0;
            {
                const bool eq = (x == vs[0]);
                const unsigned long long beq = __ballot(eq);
                const bool sel = (x > vs[0]) || (eq && (eqr0 + (int)__popcll(beq & lmask_lt) < tt[0]));
                eqr0 += (int)__popcll(beq);
                if (sel) mask |= 1u;
            }
            {
                const bool eq = (x == vs[1]);
                const unsigned long long beq = __ballot(eq);
                const bool sel = (x > vs[1]) || (eq && (eqr1 + (int)__popcll(beq & lmask_lt) < tt[1]));
                eqr1 += (int)__popcll(beq);
                if (sel) mask |= 2u;
            }
            {
                const bool eq = (x == vs[2]);
                const unsigned long long beq = __ballot(eq);
                const bool sel = (x > vs[2]) || (eq && (eqr2 + (int)__popcll(beq & lmask_lt) < tt[2]));
                eqr2 += (int)__popcll(beq);
                if (sel) mask |= 4u;
            }
            {
                const bool eq = (x == vs[3]);
                const unsigned long long beq = __ballot(eq);
                const bool sel = (x > vs[3]) || (eq && (eqr3 + (int)__popcll(beq & lmask_lt) < tt[3]));
                eqr3 += (int)__popcll(beq);
                if (sel) mask |= 8u;
            }
            const bool valid = (k <= q) && (mask != 0u);
            const unsigned long long bv = __ballot(valid);
            if (valid) {
                const unsigned pos = cnt + (unsigned)__popcll(bv & lmask_lt);
                if (pos < KMAXV) sp[pos] = (unsigned short)((unsigned)k | (mask << 11));
            }
            cnt += (unsigned)__popcll(bv);
        }
    }
    if (lane == 0) cnts[(size_t)hi * T_SEQ + q] = cnt < KMAXV ? cnt : KMAXV;
}

__device__ __forceinline__ void rope_v_body(
    int b, const unsigned short* __restrict__ lincatb,
    const float* __restrict__ cost, const float* __restrict__ sint,
    float* __restrict__ Q, unsigned short* __restrict__ Kb, unsigned short* __restrict__ Vb)
{
    const int idx = b * 256 + threadIdx.x;   // (t*16+h)*32 + i
    const int i = idx & 31;
    const int h = (idx >> 5) & 15;
    const int t = idx >> 9;
    const float cv = cost[t * 32 + i], sv = sint[t * 32 + i];
    const size_t src = (size_t)t * NCAT + h * HD + 2 * i;
    const ushort2 q2 = *(const ushort2*)(lincatb + src);
    const ushort2 k2 = *(const ushort2*)(lincatb + src + 1024);
    const ushort2 v2 = *(const ushort2*)(lincatb + src + 2048);
    const ushort2 g2 = *(const ushort2*)(lincatb + src + 3072);
    const float qx = bf16f(q2.x), qy = bf16f(q2.y);
    const float kx = bf16f(k2.x), ky = bf16f(k2.y);
    const float vx = bf16f(v2.x), vy = bf16f(v2.y);
    const float gx = bf16f(g2.x), gy = bf16f(g2.y);
    const size_t dst = ((size_t)h * T_SEQ + t) * HD;
    Q[dst + i]      = qx * cv - qy * sv;
    Q[dst + 32 + i] = qx * sv + qy * cv;
    Kb[dst + i]      = f2bf(kx * cv - ky * sv);
    Kb[dst + 32 + i] = f2bf(kx * sv + ky * cv);
    ushort2 vo;
    vo.x = f2bf(vx * sigf(gx));
    vo.y = f2bf(vy * sigf(gy));
    *(ushort2*)(Vb + dst + 2 * i) = vo;
}

// ---------------- K4: impB (LPT bands first) + rope_v -------------------------
__global__ __launch_bounds__(256) void sel_kernel(
    const float* __restrict__ imp, const float* __restrict__ head_bias,
    unsigned short* __restrict__ sidxg, unsigned* __restrict__ cnts,
    const unsigned short* __restrict__ lincatb,
    const float* __restrict__ cost, const float* __restrict__ sint,
    float* __restrict__ Q, unsigned short* __restrict__ Kb, unsigned short* __restrict__ Vb)
{
    const int b = blockIdx.x;
    if (b < 2048) {
        const int bx = b & 511;
        const int hi = b >> 9;
        const int wv = threadIdx.x >> 6;
        const int lane = threadIdx.x & 63;
        const int band = 7 - (bx >> 6);   // LPT: heaviest first
        const int bxx = bx & 63;
        const int q = band * 256 + bxx * 4 + wv;
        switch (band) {
            case 0:  impB_body< 4>(imp, head_bias, sidxg, cnts, q, hi, lane); break;
            case 1:  impB_body< 8>(imp, head_bias, sidxg, cnts, q, hi, lane); break;
            case 2:  impB_body<12>(imp, head_bias, sidxg, cnts, q, hi, lane); break;
            case 3:  impB_body<16>(imp, head_bias, sidxg, cnts, q, hi, lane); break;
            case 4:  impB_body<20>(imp, head_bias, sidxg, cnts, q, hi, lane); break;
            case 5:  impB_body<24>(imp, head_bias, sidxg, cnts, q, hi, lane); break;
            case 6:  impB_body<28>(imp, head_bias, sidxg, cnts, q, hi, lane); break;
            default: impB_body<32>(imp, head_bias, sidxg, cnts, q, hi, lane); break;
        }
    } else {
        rope_v_body(b - 2048, lincatb, cost, sint, Q, Kb, Vb);
    }
}

// ---------------- sparse gather attention: 2 queries per wave, bf16 K/V -------
__global__ __launch_bounds__(256) void attn_sparse_kernel(
    const float* __restrict__ Q, const unsigned short* __restrict__ Kb,
    const unsigned short* __restrict__ Vb,
    const unsigned short* __restrict__ sidx, const unsigned* __restrict__ cnts,
    const unsigned short* __restrict__ lincatb, unsigned short* __restrict__ ogb)
{
    const int orig = blockIdx.x + (blockIdx.y << 8);          // gridDim = (256,16)
    const int c = ((orig & 7) << 9) | (orig >> 3);            // XCD j -> heads 2j,2j+1
    const int h = c >> 8;
    const int qt = c & 255;
    const int hi = h >> 2, hj = h & 3;
    const int wv = threadIdx.x >> 6;
    const int lane = threadIdx.x & 63;
    const int qh = lane >> 5;         // query within pair
    const int l32 = lane & 31;
    const int kk = l32 >> 2;          // key slot 0..7
    const int dg = lane & 3;          // dim group 0..3
    const int q = qt * 8 + wv * 2 + qh;

    const size_t hq = (size_t)hi * T_SEQ + q;
    const int nv = (int)cnts[hq];
    const int nvm = max(nv, __shfl_xor(nv, 32));   // wave-uniform path choice
    const unsigned short* sp = sidx + hq * KMAXV;
    const unsigned short* Kh = Kb + (size_t)h * T_SEQ * HD + dg * 16;
    const unsigned short* Vh = Vb + (size_t)h * T_SEQ * HD + dg * 16;

    float4 qg[4];
    {
        const float4* qp = (const float4*)(Q + ((size_t)h * T_SEQ + q) * HD + dg * 16);
        qg[0] = qp[0]; qg[1] = qp[1]; qg[2] = qp[2]; qg[3] = qp[3];
    }

    float acc[16];
#pragma unroll
    for (int i = 0; i < 16; ++i) acc[i] = 0.f;
    float l = 0.f;

    if (nvm <= 32) {
        const ushort4 e4 = *(const ushort4*)(sp + kk * 4);
        const unsigned ev[4] = {e4.x, e4.y, e4.z, e4.w};

        float s[4]; int idxs[4];
#pragma unroll
        for (int sub = 0; sub < 4; ++sub) {
            const int kpos = kk * 4 + sub;
            const unsigned e = ev[sub];
            const bool ok = (kpos < nv) && ((e >> (11 + hj)) & 1u);
            const int iv = ok ? (int)(e & 0x7FFu) : 0;
            idxs[sub] = iv;
            const uint4* kr = (const uint4*)(Kh + (size_t)iv * HD);
            uint4 ka = kr[0], kb2 = kr[1];
            float da = 0.f, db = 0.f;
            da = fmaf(qg[0].x, bflo(ka.x), da); da = fmaf(qg[0].y, bfhi(ka.x), da);
            da = fmaf(qg[0].z, bflo(ka.y), da); da = fmaf(qg[0].w, bfhi(ka.y), da);
            db = fmaf(qg[1].x, bflo(ka.z), db); db = fmaf(qg[1].y, bfhi(ka.z), db);
            db = fmaf(qg[1].z, bflo(ka.w), db); db = fmaf(qg[1].w, bfhi(ka.w), db);
            da = fmaf(qg[2].x, bflo(kb2.x), da); da = fmaf(qg[2].y, bfhi(kb2.x), da);
            da = fmaf(qg[2].z, bflo(kb2.y), da); da = fmaf(qg[2].w, bfhi(kb2.y), da);
            db = fmaf(qg[3].x, bflo(kb2.z), db); db = fmaf(qg[3].y, bfhi(kb2.z), db);
            db = fmaf(qg[3].z, bflo(kb2.w), db); db = fmaf(qg[3].w, bfhi(kb2.w), db);
            float dot = da + db;
            dot += __shfl_xor(dot, 1);
            dot += __shfl_xor(dot, 2);
            s[sub] = ok ? dot * 0.125f : -INFINITY;
        }

        float cm = fmaxf(fmaxf(s[0], s[1]), fmaxf(s[2], s[3]));
        cm = fmaxf(cm, __shfl_xor(cm, 4));
        cm = fmaxf(cm, __shfl_xor(cm, 8));
        cm = fmaxf(cm, __shfl_xor(cm, 16));

        float p[4];
        float ls = 0.f;
#pragma unroll
        for (int sub = 0; sub < 4; ++sub) { p[sub] = expf(s[sub] - cm); ls += p[sub]; }
        ls += __shfl_xor(ls, 4);
        ls += __shfl_xor(ls, 8);
        ls += __shfl_xor(ls, 16);
        l = ls;
#pragma unroll
        for (int sub = 0; sub < 4; ++sub) {
            const float pv = p[sub];                         // 0 for masked
            const uint4* vr = (const uint4*)(Vh + (size_t)idxs[sub] * HD);
            uint4 va = vr[0], vb4 = vr[1];
            acc[0]  = fmaf(pv, bflo(va.x), acc[0]);   acc[1]  = fmaf(pv, bfhi(va.x), acc[1]);
            acc[2]  = fmaf(pv, bflo(va.y), acc[2]);   acc[3]  = fmaf(pv, bfhi(va.y), acc[3]);
            acc[4]  = fmaf(pv, bflo(va.z), acc[4]);   acc[5]  = fmaf(pv, bfhi(va.z), acc[5]);
            acc[6]  = fmaf(pv, bflo(va.w), acc[6]);   acc[7]  = fmaf(pv, bfhi(va.w), acc[7]);
            acc[8]  = fmaf(pv, bflo(vb4.x), acc[8]);  acc[9]  = fmaf(pv, bfhi(vb4.x), acc[9]);
            acc[10] = fmaf(pv, bflo(vb4.y), acc[10]); acc[11] = fmaf(pv, bfhi(vb4.y), acc[11]);
            acc[12] = fmaf(pv, bflo(vb4.z), acc[12]); acc[13] = fmaf(pv, bfhi(vb4.z), acc[13]);
            acc[14] = fmaf(pv, bflo(vb4.w), acc[14]); acc[15] = fmaf(pv, bfhi(vb4.w), acc[15]);
        }
    } else {
        float m = -INFINITY;
        for (int base = 0; base < nvm; base += 32) {
            const int nk = nv - base;
            const ushort4 e4 = *(const ushort4*)(sp + base + kk * 4);
            const unsigned ev[4] = {e4.x, e4.y, e4.z, e4.w};

            float s[4]; int idxs[4];
#pragma unroll
            for (int sub = 0; sub < 4; ++sub) {
                const int kpos = kk * 4 + sub;
                const unsigned e = ev[sub];
                const bool ok = (kpos < nk) && ((e >> (11 + hj)) & 1u);
                const int iv = ok ? (int)(e & 0x7FFu) : 0;
                idxs[sub] = iv;
                const uint4* kr = (const uint4*)(Kh + (size_t)iv * HD);
                uint4 ka = kr[0], kb2 = kr[1];
                float da = 0.f, db = 0.f;
                da = fmaf(qg[0].x, bflo(ka.x), da); da = fmaf(qg[0].y, bfhi(ka.x), da);
                da = fmaf(qg[0].z, bflo(ka.y), da); da = fmaf(qg[0].w, bfhi(ka.y), da);
                db = fmaf(qg[1].x, bflo(ka.z), db); db = fmaf(qg[1].y, bfhi(ka.z), db);
                db = fmaf(qg[1].z, bflo(ka.w), db); db = fmaf(qg[1].w, bfhi(ka.w), db);
                da = fmaf(qg[2].x, bflo(kb2.x), da); da = fmaf(qg[2].y, bfhi(kb2.x), da);
                da = fmaf(qg[2].z, bflo(kb2.y), da); da = fmaf(qg[2].w, bfhi(kb2.y), da);
                db = fmaf(qg[3].x, bflo(kb2.z), db); db = fmaf(qg[3].y, bfhi(kb2.z), db);
                db = fmaf(qg[3].z, bflo(kb2.w), db); db = fmaf(qg[3].w, bfhi(kb2.w), db);
                float dot = da + db;
                dot += __shfl_xor(dot, 1);
                dot += __shfl_xor(dot, 2);
                s[sub] = ok ? dot * 0.125f : -INFINITY;
            }

            float cm = fmaxf(fmaxf(s[0], s[1]), fmaxf(s[2], s[3]));
            cm = fmaxf(cm, __shfl_xor(cm, 4));
            cm = fmaxf(cm, __shfl_xor(cm, 8));
            cm = fmaxf(cm, __shfl_xor(cm, 16));
            const float mn = fmaxf(m, cm);
            if (mn > -INFINITY) {
                const float alpha = expf(m - mn);
                float p[4];
                float ls = 0.f;
#pragma unroll
                for (int sub = 0; sub < 4; ++sub) { p[sub] = expf(s[sub] - mn); ls += p[sub]; }
                ls += __shfl_xor(ls, 4);
                ls += __shfl_xor(ls, 8);
                ls += __shfl_xor(ls, 16);
                l = l * alpha + ls;
#pragma unroll
                for (int i = 0; i < 16; ++i) acc[i] *= alpha;
#pragma unroll
                for (int sub = 0; sub < 4; ++sub) {
                    const float pv = p[sub];
                    const uint4* vr = (const uint4*)(Vh + (size_t)idxs[sub] * HD);
                    uint4 va = vr[0], vb4 = vr[1];
                    acc[0]  = fmaf(pv, bflo(va.x), acc[0]);   acc[1]  = fmaf(pv, bfhi(va.x), acc[1]);
                    acc[2]  = fmaf(pv, bflo(va.y), acc[2]);   acc[3]  = fmaf(pv, bfhi(va.y), acc[3]);
                    acc[4]  = fmaf(pv, bflo(va.z), acc[4]);   acc[5]  = fmaf(pv, bfhi(va.z), acc[5]);
                    acc[6]  = fmaf(pv, bflo(va.w), acc[6]);   acc[7]  = fmaf(pv, bfhi(va.w), acc[7]);
                    acc[8]  = fmaf(pv, bflo(vb4.x), acc[8]);  acc[9]  = fmaf(pv, bfhi(vb4.x), acc[9]);
                    acc[10] = fmaf(pv, bflo(vb4.y), acc[10]); acc[11] = fmaf(pv, bfhi(vb4.y), acc[11]);
                    acc[12] = fmaf(pv, bflo(vb4.z), acc[12]); acc[13] = fmaf(pv, bfhi(vb4.z), acc[13]);
                    acc[14] = fmaf(pv, bflo(vb4.w), acc[14]); acc[15] = fmaf(pv, bfhi(vb4.w), acc[15]);
                }
                m = mn;
            }
        }
    }

#pragma unroll
    for (int i = 0; i < 16; ++i) {
        acc[i] += __shfl_xor(acc[i], 4);
        acc[i] += __shfl_xor(acc[i], 8);
        acc[i] += __shfl_xor(acc[i], 16);
    }
    const float invl = 1.f / l;
    float oval0 = acc[0], oval1 = acc[1];
#pragma unroll
    for (int i = 1; i < 8; ++i)
        if (kk == i) { oval0 = acc[2 * i]; oval1 = acc[2 * i + 1]; }
    const int d0 = dg * 16 + kk * 2;
    const ushort2 g2 = *(const ushort2*)(lincatb + (size_t)q * NCAT + 4096 + h * HD + d0);
    ushort2 o2;
    o2.x = f2bf(oval0 * invl * sigf(bf16f(g2.x)));
    o2.y = f2bf(oval1 * invl * sigf(bf16f(g2.y)));
    *(ushort2*)(ogb + (size_t)q * C_DIM + h * HD + d0) = o2;
}

extern "C" void kernel_launch(void* const* d_in, const int* in_sizes, int n_in,
                              void* d_out, int out_size, void* d_ws, size_t ws_size,
                              hipStream_t stream)
{
    const float* x   = (const float*)d_in[0];
    const float* WIq = (const float*)d_in[1];
    const float* WIk = (const float*)d_in[2];
    const float* WIw = (const float*)d_in[3];
    const float* gb  = (const float*)d_in[4];
    const float* hib = (const float*)d_in[5];
    const float* Wq  = (const float*)d_in[6];
    const float* Wk  = (const float*)d_in[7];
    const float* Wv  = (const float*)d_in[8];
    const float* Wgv = (const float*)d_in[9];
    const float* Wgo = (const float*)d_in[10];
    const float* Wo  = (const float*)d_in[11];
    float* out = (float*)d_out;

    char* ws = (char*)d_ws;
    const size_t MB = 1024 * 1024;
    float*    qI     = (float*)(ws + 0 * MB);                 // 1 MB
    float*    kI     = (float*)(ws + 1 * MB);                 // 1 MB
    float*    wsig   = (float*)(ws + 2 * MB);                 // 32 KB
    unsigned* cnts   = (unsigned*)(ws + 2 * MB + 64 * 1024);  // 32 KB
    float*    cost   = (float*)(ws + 2 * MB + 512 * 1024);    // 256 KB
    float*    sint   = (float*)(ws + 2 * MB + 768 * 1024);    // 256 KB
    float*    Q      = (float*)(ws + 3 * MB);                 // 8 MB  -> 11
    unsigned short* Kb = (unsigned short*)(ws + 11 * MB);     // 4 MB  -> 15
    unsigned short* Vb = (unsigned short*)(ws + 15 * MB);     // 4 MB  -> 19
    unsigned short* sidx = (unsigned short*)(ws + 19 * MB);   // 16 MB -> 35
    // region A (35..71): part (16 MB, K1 write / K2 read) -> imp (35.7 MB, K3 write / K4 read)
    float*    part    = (float*)(ws + 35 * MB);
    float*    imp     = (float*)(ws + 35 * MB);
    unsigned short* lincatb = (unsigned short*)(ws + 71 * MB);// 20 MB -> 91 (written K3)
    unsigned short* ogb   = (unsigned short*)(ws + 91 * MB);  // 4 MB  -> 95
    unsigned short* xb    = (unsigned short*)(ws + 95 * MB);  // 4 MB  -> 99
    unsigned short* Wcatb = (unsigned short*)(ws + 99 * MB);  // 10 MB -> 109
    unsigned short* Wob   = (unsigned short*)(ws + 109 * MB); // 2 MB  -> 111

    // K1: qik_splitk8_m64 (heavy first, 2 blocks/CU, XCD-swizzled) + rest
    pre_kernel<<<dim3(9088), 256, 0, stream>>>(
        x, WIq, WIk, WIw, Wq, Wk, Wv, Wgv, Wgo, Wo,
        xb, Wcatb, Wob, part, wsig, cost, sint);
    // K2
    qik_reduce_kernel<<<dim3(2048), 256, 0, stream>>>(part, qI, kI);
    // K3: proj-GEMM (bf16 out) then impA, both XCD-swizzled for L2 panel reuse
    mid_kernel<<<dim3(1184), 256, 0, stream>>>(
        xb, Wcatb, lincatb, qI, kI, wsig, gb, imp);
    // K4: impB + rope_v
    sel_kernel<<<dim3(6144), 256, 0, stream>>>(
        imp, hib, sidx, cnts, lincatb, cost, sint, Q, Kb, Vb);
    // attention + out-projection
    attn_sparse_kernel<<<dim3(256, 16), 256, 0, stream>>>(Q, Kb, Vb, sidx, cnts, lincatb, ogb);
    // out-projection: 128x64 tiles, 256 blocks 1D, XCD-swizzled
    gemm_out_kernel<<<dim3(256), 256, 0, stream>>>(ogb, Wob, out, C_DIM);
}